// Round 1
// baseline (1184.322 us; speedup 1.0000x reference)
//
#include <hip/hip_runtime.h>
#include <hip/hip_bf16.h>
#include <math.h>

#define TOK   8192
#define HDIM  1024
#define NE    16
#define NI    512
#define F2    1024
#define CAP   8192
#define ALPHA 1.702f
#define LIMIT 7.0f

typedef __attribute__((ext_vector_type(8))) short short8;
typedef __attribute__((ext_vector_type(4))) float f32x4;

static __device__ __forceinline__ unsigned short f2bf(float f) {
    unsigned int u = __float_as_uint(f);
    u += 0x7FFFu + ((u >> 16) & 1u);
    return (unsigned short)(u >> 16);
}

// ---------------- router: fp64 logits, top-2, softmax, scatter ----------------
__global__ __launch_bounds__(256) void router_kernel(
    const float* __restrict__ x, const float* __restrict__ rw,
    int* __restrict__ counts, int* __restrict__ toks, float* __restrict__ wgts)
{
    int gwave = (int)((blockIdx.x * 256 + threadIdx.x) >> 6);
    int lane = threadIdx.x & 63;
    if (gwave >= TOK) return;
    const float* xr = x + (size_t)gwave * HDIM;
    double acc[NE];
#pragma unroll
    for (int e = 0; e < NE; ++e) acc[e] = 0.0;
    for (int i = 0; i < HDIM / 64; ++i) {
        int h = i * 64 + lane;
        double xv = (double)xr[h];
        const float* r = rw + (size_t)h * NE;
#pragma unroll
        for (int e = 0; e < NE; ++e) acc[e] += xv * (double)r[e];
    }
#pragma unroll
    for (int e = 0; e < NE; ++e) {
        double v = acc[e];
#pragma unroll
        for (int off = 32; off > 0; off >>= 1) v += __shfl_xor(v, off);
        acc[e] = v;
    }
    if (lane == 0) {
        int i0 = 0; double v0 = acc[0];
#pragma unroll
        for (int e = 1; e < NE; ++e) if (acc[e] > v0) { v0 = acc[e]; i0 = e; }
        int i1 = -1; double v1 = -1e300;
#pragma unroll
        for (int e = 0; e < NE; ++e) if (e != i0 && acc[e] > v1) { v1 = acc[e]; i1 = e; }
        double e1 = exp(v1 - v0);
        float w0 = (float)(1.0 / (1.0 + e1));
        float w1 = (float)(e1 / (1.0 + e1));
        int p0 = atomicAdd(&counts[i0], 1);
        toks[i0 * CAP + p0] = gwave; wgts[i0 * CAP + p0] = w0;
        int p1 = atomicAdd(&counts[i1], 1);
        toks[i1 * CAP + p1] = gwave; wgts[i1 * CAP + p1] = w1;
    }
}

// ---------------- fused expert MLP: gather -> GEMM1 -> act -> GEMM2 -> scatter-add ----------------
__global__ __launch_bounds__(256) void moe_kernel(
    const float* __restrict__ x,
    const float* __restrict__ gup, const float* __restrict__ gub,
    const float* __restrict__ dwn, const float* __restrict__ dwb,
    const int* __restrict__ counts, const int* __restrict__ toks,
    const float* __restrict__ wgts, float* __restrict__ out)
{
    int e = blockIdx.y;
    int cnt = counts[e];
    int row0 = blockIdx.x * 64;
    if (row0 >= cnt) return;

    __shared__ __align__(16) unsigned short sA[64][40];
    __shared__ __align__(16) unsigned short sB[64][40];
    __shared__ __align__(16) unsigned short sAct[64][520];
    __shared__ int   rtok[64];
    __shared__ float rwgt[64];

    int tid = threadIdx.x;
    if (tid < 64) {
        int idx = row0 + tid;
        bool v = idx < cnt;
        rtok[tid] = v ? toks[e * CAP + idx] : -1;
        rwgt[tid] = v ? wgts[e * CAP + idx] : 0.0f;
    }
    __syncthreads();

    int lane = tid & 63;
    int w = tid >> 6;
    int wr = w >> 1, wc = w & 1;
    int lr = lane & 15, lg = lane >> 4;

    int ar = tid >> 2, ac0 = (tid & 3) * 8;   // A staging: row / col0
    int bk = tid >> 3, bf0 = (tid & 7) * 8;   // B staging: k-row / n-col0

    const float* gupE = gup + (size_t)e * HDIM * F2;

    // ---------- GEMM1 + activation -> sAct ----------
    for (int nb = 0; nb < F2 / 64; ++nb) {
        f32x4 acc[2][2];
#pragma unroll
        for (int mi = 0; mi < 2; ++mi)
#pragma unroll
            for (int ni = 0; ni < 2; ++ni)
                acc[mi][ni] = (f32x4){0.f, 0.f, 0.f, 0.f};

        for (int kb = 0; kb < HDIM / 32; ++kb) {
            __syncthreads();
            {   // stage A (gathered tokens), 64x32 bf16
                int tk = rtok[ar];
                short8 vv = {0, 0, 0, 0, 0, 0, 0, 0};
                if (tk >= 0) {
                    const float* p = x + (size_t)tk * HDIM + kb * 32 + ac0;
                    float4 u0 = *(const float4*)(p);
                    float4 u1 = *(const float4*)(p + 4);
                    vv[0] = (short)f2bf(u0.x); vv[1] = (short)f2bf(u0.y);
                    vv[2] = (short)f2bf(u0.z); vv[3] = (short)f2bf(u0.w);
                    vv[4] = (short)f2bf(u1.x); vv[5] = (short)f2bf(u1.y);
                    vv[6] = (short)f2bf(u1.z); vv[7] = (short)f2bf(u1.w);
                }
                *(short8*)&sA[ar][ac0] = vv;
            }
            {   // stage B transposed: sB[n][k]
                const float* p = gupE + (size_t)(kb * 32 + bk) * F2 + nb * 64 + bf0;
                float4 u0 = *(const float4*)(p);
                float4 u1 = *(const float4*)(p + 4);
                sB[bf0 + 0][bk] = f2bf(u0.x); sB[bf0 + 1][bk] = f2bf(u0.y);
                sB[bf0 + 2][bk] = f2bf(u0.z); sB[bf0 + 3][bk] = f2bf(u0.w);
                sB[bf0 + 4][bk] = f2bf(u1.x); sB[bf0 + 5][bk] = f2bf(u1.y);
                sB[bf0 + 6][bk] = f2bf(u1.z); sB[bf0 + 7][bk] = f2bf(u1.w);
            }
            __syncthreads();
            short8 a0 = *(const short8*)&sA[wr * 32 + lr][lg * 8];
            short8 a1 = *(const short8*)&sA[wr * 32 + 16 + lr][lg * 8];
            short8 b0 = *(const short8*)&sB[wc * 32 + lr][lg * 8];
            short8 b1 = *(const short8*)&sB[wc * 32 + 16 + lr][lg * 8];
            acc[0][0] = __builtin_amdgcn_mfma_f32_16x16x32_bf16(a0, b0, acc[0][0], 0, 0, 0);
            acc[0][1] = __builtin_amdgcn_mfma_f32_16x16x32_bf16(a0, b1, acc[0][1], 0, 0, 0);
            acc[1][0] = __builtin_amdgcn_mfma_f32_16x16x32_bf16(a1, b0, acc[1][0], 0, 0, 0);
            acc[1][1] = __builtin_amdgcn_mfma_f32_16x16x32_bf16(a1, b1, acc[1][1], 0, 0, 0);
        }
        // epilogue: +bias, pair gate/up via shfl_xor(1), activation, write sAct
#pragma unroll
        for (int ni = 0; ni < 2; ++ni) {
            int fc = nb * 64 + wc * 32 + ni * 16 + lr;
            float bias = gub[e * F2 + fc];
#pragma unroll
            for (int mi = 0; mi < 2; ++mi) {
#pragma unroll
                for (int r = 0; r < 4; ++r) {
                    float gu = acc[mi][ni][r] + bias;
                    float other = __shfl_xor(gu, 1);
                    float gate = (lr & 1) ? other : gu;
                    float up   = (lr & 1) ? gu : other;
                    gate = fminf(gate, LIMIT);
                    up = fminf(fmaxf(up, -LIMIT), LIMIT);
                    float glu = gate / (1.0f + __expf(-ALPHA * gate));
                    float av = (up + 1.0f) * glu;
                    if (!(lr & 1)) {
                        int row = wr * 32 + mi * 16 + lg * 4 + r;
                        sAct[row][fc >> 1] = f2bf(av);
                    }
                }
            }
        }
    }
    __syncthreads();

    // ---------- GEMM2: act @ down, *score, +bias, scatter-add ----------
    const float* dwnE = dwn + (size_t)e * NI * HDIM;
    int tks[2][4]; float wvs[2][4];
#pragma unroll
    for (int mi = 0; mi < 2; ++mi)
#pragma unroll
        for (int r = 0; r < 4; ++r) {
            int row = wr * 32 + mi * 16 + lg * 4 + r;
            tks[mi][r] = rtok[row];
            wvs[mi][r] = rwgt[row];
        }

    for (int nb = 0; nb < HDIM / 64; ++nb) {
        f32x4 acc[2][2];
#pragma unroll
        for (int mi = 0; mi < 2; ++mi)
#pragma unroll
            for (int ni = 0; ni < 2; ++ni)
                acc[mi][ni] = (f32x4){0.f, 0.f, 0.f, 0.f};

        for (int kb = 0; kb < NI / 32; ++kb) {
            __syncthreads();
            {   // stage down transposed: sB[n][k]
                const float* p = dwnE + (size_t)(kb * 32 + bk) * HDIM + nb * 64 + bf0;
                float4 u0 = *(const float4*)(p);
                float4 u1 = *(const float4*)(p + 4);
                sB[bf0 + 0][bk] = f2bf(u0.x); sB[bf0 + 1][bk] = f2bf(u0.y);
                sB[bf0 + 2][bk] = f2bf(u0.z); sB[bf0 + 3][bk] = f2bf(u0.w);
                sB[bf0 + 4][bk] = f2bf(u1.x); sB[bf0 + 5][bk] = f2bf(u1.y);
                sB[bf0 + 6][bk] = f2bf(u1.z); sB[bf0 + 7][bk] = f2bf(u1.w);
            }
            __syncthreads();
            short8 a0 = *(const short8*)&sAct[wr * 32 + lr][kb * 32 + lg * 8];
            short8 a1 = *(const short8*)&sAct[wr * 32 + 16 + lr][kb * 32 + lg * 8];
            short8 b0 = *(const short8*)&sB[wc * 32 + lr][lg * 8];
            short8 b1 = *(const short8*)&sB[wc * 32 + 16 + lr][lg * 8];
            acc[0][0] = __builtin_amdgcn_mfma_f32_16x16x32_bf16(a0, b0, acc[0][0], 0, 0, 0);
            acc[0][1] = __builtin_amdgcn_mfma_f32_16x16x32_bf16(a0, b1, acc[0][1], 0, 0, 0);
            acc[1][0] = __builtin_amdgcn_mfma_f32_16x16x32_bf16(a1, b0, acc[1][0], 0, 0, 0);
            acc[1][1] = __builtin_amdgcn_mfma_f32_16x16x32_bf16(a1, b1, acc[1][1], 0, 0, 0);
        }
#pragma unroll
        for (int ni = 0; ni < 2; ++ni) {
            int hc = nb * 64 + wc * 32 + ni * 16 + lr;
            float db = dwb[e * HDIM + hc];
#pragma unroll
            for (int mi = 0; mi < 2; ++mi)
#pragma unroll
                for (int r = 0; r < 4; ++r) {
                    int tk = tks[mi][r];
                    if (tk >= 0)
                        atomicAdd(out + (size_t)tk * HDIM + hc,
                                  wvs[mi][r] * (acc[mi][ni][r] + db));
                }
        }
    }
}

extern "C" void kernel_launch(void* const* d_in, const int* in_sizes, int n_in,
                              void* d_out, int out_size, void* d_ws, size_t ws_size,
                              hipStream_t stream) {
    const float* x   = (const float*)d_in[0];
    const float* rw  = (const float*)d_in[1];
    const float* gup = (const float*)d_in[2];
    const float* gub = (const float*)d_in[3];
    const float* dwn = (const float*)d_in[4];
    const float* dwb = (const float*)d_in[5];
    float* out = (float*)d_out;

    int*   counts = (int*)d_ws;
    int*   toks   = (int*)((char*)d_ws + 64);
    float* wgts   = (float*)((char*)d_ws + 64 + (size_t)NE * CAP * sizeof(int));

    hipMemsetAsync(d_ws, 0, 64, stream);
    hipMemsetAsync(d_out, 0, (size_t)out_size * sizeof(float), stream);

    router_kernel<<<TOK / 4, 256, 0, stream>>>(x, rw, counts, toks, wgts);

    dim3 g2(TOK / 64, NE);
    moe_kernel<<<g2, 256, 0, stream>>>(x, gup, gub, dwn, dwb, counts, toks, wgts, out);
}

// Round 2
// 421.374 us; speedup vs baseline: 2.8106x; 2.8106x over previous
//
#include <hip/hip_runtime.h>
#include <hip/hip_bf16.h>
#include <math.h>

#define TOK   8192
#define HDIM  1024
#define NE    16
#define NI    512
#define F2    1024
#define CAP   8192
#define CAP2  2048
#define ALPHA 1.702f
#define LIMIT 7.0f

typedef __attribute__((ext_vector_type(8))) short short8;
typedef __attribute__((ext_vector_type(4))) float f32x4;

static __device__ __forceinline__ unsigned short f2bf(float f) {
    unsigned int u = __float_as_uint(f);
    u += 0x7FFFu + ((u >> 16) & 1u);
    return (unsigned short)(u >> 16);
}

#define GLD_LDS16(g, l) __builtin_amdgcn_global_load_lds(                     \
    (const __attribute__((address_space(1))) void*)(g),                       \
    (__attribute__((address_space(3))) void*)(l), 16, 0, 0)

// ---------------- router: fp64 logits, top-2, softmax, scatter ----------------
__global__ __launch_bounds__(256) void router_kernel(
    const float* __restrict__ x, const float* __restrict__ rw,
    int* __restrict__ counts, int* __restrict__ toks, float* __restrict__ wgts)
{
    int gwave = (int)((blockIdx.x * 256 + threadIdx.x) >> 6);
    int lane = threadIdx.x & 63;
    if (gwave >= TOK) return;
    const float* xr = x + (size_t)gwave * HDIM;
    double acc[NE];
#pragma unroll
    for (int e = 0; e < NE; ++e) acc[e] = 0.0;
    for (int i = 0; i < HDIM / 64; ++i) {
        int h = i * 64 + lane;
        double xv = (double)xr[h];
        const float* r = rw + (size_t)h * NE;
#pragma unroll
        for (int e = 0; e < NE; ++e) acc[e] += xv * (double)r[e];
    }
#pragma unroll
    for (int e = 0; e < NE; ++e) {
        double v = acc[e];
#pragma unroll
        for (int off = 32; off > 0; off >>= 1) v += __shfl_xor(v, off);
        acc[e] = v;
    }
    if (lane == 0) {
        int i0 = 0; double v0 = acc[0];
#pragma unroll
        for (int e = 1; e < NE; ++e) if (acc[e] > v0) { v0 = acc[e]; i0 = e; }
        int i1 = -1; double v1 = -1e300;
#pragma unroll
        for (int e = 0; e < NE; ++e) if (e != i0 && acc[e] > v1) { v1 = acc[e]; i1 = e; }
        double e1 = exp(v1 - v0);
        float w0 = (float)(1.0 / (1.0 + e1));
        float w1 = (float)(e1 / (1.0 + e1));
        int p0 = atomicAdd(&counts[i0], 1);
        toks[i0 * CAP + p0] = gwave; wgts[i0 * CAP + p0] = w0;
        int p1 = atomicAdd(&counts[i1], 1);
        toks[i1 * CAP + p1] = gwave; wgts[i1 * CAP + p1] = w1;
    }
}

// ---------------- fp32 -> bf16 bulk convert (x) ----------------
__global__ __launch_bounds__(256) void cvt_x_kernel(
    const float* __restrict__ in, unsigned short* __restrict__ out)
{
    size_t i = ((size_t)blockIdx.x * 256 + threadIdx.x) * 8;
    float4 u0 = *(const float4*)(in + i);
    float4 u1 = *(const float4*)(in + i + 4);
    short8 v;
    v[0] = (short)f2bf(u0.x); v[1] = (short)f2bf(u0.y);
    v[2] = (short)f2bf(u0.z); v[3] = (short)f2bf(u0.w);
    v[4] = (short)f2bf(u1.x); v[5] = (short)f2bf(u1.y);
    v[6] = (short)f2bf(u1.z); v[7] = (short)f2bf(u1.w);
    *(short8*)(out + i) = v;
}

// ------------- transpose + convert: in [E][R][C] fp32 -> out [E][C][R] bf16 -------------
__global__ __launch_bounds__(256) void transpose_kernel(
    const float* __restrict__ in, unsigned short* __restrict__ out, int R, int C)
{
    int e = blockIdx.z;
    const float* pin = in + (size_t)e * R * C;
    unsigned short* pout = out + (size_t)e * R * C;
    __shared__ float t[64][65];
    int c0 = blockIdx.x * 64, r0 = blockIdx.y * 64;
    int tid = threadIdx.x;
#pragma unroll
    for (int j = 0; j < 16; ++j) {
        int idx = j * 256 + tid;
        int r = idx >> 6, c = idx & 63;
        t[r][c] = pin[(size_t)(r0 + r) * C + c0 + c];
    }
    __syncthreads();
#pragma unroll
    for (int j = 0; j < 16; ++j) {
        int idx = j * 256 + tid;
        int n = idx >> 6, k = idx & 63;
        pout[(size_t)(c0 + n) * R + r0 + k] = f2bf(t[k][n]);
    }
}

// ---------------- GEMM1: x_bf (gathered) @ gupT^T + bias -> act (bf16) ----------------
__global__ __launch_bounds__(256) void gemm1_kernel(
    const unsigned short* __restrict__ xb, const unsigned short* __restrict__ gupT,
    const float* __restrict__ gub,
    const int* __restrict__ counts, const int* __restrict__ toks,
    unsigned short* __restrict__ act, const unsigned short* __restrict__ zp)
{
    int b = blockIdx.x;
    int e = b & 15;
    int j = b >> 4;
    int nt = j & 7;
    int mt = j >> 3;
    int cnt = counts[e];
    int row0 = mt * 128;
    if (row0 >= cnt) return;
    int n0 = nt * 128;

    __shared__ __align__(16) unsigned short As[128][32];
    __shared__ __align__(16) unsigned short Bs[128][32];
    __shared__ int rtok[128];

    int tid = threadIdx.x;
    int lane = tid & 63;
    int w = tid >> 6;
    int wr = w >> 1, wc = w & 1;
    int lr = lane & 15, lg = lane >> 4;

    if (tid < 128) {
        int p = row0 + tid;
        rtok[tid] = (p < cnt) ? toks[e * CAP + p] : -1;
    }
    __syncthreads();

    int srow = lane >> 2;
    int scol = (lane & 3) * 8;
    const unsigned short* gaA[2];
    const unsigned short* gaB[2];
    const unsigned short* gupE = gupT + (size_t)e * HDIM * F2;
#pragma unroll
    for (int i = 0; i < 2; ++i) {
        int arow = w * 32 + i * 16 + srow;
        int tk = rtok[arow];
        gaA[i] = (tk >= 0) ? (xb + (size_t)tk * HDIM + scol) : (zp + scol);
        int brow = n0 + w * 32 + i * 16 + srow;
        gaB[i] = gupE + (size_t)brow * HDIM + scol;
    }

    f32x4 acc[4][4];
#pragma unroll
    for (int m = 0; m < 4; ++m)
#pragma unroll
        for (int n = 0; n < 4; ++n) acc[m][n] = (f32x4){0.f, 0.f, 0.f, 0.f};

    for (int kb = 0; kb < HDIM / 32; ++kb) {
#pragma unroll
        for (int i = 0; i < 2; ++i) {
            GLD_LDS16(gaA[i] + kb * 32, &As[w * 32 + i * 16][0]);
            GLD_LDS16(gaB[i] + kb * 32, &Bs[w * 32 + i * 16][0]);
        }
        __syncthreads();
        short8 af[4], bfr[4];
#pragma unroll
        for (int m = 0; m < 4; ++m) af[m] = *(const short8*)&As[wr * 64 + m * 16 + lr][lg * 8];
#pragma unroll
        for (int n = 0; n < 4; ++n) bfr[n] = *(const short8*)&Bs[wc * 64 + n * 16 + lr][lg * 8];
#pragma unroll
        for (int m = 0; m < 4; ++m)
#pragma unroll
            for (int n = 0; n < 4; ++n)
                acc[m][n] = __builtin_amdgcn_mfma_f32_16x16x32_bf16(af[m], bfr[n], acc[m][n], 0, 0, 0);
        __syncthreads();
    }

    unsigned short* actE = act + (size_t)e * CAP2 * NI;
#pragma unroll
    for (int n = 0; n < 4; ++n) {
        int fc = n0 + wc * 64 + n * 16 + lr;
        float bias = gub[e * F2 + fc];
#pragma unroll
        for (int m = 0; m < 4; ++m) {
#pragma unroll
            for (int r = 0; r < 4; ++r) {
                float gu = acc[m][n][r] + bias;
                float other = __shfl_xor(gu, 1);
                float gate = (lr & 1) ? other : gu;
                float up   = (lr & 1) ? gu    : other;
                gate = fminf(gate, LIMIT);
                up   = fminf(fmaxf(up, -LIMIT), LIMIT);
                float glu = gate / (1.0f + __expf(-ALPHA * gate));
                float av  = (up + 1.0f) * glu;
                if (!(lr & 1)) {
                    int row = row0 + wr * 64 + m * 16 + lg * 4 + r;
                    actE[(size_t)row * NI + (fc >> 1)] = f2bf(av);
                }
            }
        }
    }
}

// ---------------- GEMM2: act @ dwnT^T, *score, +bias, scatter-add ----------------
__global__ __launch_bounds__(256) void gemm2_kernel(
    const unsigned short* __restrict__ act, const unsigned short* __restrict__ dwnT,
    const float* __restrict__ dwb,
    const int* __restrict__ counts, const int* __restrict__ toks,
    const float* __restrict__ wgts, float* __restrict__ out)
{
    int b = blockIdx.x;
    int e = b & 15;
    int j = b >> 4;
    int nt = j & 7;
    int mt = j >> 3;
    int cnt = counts[e];
    int row0 = mt * 128;
    if (row0 >= cnt) return;
    int n0 = nt * 128;

    __shared__ __align__(16) unsigned short As[128][32];
    __shared__ __align__(16) unsigned short Bs[128][32];
    __shared__ int   rtok[128];
    __shared__ float rwgt[128];

    int tid = threadIdx.x;
    int lane = tid & 63;
    int w = tid >> 6;
    int wr = w >> 1, wc = w & 1;
    int lr = lane & 15, lg = lane >> 4;

    if (tid < 128) {
        int p = row0 + tid;
        bool v = p < cnt;
        rtok[tid] = v ? toks[e * CAP + p] : -1;
        rwgt[tid] = v ? wgts[e * CAP + p] : 0.0f;
    }
    __syncthreads();

    int srow = lane >> 2;
    int scol = (lane & 3) * 8;
    const unsigned short* gaA[2];
    const unsigned short* gaB[2];
    const unsigned short* actE = act + (size_t)e * CAP2 * NI;
    const unsigned short* dwnE = dwnT + (size_t)e * HDIM * NI;
#pragma unroll
    for (int i = 0; i < 2; ++i) {
        int arow = row0 + w * 32 + i * 16 + srow;
        gaA[i] = actE + (size_t)arow * NI + scol;
        int brow = n0 + w * 32 + i * 16 + srow;
        gaB[i] = dwnE + (size_t)brow * NI + scol;
    }

    f32x4 acc[4][4];
#pragma unroll
    for (int m = 0; m < 4; ++m)
#pragma unroll
        for (int n = 0; n < 4; ++n) acc[m][n] = (f32x4){0.f, 0.f, 0.f, 0.f};

    for (int kb = 0; kb < NI / 32; ++kb) {
#pragma unroll
        for (int i = 0; i < 2; ++i) {
            GLD_LDS16(gaA[i] + kb * 32, &As[w * 32 + i * 16][0]);
            GLD_LDS16(gaB[i] + kb * 32, &Bs[w * 32 + i * 16][0]);
        }
        __syncthreads();
        short8 af[4], bfr[4];
#pragma unroll
        for (int m = 0; m < 4; ++m) af[m] = *(const short8*)&As[wr * 64 + m * 16 + lr][lg * 8];
#pragma unroll
        for (int n = 0; n < 4; ++n) bfr[n] = *(const short8*)&Bs[wc * 64 + n * 16 + lr][lg * 8];
#pragma unroll
        for (int m = 0; m < 4; ++m)
#pragma unroll
            for (int n = 0; n < 4; ++n)
                acc[m][n] = __builtin_amdgcn_mfma_f32_16x16x32_bf16(af[m], bfr[n], acc[m][n], 0, 0, 0);
        __syncthreads();
    }

#pragma unroll
    for (int n = 0; n < 4; ++n) {
        int hc = n0 + wc * 64 + n * 16 + lr;
        float db = dwb[e * HDIM + hc];
#pragma unroll
        for (int m = 0; m < 4; ++m) {
#pragma unroll
            for (int r = 0; r < 4; ++r) {
                int row = wr * 64 + m * 16 + lg * 4 + r;
                int tk = rtok[row];
                if (tk >= 0)
                    atomicAdd(out + (size_t)tk * HDIM + hc,
                              rwgt[row] * (acc[m][n][r] + db));
            }
        }
    }
}

// ================= fallback (round-1) expert kernel, used if ws too small =================
__global__ __launch_bounds__(256) void moe_kernel(
    const float* __restrict__ x,
    const float* __restrict__ gup, const float* __restrict__ gub,
    const float* __restrict__ dwn, const float* __restrict__ dwb,
    const int* __restrict__ counts, const int* __restrict__ toks,
    const float* __restrict__ wgts, float* __restrict__ out)
{
    int e = blockIdx.y;
    int cnt = counts[e];
    int row0 = blockIdx.x * 64;
    if (row0 >= cnt) return;

    __shared__ __align__(16) unsigned short sA[64][40];
    __shared__ __align__(16) unsigned short sB[64][40];
    __shared__ __align__(16) unsigned short sAct[64][520];
    __shared__ int   rtok[64];
    __shared__ float rwgt[64];

    int tid = threadIdx.x;
    if (tid < 64) {
        int idx = row0 + tid;
        bool v = idx < cnt;
        rtok[tid] = v ? toks[e * CAP + idx] : -1;
        rwgt[tid] = v ? wgts[e * CAP + idx] : 0.0f;
    }
    __syncthreads();

    int lane = tid & 63;
    int w = tid >> 6;
    int wr = w >> 1, wc = w & 1;
    int lr = lane & 15, lg = lane >> 4;
    int ar = tid >> 2, ac0 = (tid & 3) * 8;
    int bk = tid >> 3, bf0 = (tid & 7) * 8;
    const float* gupE = gup + (size_t)e * HDIM * F2;

    for (int nb = 0; nb < F2 / 64; ++nb) {
        f32x4 acc[2][2];
#pragma unroll
        for (int mi = 0; mi < 2; ++mi)
#pragma unroll
            for (int ni = 0; ni < 2; ++ni) acc[mi][ni] = (f32x4){0.f, 0.f, 0.f, 0.f};
        for (int kb = 0; kb < HDIM / 32; ++kb) {
            __syncthreads();
            {
                int tk = rtok[ar];
                short8 vv = {0,0,0,0,0,0,0,0};
                if (tk >= 0) {
                    const float* p = x + (size_t)tk * HDIM + kb * 32 + ac0;
                    float4 u0 = *(const float4*)(p); float4 u1 = *(const float4*)(p + 4);
                    vv[0]=(short)f2bf(u0.x); vv[1]=(short)f2bf(u0.y); vv[2]=(short)f2bf(u0.z); vv[3]=(short)f2bf(u0.w);
                    vv[4]=(short)f2bf(u1.x); vv[5]=(short)f2bf(u1.y); vv[6]=(short)f2bf(u1.z); vv[7]=(short)f2bf(u1.w);
                }
                *(short8*)&sA[ar][ac0] = vv;
            }
            {
                const float* p = gupE + (size_t)(kb * 32 + bk) * F2 + nb * 64 + bf0;
                float4 u0 = *(const float4*)(p); float4 u1 = *(const float4*)(p + 4);
                sB[bf0+0][bk]=f2bf(u0.x); sB[bf0+1][bk]=f2bf(u0.y); sB[bf0+2][bk]=f2bf(u0.z); sB[bf0+3][bk]=f2bf(u0.w);
                sB[bf0+4][bk]=f2bf(u1.x); sB[bf0+5][bk]=f2bf(u1.y); sB[bf0+6][bk]=f2bf(u1.z); sB[bf0+7][bk]=f2bf(u1.w);
            }
            __syncthreads();
            short8 a0 = *(const short8*)&sA[wr*32+lr][lg*8];
            short8 a1 = *(const short8*)&sA[wr*32+16+lr][lg*8];
            short8 b0 = *(const short8*)&sB[wc*32+lr][lg*8];
            short8 b1 = *(const short8*)&sB[wc*32+16+lr][lg*8];
            acc[0][0] = __builtin_amdgcn_mfma_f32_16x16x32_bf16(a0,b0,acc[0][0],0,0,0);
            acc[0][1] = __builtin_amdgcn_mfma_f32_16x16x32_bf16(a0,b1,acc[0][1],0,0,0);
            acc[1][0] = __builtin_amdgcn_mfma_f32_16x16x32_bf16(a1,b0,acc[1][0],0,0,0);
            acc[1][1] = __builtin_amdgcn_mfma_f32_16x16x32_bf16(a1,b1,acc[1][1],0,0,0);
        }
#pragma unroll
        for (int ni = 0; ni < 2; ++ni) {
            int fc = nb * 64 + wc * 32 + ni * 16 + lr;
            float bias = gub[e * F2 + fc];
#pragma unroll
            for (int mi = 0; mi < 2; ++mi)
#pragma unroll
                for (int r = 0; r < 4; ++r) {
                    float gu = acc[mi][ni][r] + bias;
                    float other = __shfl_xor(gu, 1);
                    float gate = (lr & 1) ? other : gu;
                    float up   = (lr & 1) ? gu : other;
                    gate = fminf(gate, LIMIT);
                    up = fminf(fmaxf(up, -LIMIT), LIMIT);
                    float glu = gate / (1.0f + __expf(-ALPHA * gate));
                    float av = (up + 1.0f) * glu;
                    if (!(lr & 1)) sAct[wr*32+mi*16+lg*4+r][fc >> 1] = f2bf(av);
                }
        }
    }
    __syncthreads();

    const float* dwnE = dwn + (size_t)e * NI * HDIM;
    int tks[2][4]; float wvs[2][4];
#pragma unroll
    for (int mi = 0; mi < 2; ++mi)
#pragma unroll
        for (int r = 0; r < 4; ++r) {
            int row = wr*32 + mi*16 + lg*4 + r;
            tks[mi][r] = rtok[row]; wvs[mi][r] = rwgt[row];
        }
    for (int nb = 0; nb < HDIM / 64; ++nb) {
        f32x4 acc[2][2];
#pragma unroll
        for (int mi = 0; mi < 2; ++mi)
#pragma unroll
            for (int ni = 0; ni < 2; ++ni) acc[mi][ni] = (f32x4){0.f,0.f,0.f,0.f};
        for (int kb = 0; kb < NI / 32; ++kb) {
            __syncthreads();
            {
                const float* p = dwnE + (size_t)(kb*32 + bk) * HDIM + nb*64 + bf0;
                float4 u0 = *(const float4*)(p); float4 u1 = *(const float4*)(p + 4);
                sB[bf0+0][bk]=f2bf(u0.x); sB[bf0+1][bk]=f2bf(u0.y); sB[bf0+2][bk]=f2bf(u0.z); sB[bf0+3][bk]=f2bf(u0.w);
                sB[bf0+4][bk]=f2bf(u1.x); sB[bf0+5][bk]=f2bf(u1.y); sB[bf0+6][bk]=f2bf(u1.z); sB[bf0+7][bk]=f2bf(u1.w);
            }
            __syncthreads();
            short8 a0 = *(const short8*)&sAct[wr*32+lr][kb*32+lg*8];
            short8 a1 = *(const short8*)&sAct[wr*32+16+lr][kb*32+lg*8];
            short8 b0 = *(const short8*)&sB[wc*32+lr][lg*8];
            short8 b1 = *(const short8*)&sB[wc*32+16+lr][lg*8];
            acc[0][0] = __builtin_amdgcn_mfma_f32_16x16x32_bf16(a0,b0,acc[0][0],0,0,0);
            acc[0][1] = __builtin_amdgcn_mfma_f32_16x16x32_bf16(a0,b1,acc[0][1],0,0,0);
            acc[1][0] = __builtin_amdgcn_mfma_f32_16x16x32_bf16(a1,b0,acc[1][0],0,0,0);
            acc[1][1] = __builtin_amdgcn_mfma_f32_16x16x32_bf16(a1,b1,acc[1][1],0,0,0);
        }
#pragma unroll
        for (int ni = 0; ni < 2; ++ni) {
            int hc = nb*64 + wc*32 + ni*16 + lr;
            float db = dwb[e * HDIM + hc];
#pragma unroll
            for (int mi = 0; mi < 2; ++mi)
#pragma unroll
                for (int r = 0; r < 4; ++r) {
                    int tk = tks[mi][r];
                    if (tk >= 0)
                        atomicAdd(out + (size_t)tk * HDIM + hc, wvs[mi][r] * (acc[mi][ni][r] + db));
                }
        }
    }
}

extern "C" void kernel_launch(void* const* d_in, const int* in_sizes, int n_in,
                              void* d_out, int out_size, void* d_ws, size_t ws_size,
                              hipStream_t stream) {
    const float* x   = (const float*)d_in[0];
    const float* rw  = (const float*)d_in[1];
    const float* gup = (const float*)d_in[2];
    const float* gub = (const float*)d_in[3];
    const float* dwn = (const float*)d_in[4];
    const float* dwb = (const float*)d_in[5];
    float* out = (float*)d_out;

    // ---- new-path ws layout ----
    const size_t OFF_COUNTS = 0;                 // 256 B
    const size_t OFF_ZP     = 256;               // 4 KB zero page
    const size_t OFF_TOKS   = 4352;
    const size_t OFF_WGTS   = OFF_TOKS + (size_t)NE * CAP * 4;
    const size_t OFF_XBF    = OFF_WGTS + (size_t)NE * CAP * 4;
    const size_t OFF_GUPT   = OFF_XBF  + (size_t)TOK * HDIM * 2;
    const size_t OFF_DWNT   = OFF_GUPT + (size_t)NE * HDIM * F2 * 2;
    const size_t OFF_ACT    = OFF_DWNT + (size_t)NE * NI * HDIM * 2;
    const size_t REQ        = OFF_ACT  + (size_t)NE * CAP2 * NI * 2;

    if (ws_size >= REQ) {
        int*            counts = (int*)((char*)d_ws + OFF_COUNTS);
        unsigned short* zp     = (unsigned short*)((char*)d_ws + OFF_ZP);
        int*            toks   = (int*)((char*)d_ws + OFF_TOKS);
        float*          wgts   = (float*)((char*)d_ws + OFF_WGTS);
        unsigned short* xbf    = (unsigned short*)((char*)d_ws + OFF_XBF);
        unsigned short* gupT   = (unsigned short*)((char*)d_ws + OFF_GUPT);
        unsigned short* dwnT   = (unsigned short*)((char*)d_ws + OFF_DWNT);
        unsigned short* act    = (unsigned short*)((char*)d_ws + OFF_ACT);

        hipMemsetAsync(d_ws, 0, 4352, stream);                       // counts + zero page
        hipMemsetAsync(d_out, 0, (size_t)out_size * sizeof(float), stream);

        cvt_x_kernel<<<(TOK * HDIM) / (256 * 8), 256, 0, stream>>>(x, xbf);
        dim3 tg1(F2 / 64, HDIM / 64, NE);
        transpose_kernel<<<tg1, 256, 0, stream>>>(gup, gupT, HDIM, F2);
        dim3 tg2(HDIM / 64, NI / 64, NE);
        transpose_kernel<<<tg2, 256, 0, stream>>>(dwn, dwnT, NI, HDIM);

        router_kernel<<<TOK / 4, 256, 0, stream>>>(x, rw, counts, toks, wgts);

        int g1 = (CAP2 / 128) * (F2 / 128) * NE;     // 16*8*16 = 2048
        gemm1_kernel<<<g1, 256, 0, stream>>>(xbf, gupT, gub, counts, toks, act, zp);
        int g2 = (CAP2 / 128) * (HDIM / 128) * NE;   // 2048
        gemm2_kernel<<<g2, 256, 0, stream>>>(act, dwnT, dwb, counts, toks, wgts, out);
    } else {
        // fallback: round-1 path (~1.1 MB of ws)
        int*   counts = (int*)d_ws;
        int*   toks   = (int*)((char*)d_ws + 64);
        float* wgts   = (float*)((char*)d_ws + 64 + (size_t)NE * CAP * sizeof(int));
        hipMemsetAsync(d_ws, 0, 64, stream);
        hipMemsetAsync(d_out, 0, (size_t)out_size * sizeof(float), stream);
        router_kernel<<<TOK / 4, 256, 0, stream>>>(x, rw, counts, toks, wgts);
        dim3 gm(TOK / 64, NE);
        moe_kernel<<<gm, 256, 0, stream>>>(x, gup, gub, dwn, dwb, counts, toks, wgts, out);
    }
}

// Round 3
// 303.538 us; speedup vs baseline: 3.9017x; 1.3882x over previous
//
#include <hip/hip_runtime.h>
#include <hip/hip_bf16.h>
#include <math.h>

#define TOK   8192
#define HDIM  1024
#define NE    16
#define NI    512
#define F2    1024
#define CAP   8192
#define CAP2  2048
#define ALPHA 1.702f
#define LIMIT 7.0f

typedef __attribute__((ext_vector_type(8))) short short8;
typedef __attribute__((ext_vector_type(4))) short short4v;
typedef __attribute__((ext_vector_type(4))) float f32x4;

static __device__ __forceinline__ unsigned short f2bf(float f) {
    unsigned int u = __float_as_uint(f);
    u += 0x7FFFu + ((u >> 16) & 1u);
    return (unsigned short)(u >> 16);
}

#define GLD_LDS16(g, l) __builtin_amdgcn_global_load_lds(                     \
    (const __attribute__((address_space(1))) void*)(g),                       \
    (__attribute__((address_space(3))) void*)(l), 16, 0, 0)

// ---------------- router: LDS-staged rw, fp64 accum, top-2, fused x->bf16 ----------------
// block = 256 threads (4 waves); each wave handles 2 tokens; block handles 8 tokens.
#define RW_STRIDE 1040   // 1024 + 16 pad: 16B aligned rows, bank-minimal b128 reads

static __device__ __forceinline__ void top2_store(
    const double* acc, int t,
    int* counts, int* toks, float* wgts)
{
    int i0 = 0; double v0 = acc[0];
#pragma unroll
    for (int e = 1; e < NE; ++e) if (acc[e] > v0) { v0 = acc[e]; i0 = e; }
    int i1 = -1; double v1 = -1e300;
#pragma unroll
    for (int e = 0; e < NE; ++e) if (e != i0 && acc[e] > v1) { v1 = acc[e]; i1 = e; }
    double e1 = exp(v1 - v0);
    float w0 = (float)(1.0 / (1.0 + e1));
    float w1 = (float)(e1 / (1.0 + e1));
    int p0 = atomicAdd(&counts[i0], 1);
    toks[i0 * CAP + p0] = t; wgts[i0 * CAP + p0] = w0;
    int p1 = atomicAdd(&counts[i1], 1);
    toks[i1 * CAP + p1] = t; wgts[i1 * CAP + p1] = w1;
}

__global__ __launch_bounds__(256) void router_kernel(
    const float* __restrict__ x, const float* __restrict__ rw,
    int* __restrict__ counts, int* __restrict__ toks, float* __restrict__ wgts,
    unsigned short* __restrict__ xbf)
{
    __shared__ __align__(16) float srw[NE * RW_STRIDE];   // srw[e*RW_STRIDE + h], ~66.5 KB
    int tid = threadIdx.x;

    // cooperative load rw [1024][16] -> srw[e][h]
#pragma unroll
    for (int j = 0; j < 16; ++j) {
        int idx4 = j * 256 + tid;                 // 4096 float4 total
        float4 v = *(const float4*)(rw + (size_t)idx4 * 4);
        int h = idx4 >> 2, e0 = (idx4 & 3) * 4;
        srw[(e0 + 0) * RW_STRIDE + h] = v.x;
        srw[(e0 + 1) * RW_STRIDE + h] = v.y;
        srw[(e0 + 2) * RW_STRIDE + h] = v.z;
        srw[(e0 + 3) * RW_STRIDE + h] = v.w;
    }
    __syncthreads();

    int lane = tid & 63;
    int w = tid >> 6;
    int t0 = blockIdx.x * 8 + w * 2;              // wave handles tokens t0, t0+1

    const float* xr0 = x + (size_t)t0 * HDIM;
    const float* xr1 = xr0 + HDIM;
    double acc0[NE], acc1[NE];
#pragma unroll
    for (int e = 0; e < NE; ++e) { acc0[e] = 0.0; acc1[e] = 0.0; }

#pragma unroll
    for (int i = 0; i < 4; ++i) {
        int h0 = i * 256 + lane * 4;
        float4 xa = *(const float4*)(xr0 + h0);
        float4 xb = *(const float4*)(xr1 + h0);
        if (xbf) {
            short4v sa, sb;
            sa[0]=(short)f2bf(xa.x); sa[1]=(short)f2bf(xa.y); sa[2]=(short)f2bf(xa.z); sa[3]=(short)f2bf(xa.w);
            sb[0]=(short)f2bf(xb.x); sb[1]=(short)f2bf(xb.y); sb[2]=(short)f2bf(xb.z); sb[3]=(short)f2bf(xb.w);
            *(short4v*)(xbf + (size_t)t0 * HDIM + h0) = sa;
            *(short4v*)(xbf + (size_t)(t0 + 1) * HDIM + h0) = sb;
        }
        double xa0 = xa.x, xa1 = xa.y, xa2 = xa.z, xa3 = xa.w;
        double xb0 = xb.x, xb1 = xb.y, xb2 = xb.z, xb3 = xb.w;
#pragma unroll
        for (int e = 0; e < NE; ++e) {
            float4 wv = *(const float4*)(&srw[e * RW_STRIDE + h0]);
            double w0d = wv.x, w1d = wv.y, w2d = wv.z, w3d = wv.w;
            acc0[e] += xa0 * w0d + xa1 * w1d + xa2 * w2d + xa3 * w3d;
            acc1[e] += xb0 * w0d + xb1 * w1d + xb2 * w2d + xb3 * w3d;
        }
    }

    // butterfly reduce all 16 accs for both tokens
#pragma unroll
    for (int e = 0; e < NE; ++e) {
        double v0 = acc0[e], v1 = acc1[e];
#pragma unroll
        for (int off = 32; off > 0; off >>= 1) {
            v0 += __shfl_xor(v0, off);
            v1 += __shfl_xor(v1, off);
        }
        acc0[e] = v0; acc1[e] = v1;
    }

    if (lane == 0)      top2_store(acc0, t0,     counts, toks, wgts);
    else if (lane == 1) top2_store(acc1, t0 + 1, counts, toks, wgts);
}

// ------------- transpose + convert: in [E][R][C] fp32 -> out [E][C][R] bf16 -------------
// LDS staged as t2[c][r]; vectorized short8 output writes.
__global__ __launch_bounds__(256) void transpose_kernel(
    const float* __restrict__ in, unsigned short* __restrict__ out, int R, int C)
{
    int e = blockIdx.z;
    const float* pin = in + (size_t)e * R * C;
    unsigned short* pout = out + (size_t)e * R * C;
    __shared__ float t2[64][65];                   // [c][r]
    int c0 = blockIdx.x * 64, r0 = blockIdx.y * 64;
    int tid = threadIdx.x;

    // read 64x64 tile as float4, scatter into t2[c][r]
#pragma unroll
    for (int j = 0; j < 4; ++j) {
        int idx4 = j * 256 + tid;                  // 1024 float4
        int r = idx4 >> 4, c4 = (idx4 & 15) * 4;
        float4 v = *(const float4*)(pin + (size_t)(r0 + r) * C + c0 + c4);
        t2[c4 + 0][r] = v.x;
        t2[c4 + 1][r] = v.y;
        t2[c4 + 2][r] = v.z;
        t2[c4 + 3][r] = v.w;
    }
    __syncthreads();

    // write: thread handles 8 consecutive r (=k) for one c (=n); short8 stores
#pragma unroll
    for (int j = 0; j < 2; ++j) {
        int idx = j * 256 + tid;                   // 512 work items
        int n = idx >> 3, k0 = (idx & 7) * 8;
        short8 v;
#pragma unroll
        for (int q = 0; q < 8; ++q) v[q] = (short)f2bf(t2[n][k0 + q]);
        *(short8*)(pout + (size_t)(c0 + n) * R + r0 + k0) = v;
    }
}

// ---------------- GEMM1: x_bf (gathered) @ gupT^T + bias -> act (bf16) ----------------
__global__ __launch_bounds__(256) void gemm1_kernel(
    const unsigned short* __restrict__ xb, const unsigned short* __restrict__ gupT,
    const float* __restrict__ gub,
    const int* __restrict__ counts, const int* __restrict__ toks,
    unsigned short* __restrict__ act, const unsigned short* __restrict__ zp)
{
    int b = blockIdx.x;
    int e = b & 15;
    int j = b >> 4;
    int nt = j & 7;
    int mt = j >> 3;
    int cnt = counts[e];
    int row0 = mt * 128;
    if (row0 >= cnt) return;
    int n0 = nt * 128;

    __shared__ __align__(16) unsigned short As[128][32];
    __shared__ __align__(16) unsigned short Bs[128][32];
    __shared__ int rtok[128];

    int tid = threadIdx.x;
    int lane = tid & 63;
    int w = tid >> 6;
    int wr = w >> 1, wc = w & 1;
    int lr = lane & 15, lg = lane >> 4;

    if (tid < 128) {
        int p = row0 + tid;
        rtok[tid] = (p < cnt) ? toks[e * CAP + p] : -1;
    }
    __syncthreads();

    int srow = lane >> 2;
    int scol = (lane & 3) * 8;
    const unsigned short* gaA[2];
    const unsigned short* gaB[2];
    const unsigned short* gupE = gupT + (size_t)e * HDIM * F2;
#pragma unroll
    for (int i = 0; i < 2; ++i) {
        int arow = w * 32 + i * 16 + srow;
        int tk = rtok[arow];
        gaA[i] = (tk >= 0) ? (xb + (size_t)tk * HDIM + scol) : (zp + scol);
        int brow = n0 + w * 32 + i * 16 + srow;
        gaB[i] = gupE + (size_t)brow * HDIM + scol;
    }

    f32x4 acc[4][4];
#pragma unroll
    for (int m = 0; m < 4; ++m)
#pragma unroll
        for (int n = 0; n < 4; ++n) acc[m][n] = (f32x4){0.f, 0.f, 0.f, 0.f};

    for (int kb = 0; kb < HDIM / 32; ++kb) {
#pragma unroll
        for (int i = 0; i < 2; ++i) {
            GLD_LDS16(gaA[i] + kb * 32, &As[w * 32 + i * 16][0]);
            GLD_LDS16(gaB[i] + kb * 32, &Bs[w * 32 + i * 16][0]);
        }
        __syncthreads();
        short8 af[4], bfr[4];
#pragma unroll
        for (int m = 0; m < 4; ++m) af[m] = *(const short8*)&As[wr * 64 + m * 16 + lr][lg * 8];
#pragma unroll
        for (int n = 0; n < 4; ++n) bfr[n] = *(const short8*)&Bs[wc * 64 + n * 16 + lr][lg * 8];
#pragma unroll
        for (int m = 0; m < 4; ++m)
#pragma unroll
            for (int n = 0; n < 4; ++n)
                acc[m][n] = __builtin_amdgcn_mfma_f32_16x16x32_bf16(af[m], bfr[n], acc[m][n], 0, 0, 0);
        __syncthreads();
    }

    unsigned short* actE = act + (size_t)e * CAP2 * NI;
#pragma unroll
    for (int n = 0; n < 4; ++n) {
        int fc = n0 + wc * 64 + n * 16 + lr;
        float bias = gub[e * F2 + fc];
#pragma unroll
        for (int m = 0; m < 4; ++m) {
#pragma unroll
            for (int r = 0; r < 4; ++r) {
                float gu = acc[m][n][r] + bias;
                float other = __shfl_xor(gu, 1);
                float gate = (lr & 1) ? other : gu;
                float up   = (lr & 1) ? gu    : other;
                gate = fminf(gate, LIMIT);
                up   = fminf(fmaxf(up, -LIMIT), LIMIT);
                float glu = gate / (1.0f + __expf(-ALPHA * gate));
                float av  = (up + 1.0f) * glu;
                if (!(lr & 1)) {
                    int row = row0 + wr * 64 + m * 16 + lg * 4 + r;
                    actE[(size_t)row * NI + (fc >> 1)] = f2bf(av);
                }
            }
        }
    }
}

// ---------------- GEMM2: act @ dwnT^T, *score, +bias, scatter-add ----------------
__global__ __launch_bounds__(256) void gemm2_kernel(
    const unsigned short* __restrict__ act, const unsigned short* __restrict__ dwnT,
    const float* __restrict__ dwb,
    const int* __restrict__ counts, const int* __restrict__ toks,
    const float* __restrict__ wgts, float* __restrict__ out)
{
    int b = blockIdx.x;
    int e = b & 15;
    int j = b >> 4;
    int nt = j & 7;
    int mt = j >> 3;
    int cnt = counts[e];
    int row0 = mt * 128;
    if (row0 >= cnt) return;
    int n0 = nt * 128;

    __shared__ __align__(16) unsigned short As[128][32];
    __shared__ __align__(16) unsigned short Bs[128][32];
    __shared__ int   rtok[128];
    __shared__ float rwgt[128];

    int tid = threadIdx.x;
    int lane = tid & 63;
    int w = tid >> 6;
    int wr = w >> 1, wc = w & 1;
    int lr = lane & 15, lg = lane >> 4;

    if (tid < 128) {
        int p = row0 + tid;
        bool v = p < cnt;
        rtok[tid] = v ? toks[e * CAP + p] : -1;
        rwgt[tid] = v ? wgts[e * CAP + p] : 0.0f;
    }
    __syncthreads();

    int srow = lane >> 2;
    int scol = (lane & 3) * 8;
    const unsigned short* gaA[2];
    const unsigned short* gaB[2];
    const unsigned short* actE = act + (size_t)e * CAP2 * NI;
    const unsigned short* dwnE = dwnT + (size_t)e * HDIM * NI;
#pragma unroll
    for (int i = 0; i < 2; ++i) {
        int arow = row0 + w * 32 + i * 16 + srow;
        gaA[i] = actE + (size_t)arow * NI + scol;
        int brow = n0 + w * 32 + i * 16 + srow;
        gaB[i] = dwnE + (size_t)brow * NI + scol;
    }

    f32x4 acc[4][4];
#pragma unroll
    for (int m = 0; m < 4; ++m)
#pragma unroll
        for (int n = 0; n < 4; ++n) acc[m][n] = (f32x4){0.f, 0.f, 0.f, 0.f};

    for (int kb = 0; kb < NI / 32; ++kb) {
#pragma unroll
        for (int i = 0; i < 2; ++i) {
            GLD_LDS16(gaA[i] + kb * 32, &As[w * 32 + i * 16][0]);
            GLD_LDS16(gaB[i] + kb * 32, &Bs[w * 32 + i * 16][0]);
        }
        __syncthreads();
        short8 af[4], bfr[4];
#pragma unroll
        for (int m = 0; m < 4; ++m) af[m] = *(const short8*)&As[wr * 64 + m * 16 + lr][lg * 8];
#pragma unroll
        for (int n = 0; n < 4; ++n) bfr[n] = *(const short8*)&Bs[wc * 64 + n * 16 + lr][lg * 8];
#pragma unroll
        for (int m = 0; m < 4; ++m)
#pragma unroll
            for (int n = 0; n < 4; ++n)
                acc[m][n] = __builtin_amdgcn_mfma_f32_16x16x32_bf16(af[m], bfr[n], acc[m][n], 0, 0, 0);
        __syncthreads();
    }

#pragma unroll
    for (int n = 0; n < 4; ++n) {
        int hc = n0 + wc * 64 + n * 16 + lr;
        float db = dwb[e * HDIM + hc];
#pragma unroll
        for (int m = 0; m < 4; ++m) {
#pragma unroll
            for (int r = 0; r < 4; ++r) {
                int row = wr * 64 + m * 16 + lg * 4 + r;
                int tk = rtok[row];
                if (tk >= 0)
                    atomicAdd(out + (size_t)tk * HDIM + hc,
                              rwgt[row] * (acc[m][n][r] + db));
            }
        }
    }
}

// ================= fallback (round-1) expert kernel, used if ws too small =================
__global__ __launch_bounds__(256) void moe_kernel(
    const float* __restrict__ x,
    const float* __restrict__ gup, const float* __restrict__ gub,
    const float* __restrict__ dwn, const float* __restrict__ dwb,
    const int* __restrict__ counts, const int* __restrict__ toks,
    const float* __restrict__ wgts, float* __restrict__ out)
{
    int e = blockIdx.y;
    int cnt = counts[e];
    int row0 = blockIdx.x * 64;
    if (row0 >= cnt) return;

    __shared__ __align__(16) unsigned short sA[64][40];
    __shared__ __align__(16) unsigned short sB[64][40];
    __shared__ __align__(16) unsigned short sAct[64][520];
    __shared__ int   rtok[64];
    __shared__ float rwgt[64];

    int tid = threadIdx.x;
    if (tid < 64) {
        int idx = row0 + tid;
        bool v = idx < cnt;
        rtok[tid] = v ? toks[e * CAP + idx] : -1;
        rwgt[tid] = v ? wgts[e * CAP + idx] : 0.0f;
    }
    __syncthreads();

    int lane = tid & 63;
    int w = tid >> 6;
    int wr = w >> 1, wc = w & 1;
    int lr = lane & 15, lg = lane >> 4;
    int ar = tid >> 2, ac0 = (tid & 3) * 8;
    int bk = tid >> 3, bf0 = (tid & 7) * 8;
    const float* gupE = gup + (size_t)e * HDIM * F2;

    for (int nb = 0; nb < F2 / 64; ++nb) {
        f32x4 acc[2][2];
#pragma unroll
        for (int mi = 0; mi < 2; ++mi)
#pragma unroll
            for (int ni = 0; ni < 2; ++ni) acc[mi][ni] = (f32x4){0.f, 0.f, 0.f, 0.f};
        for (int kb = 0; kb < HDIM / 32; ++kb) {
            __syncthreads();
            {
                int tk = rtok[ar];
                short8 vv = {0,0,0,0,0,0,0,0};
                if (tk >= 0) {
                    const float* p = x + (size_t)tk * HDIM + kb * 32 + ac0;
                    float4 u0 = *(const float4*)(p); float4 u1 = *(const float4*)(p + 4);
                    vv[0]=(short)f2bf(u0.x); vv[1]=(short)f2bf(u0.y); vv[2]=(short)f2bf(u0.z); vv[3]=(short)f2bf(u0.w);
                    vv[4]=(short)f2bf(u1.x); vv[5]=(short)f2bf(u1.y); vv[6]=(short)f2bf(u1.z); vv[7]=(short)f2bf(u1.w);
                }
                *(short8*)&sA[ar][ac0] = vv;
            }
            {
                const float* p = gupE + (size_t)(kb * 32 + bk) * F2 + nb * 64 + bf0;
                float4 u0 = *(const float4*)(p); float4 u1 = *(const float4*)(p + 4);
                sB[bf0+0][bk]=f2bf(u0.x); sB[bf0+1][bk]=f2bf(u0.y); sB[bf0+2][bk]=f2bf(u0.z); sB[bf0+3][bk]=f2bf(u0.w);
                sB[bf0+4][bk]=f2bf(u1.x); sB[bf0+5][bk]=f2bf(u1.y); sB[bf0+6][bk]=f2bf(u1.z); sB[bf0+7][bk]=f2bf(u1.w);
            }
            __syncthreads();
            short8 a0 = *(const short8*)&sA[wr*32+lr][lg*8];
            short8 a1 = *(const short8*)&sA[wr*32+16+lr][lg*8];
            short8 b0 = *(const short8*)&sB[wc*32+lr][lg*8];
            short8 b1 = *(const short8*)&sB[wc*32+16+lr][lg*8];
            acc[0][0] = __builtin_amdgcn_mfma_f32_16x16x32_bf16(a0,b0,acc[0][0],0,0,0);
            acc[0][1] = __builtin_amdgcn_mfma_f32_16x16x32_bf16(a0,b1,acc[0][1],0,0,0);
            acc[1][0] = __builtin_amdgcn_mfma_f32_16x16x32_bf16(a1,b0,acc[1][0],0,0,0);
            acc[1][1] = __builtin_amdgcn_mfma_f32_16x16x32_bf16(a1,b1,acc[1][1],0,0,0);
        }
#pragma unroll
        for (int ni = 0; ni < 2; ++ni) {
            int fc = nb * 64 + wc * 32 + ni * 16 + lr;
            float bias = gub[e * F2 + fc];
#pragma unroll
            for (int mi = 0; mi < 2; ++mi)
#pragma unroll
                for (int r = 0; r < 4; ++r) {
                    float gu = acc[mi][ni][r] + bias;
                    float other = __shfl_xor(gu, 1);
                    float gate = (lr & 1) ? other : gu;
                    float up   = (lr & 1) ? gu : other;
                    gate = fminf(gate, LIMIT);
                    up = fminf(fmaxf(up, -LIMIT), LIMIT);
                    float glu = gate / (1.0f + __expf(-ALPHA * gate));
                    float av = (up + 1.0f) * glu;
                    if (!(lr & 1)) sAct[wr*32+mi*16+lg*4+r][fc >> 1] = f2bf(av);
                }
        }
    }
    __syncthreads();

    const float* dwnE = dwn + (size_t)e * NI * HDIM;
    int tks[2][4]; float wvs[2][4];
#pragma unroll
    for (int mi = 0; mi < 2; ++mi)
#pragma unroll
        for (int r = 0; r < 4; ++r) {
            int row = wr*32 + mi*16 + lg*4 + r;
            tks[mi][r] = rtok[row]; wvs[mi][r] = rwgt[row];
        }
    for (int nb = 0; nb < HDIM / 64; ++nb) {
        f32x4 acc[2][2];
#pragma unroll
        for (int mi = 0; mi < 2; ++mi)
#pragma unroll
            for (int ni = 0; ni < 2; ++ni) acc[mi][ni] = (f32x4){0.f,0.f,0.f,0.f};
        for (int kb = 0; kb < NI / 32; ++kb) {
            __syncthreads();
            {
                const float* p = dwnE + (size_t)(kb*32 + bk) * HDIM + nb*64 + bf0;
                float4 u0 = *(const float4*)(p); float4 u1 = *(const float4*)(p + 4);
                sB[bf0+0][bk]=f2bf(u0.x); sB[bf0+1][bk]=f2bf(u0.y); sB[bf0+2][bk]=f2bf(u0.z); sB[bf0+3][bk]=f2bf(u0.w);
                sB[bf0+4][bk]=f2bf(u1.x); sB[bf0+5][bk]=f2bf(u1.y); sB[bf0+6][bk]=f2bf(u1.z); sB[bf0+7][bk]=f2bf(u1.w);
            }
            __syncthreads();
            short8 a0 = *(const short8*)&sAct[wr*32+lr][kb*32+lg*8];
            short8 a1 = *(const short8*)&sAct[wr*32+16+lr][kb*32+lg*8];
            short8 b0 = *(const short8*)&sB[wc*32+lr][lg*8];
            short8 b1 = *(const short8*)&sB[wc*32+16+lr][lg*8];
            acc[0][0] = __builtin_amdgcn_mfma_f32_16x16x32_bf16(a0,b0,acc[0][0],0,0,0);
            acc[0][1] = __builtin_amdgcn_mfma_f32_16x16x32_bf16(a0,b1,acc[0][1],0,0,0);
            acc[1][0] = __builtin_amdgcn_mfma_f32_16x16x32_bf16(a1,b0,acc[1][0],0,0,0);
            acc[1][1] = __builtin_amdgcn_mfma_f32_16x16x32_bf16(a1,b1,acc[1][1],0,0,0);
        }
#pragma unroll
        for (int ni = 0; ni < 2; ++ni) {
            int hc = nb*64 + wc*32 + ni*16 + lr;
            float db = dwb[e * HDIM + hc];
#pragma unroll
            for (int mi = 0; mi < 2; ++mi)
#pragma unroll
                for (int r = 0; r < 4; ++r) {
                    int tk = tks[mi][r];
                    if (tk >= 0)
                        atomicAdd(out + (size_t)tk * HDIM + hc, wvs[mi][r] * (acc[mi][ni][r] + db));
                }
        }
    }
}

extern "C" void kernel_launch(void* const* d_in, const int* in_sizes, int n_in,
                              void* d_out, int out_size, void* d_ws, size_t ws_size,
                              hipStream_t stream) {
    const float* x   = (const float*)d_in[0];
    const float* rw  = (const float*)d_in[1];
    const float* gup = (const float*)d_in[2];
    const float* gub = (const float*)d_in[3];
    const float* dwn = (const float*)d_in[4];
    const float* dwb = (const float*)d_in[5];
    float* out = (float*)d_out;

    // ---- new-path ws layout ----
    const size_t OFF_COUNTS = 0;                 // 256 B
    const size_t OFF_ZP     = 256;               // 4 KB zero page
    const size_t OFF_TOKS   = 4352;
    const size_t OFF_WGTS   = OFF_TOKS + (size_t)NE * CAP * 4;
    const size_t OFF_XBF    = OFF_WGTS + (size_t)NE * CAP * 4;
    const size_t OFF_GUPT   = OFF_XBF  + (size_t)TOK * HDIM * 2;
    const size_t OFF_DWNT   = OFF_GUPT + (size_t)NE * HDIM * F2 * 2;
    const size_t OFF_ACT    = OFF_DWNT + (size_t)NE * NI * HDIM * 2;
    const size_t REQ        = OFF_ACT  + (size_t)NE * CAP2 * NI * 2;

    if (ws_size >= REQ) {
        int*            counts = (int*)((char*)d_ws + OFF_COUNTS);
        unsigned short* zp     = (unsigned short*)((char*)d_ws + OFF_ZP);
        int*            toks   = (int*)((char*)d_ws + OFF_TOKS);
        float*          wgts   = (float*)((char*)d_ws + OFF_WGTS);
        unsigned short* xbf    = (unsigned short*)((char*)d_ws + OFF_XBF);
        unsigned short* gupT   = (unsigned short*)((char*)d_ws + OFF_GUPT);
        unsigned short* dwnT   = (unsigned short*)((char*)d_ws + OFF_DWNT);
        unsigned short* act    = (unsigned short*)((char*)d_ws + OFF_ACT);

        hipMemsetAsync(d_ws, 0, 4352, stream);                       // counts + zero page
        hipMemsetAsync(d_out, 0, (size_t)out_size * sizeof(float), stream);

        dim3 tg1(F2 / 64, HDIM / 64, NE);
        transpose_kernel<<<tg1, 256, 0, stream>>>(gup, gupT, HDIM, F2);
        dim3 tg2(HDIM / 64, NI / 64, NE);
        transpose_kernel<<<tg2, 256, 0, stream>>>(dwn, dwnT, NI, HDIM);

        router_kernel<<<TOK / 8, 256, 0, stream>>>(x, rw, counts, toks, wgts, xbf);

        int g1 = (CAP2 / 128) * (F2 / 128) * NE;     // 2048
        gemm1_kernel<<<g1, 256, 0, stream>>>(xbf, gupT, gub, counts, toks, act, zp);
        int g2 = (CAP2 / 128) * (HDIM / 128) * NE;   // 2048
        gemm2_kernel<<<g2, 256, 0, stream>>>(act, dwnT, dwb, counts, toks, wgts, out);
    } else {
        // fallback: round-1 path (~1.1 MB of ws)
        int*   counts = (int*)d_ws;
        int*   toks   = (int*)((char*)d_ws + 64);
        float* wgts   = (float*)((char*)d_ws + 64 + (size_t)NE * CAP * sizeof(int));
        hipMemsetAsync(d_ws, 0, 64, stream);
        hipMemsetAsync(d_out, 0, (size_t)out_size * sizeof(float), stream);
        router_kernel<<<TOK / 8, 256, 0, stream>>>(x, rw, counts, toks, wgts, (unsigned short*)nullptr);
        dim3 gm(TOK / 64, NE);
        moe_kernel<<<gm, 256, 0, stream>>>(x, gup, gub, dwn, dwb, counts, toks, wgts, out);
    }
}

// Round 4
// 230.526 us; speedup vs baseline: 5.1375x; 1.3167x over previous
//
#include <hip/hip_runtime.h>
#include <hip/hip_bf16.h>
#include <math.h>

#define TOK   8192
#define HDIM  1024
#define NE    16
#define NI    512
#define F2    1024
#define CAP   8192
#define CAP2  2048
#define ALPHA 1.702f
#define LIMIT 7.0f

typedef __attribute__((ext_vector_type(8))) short short8;
typedef __attribute__((ext_vector_type(4))) short short4v;
typedef __attribute__((ext_vector_type(4))) float f32x4;

static __device__ __forceinline__ unsigned short f2bf(float f) {
    unsigned int u = __float_as_uint(f);
    u += 0x7FFFu + ((u >> 16) & 1u);
    return (unsigned short)(u >> 16);
}

#define GLD_LDS16(g, l) __builtin_amdgcn_global_load_lds(                     \
    (const __attribute__((address_space(1))) void*)(g),                       \
    (__attribute__((address_space(3))) void*)(l), 16, 0, 0)

// ================= router phase A: fp64 partial logits, fused x->bf16 =================
// grid = 512 token-tiles(16 tok) x 4 K-slices(256 h); block = 1 wave (64 thr).
// lane = (tt = lane&15, eg = lane>>4); acc[4] fp64 per lane; NO cross-lane reduction.
// partials: part[ksl*16 + e][TOK] fp64 (lives in the idle `act` ws region).
__global__ __launch_bounds__(64) void router_partial_kernel(
    const float* __restrict__ x, const float* __restrict__ rw,
    double* __restrict__ part, unsigned short* __restrict__ xbf)
{
    int bx = blockIdx.x;
    int tile = bx >> 2, ksl = bx & 3;
    int t0 = tile * 16;
    int hbase = ksl * 256;

    __shared__ __align__(16) float sx[16][68];
    __shared__ __align__(16) float srw[64][16];

    int lane = threadIdx.x;
    int tt = lane & 15, eg = lane >> 4;

    double acc[4] = {0.0, 0.0, 0.0, 0.0};

    for (int hc = 0; hc < 4; ++hc) {
        int h0 = hbase + hc * 64;
        __syncthreads();   // protect previous chunk's LDS from overwrite
        // stage x tile 16x64 (+ fused bf16 cast-out)
#pragma unroll
        for (int j = 0; j < 4; ++j) {
            int fidx = j * 64 + lane;
            int t = fidx >> 4, c4 = (fidx & 15) * 4;
            float4 v = *(const float4*)(x + (size_t)(t0 + t) * HDIM + h0 + c4);
            *(float4*)&sx[t][c4] = v;
            short4v s;
            s[0] = (short)f2bf(v.x); s[1] = (short)f2bf(v.y);
            s[2] = (short)f2bf(v.z); s[3] = (short)f2bf(v.w);
            *(short4v*)(xbf + (size_t)(t0 + t) * HDIM + h0 + c4) = s;
        }
        // stage rw chunk 64x16
#pragma unroll
        for (int j = 0; j < 4; ++j) {
            int ridx = j * 64 + lane;
            int h = ridx >> 2, e4 = (ridx & 3) * 4;
            float4 v = *(const float4*)(rw + (size_t)(h0 + h) * NE + e4);
            *(float4*)&srw[h][e4] = v;
        }
        __syncthreads();
#pragma unroll 8
        for (int j = 0; j < 64; ++j) {
            float xv = sx[tt][j];
            float4 wv = *(const float4*)&srw[j][eg * 4];
            double xd = (double)xv;
            acc[0] += xd * (double)wv.x;
            acc[1] += xd * (double)wv.y;
            acc[2] += xd * (double)wv.z;
            acc[3] += xd * (double)wv.w;
        }
    }
#pragma unroll
    for (int q = 0; q < 4; ++q)
        part[(size_t)(ksl * NE + eg * 4 + q) * TOK + t0 + tt] = acc[q];
}

// ================= router phase B: combine, top-2, softmax, aggregated scatter =================
__global__ __launch_bounds__(256) void router_combine_kernel(
    const double* __restrict__ part,
    int* __restrict__ counts, int* __restrict__ toks, float* __restrict__ wgts)
{
    __shared__ int lhist[NE];
    __shared__ int lbase[NE];
    int tid = threadIdx.x;
    int t = blockIdx.x * 256 + tid;
    if (tid < NE) lhist[tid] = 0;
    __syncthreads();

    double acc[NE];
#pragma unroll
    for (int e = 0; e < NE; ++e)
        acc[e] = part[(size_t)(0 * NE + e) * TOK + t]
               + part[(size_t)(1 * NE + e) * TOK + t]
               + part[(size_t)(2 * NE + e) * TOK + t]
               + part[(size_t)(3 * NE + e) * TOK + t];

    int i0 = 0; double v0 = acc[0];
#pragma unroll
    for (int e = 1; e < NE; ++e) if (acc[e] > v0) { v0 = acc[e]; i0 = e; }
    int i1 = -1; double v1 = -1e300;
#pragma unroll
    for (int e = 0; e < NE; ++e) if (e != i0 && acc[e] > v1) { v1 = acc[e]; i1 = e; }
    double e1 = exp(v1 - v0);
    float w0 = (float)(1.0 / (1.0 + e1));
    float w1 = (float)(e1 / (1.0 + e1));

    int r0 = atomicAdd(&lhist[i0], 1);
    int r1 = atomicAdd(&lhist[i1], 1);
    __syncthreads();
    if (tid < NE) lbase[tid] = atomicAdd(&counts[tid], lhist[tid]);
    __syncthreads();
    int p0 = lbase[i0] + r0;
    toks[i0 * CAP + p0] = t; wgts[i0 * CAP + p0] = w0;
    int p1 = lbase[i1] + r1;
    toks[i1 * CAP + p1] = t; wgts[i1 * CAP + p1] = w1;
}

// ------------- transpose + convert: in [E][R][C] fp32 -> out [E][C][R] bf16 -------------
__global__ __launch_bounds__(256) void transpose_kernel(
    const float* __restrict__ in, unsigned short* __restrict__ out, int R, int C)
{
    int e = blockIdx.z;
    const float* pin = in + (size_t)e * R * C;
    unsigned short* pout = out + (size_t)e * R * C;
    __shared__ float t2[64][65];                   // [c][r]
    int c0 = blockIdx.x * 64, r0 = blockIdx.y * 64;
    int tid = threadIdx.x;
#pragma unroll
    for (int j = 0; j < 4; ++j) {
        int idx4 = j * 256 + tid;
        int r = idx4 >> 4, c4 = (idx4 & 15) * 4;
        float4 v = *(const float4*)(pin + (size_t)(r0 + r) * C + c0 + c4);
        t2[c4 + 0][r] = v.x;
        t2[c4 + 1][r] = v.y;
        t2[c4 + 2][r] = v.z;
        t2[c4 + 3][r] = v.w;
    }
    __syncthreads();
#pragma unroll
    for (int j = 0; j < 2; ++j) {
        int idx = j * 256 + tid;
        int n = idx >> 3, k0 = (idx & 7) * 8;
        short8 v;
#pragma unroll
        for (int q = 0; q < 8; ++q) v[q] = (short)f2bf(t2[n][k0 + q]);
        *(short8*)(pout + (size_t)(c0 + n) * R + r0 + k0) = v;
    }
}

// ---------------- GEMM1: x_bf (gathered) @ gupT^T + bias -> act (bf16); 2-phase dbuf ----------------
__global__ __launch_bounds__(256) void gemm1_kernel(
    const unsigned short* __restrict__ xb, const unsigned short* __restrict__ gupT,
    const float* __restrict__ gub,
    const int* __restrict__ counts, const int* __restrict__ toks,
    unsigned short* __restrict__ act, const unsigned short* __restrict__ zp)
{
    int b = blockIdx.x;
    int e = b & 15;
    int j = b >> 4;
    int nt = j & 7;
    int mt = j >> 3;
    int cnt = counts[e];
    int row0 = mt * 128;
    if (row0 >= cnt) return;
    int n0 = nt * 128;

    __shared__ __align__(16) unsigned short As[2][128][32];
    __shared__ __align__(16) unsigned short Bs[2][128][32];
    __shared__ int rtok[128];

    int tid = threadIdx.x;
    int lane = tid & 63;
    int w = tid >> 6;
    int wr = w >> 1, wc = w & 1;
    int lr = lane & 15, lg = lane >> 4;

    if (tid < 128) {
        int p = row0 + tid;
        rtok[tid] = (p < cnt) ? toks[e * CAP + p] : -1;
    }
    __syncthreads();

    int srow = lane >> 2;
    int scol = (lane & 3) * 8;
    const unsigned short* gaA[2];
    const unsigned short* gaB[2];
    const unsigned short* gupE = gupT + (size_t)e * HDIM * F2;
#pragma unroll
    for (int i = 0; i < 2; ++i) {
        int arow = w * 32 + i * 16 + srow;
        int tk = rtok[arow];
        gaA[i] = (tk >= 0) ? (xb + (size_t)tk * HDIM + scol) : (zp + scol);
        int brow = n0 + w * 32 + i * 16 + srow;
        gaB[i] = gupE + (size_t)brow * HDIM + scol;
    }

    f32x4 acc[4][4];
#pragma unroll
    for (int m = 0; m < 4; ++m)
#pragma unroll
        for (int n = 0; n < 4; ++n) acc[m][n] = (f32x4){0.f, 0.f, 0.f, 0.f};

    const int NT = HDIM / 32;
    // prologue: stage tile 0 into buf 0
#pragma unroll
    for (int i = 0; i < 2; ++i) {
        GLD_LDS16(gaA[i], &As[0][w * 32 + i * 16][0]);
        GLD_LDS16(gaB[i], &Bs[0][w * 32 + i * 16][0]);
    }
    __syncthreads();

    int cur = 0;
    for (int kb = 0; kb < NT; ++kb) {
        if (kb + 1 < NT) {
#pragma unroll
            for (int i = 0; i < 2; ++i) {
                GLD_LDS16(gaA[i] + (kb + 1) * 32, &As[cur ^ 1][w * 32 + i * 16][0]);
                GLD_LDS16(gaB[i] + (kb + 1) * 32, &Bs[cur ^ 1][w * 32 + i * 16][0]);
            }
        }
        short8 af[4], bfr[4];
#pragma unroll
        for (int m = 0; m < 4; ++m) af[m] = *(const short8*)&As[cur][wr * 64 + m * 16 + lr][lg * 8];
#pragma unroll
        for (int n = 0; n < 4; ++n) bfr[n] = *(const short8*)&Bs[cur][wc * 64 + n * 16 + lr][lg * 8];
#pragma unroll
        for (int m = 0; m < 4; ++m)
#pragma unroll
            for (int n = 0; n < 4; ++n)
                acc[m][n] = __builtin_amdgcn_mfma_f32_16x16x32_bf16(af[m], bfr[n], acc[m][n], 0, 0, 0);
        __syncthreads();   // drains vmcnt(0): next tile landed; all reads of cur done
        cur ^= 1;
    }

    unsigned short* actE = act + (size_t)e * CAP2 * NI;
#pragma unroll
    for (int n = 0; n < 4; ++n) {
        int fc = n0 + wc * 64 + n * 16 + lr;
        float bias = gub[e * F2 + fc];
#pragma unroll
        for (int m = 0; m < 4; ++m) {
#pragma unroll
            for (int r = 0; r < 4; ++r) {
                float gu = acc[m][n][r] + bias;
                float other = __shfl_xor(gu, 1);
                float gate = (lr & 1) ? other : gu;
                float up   = (lr & 1) ? gu    : other;
                gate = fminf(gate, LIMIT);
                up   = fminf(fmaxf(up, -LIMIT), LIMIT);
                float glu = gate / (1.0f + __expf(-ALPHA * gate));
                float av  = (up + 1.0f) * glu;
                if (!(lr & 1)) {
                    int row = row0 + wr * 64 + m * 16 + lg * 4 + r;
                    actE[(size_t)row * NI + (fc >> 1)] = f2bf(av);
                }
            }
        }
    }
}

// ---------------- GEMM2: act @ dwnT^T, *score, +bias, scatter-add; 2-phase dbuf ----------------
__global__ __launch_bounds__(256) void gemm2_kernel(
    const unsigned short* __restrict__ act, const unsigned short* __restrict__ dwnT,
    const float* __restrict__ dwb,
    const int* __restrict__ counts, const int* __restrict__ toks,
    const float* __restrict__ wgts, float* __restrict__ out)
{
    int b = blockIdx.x;
    int e = b & 15;
    int j = b >> 4;
    int nt = j & 7;
    int mt = j >> 3;
    int cnt = counts[e];
    int row0 = mt * 128;
    if (row0 >= cnt) return;
    int n0 = nt * 128;

    __shared__ __align__(16) unsigned short As[2][128][32];
    __shared__ __align__(16) unsigned short Bs[2][128][32];
    __shared__ int   rtok[128];
    __shared__ float rwgt[128];

    int tid = threadIdx.x;
    int lane = tid & 63;
    int w = tid >> 6;
    int wr = w >> 1, wc = w & 1;
    int lr = lane & 15, lg = lane >> 4;

    if (tid < 128) {
        int p = row0 + tid;
        bool v = p < cnt;
        rtok[tid] = v ? toks[e * CAP + p] : -1;
        rwgt[tid] = v ? wgts[e * CAP + p] : 0.0f;
    }
    __syncthreads();

    int srow = lane >> 2;
    int scol = (lane & 3) * 8;
    const unsigned short* gaA[2];
    const unsigned short* gaB[2];
    const unsigned short* actE = act + (size_t)e * CAP2 * NI;
    const unsigned short* dwnE = dwnT + (size_t)e * HDIM * NI;
#pragma unroll
    for (int i = 0; i < 2; ++i) {
        int arow = row0 + w * 32 + i * 16 + srow;
        gaA[i] = actE + (size_t)arow * NI + scol;
        int brow = n0 + w * 32 + i * 16 + srow;
        gaB[i] = dwnE + (size_t)brow * NI + scol;
    }

    f32x4 acc[4][4];
#pragma unroll
    for (int m = 0; m < 4; ++m)
#pragma unroll
        for (int n = 0; n < 4; ++n) acc[m][n] = (f32x4){0.f, 0.f, 0.f, 0.f};

    const int NT = NI / 32;
#pragma unroll
    for (int i = 0; i < 2; ++i) {
        GLD_LDS16(gaA[i], &As[0][w * 32 + i * 16][0]);
        GLD_LDS16(gaB[i], &Bs[0][w * 32 + i * 16][0]);
    }
    __syncthreads();

    int cur = 0;
    for (int kb = 0; kb < NT; ++kb) {
        if (kb + 1 < NT) {
#pragma unroll
            for (int i = 0; i < 2; ++i) {
                GLD_LDS16(gaA[i] + (kb + 1) * 32, &As[cur ^ 1][w * 32 + i * 16][0]);
                GLD_LDS16(gaB[i] + (kb + 1) * 32, &Bs[cur ^ 1][w * 32 + i * 16][0]);
            }
        }
        short8 af[4], bfr[4];
#pragma unroll
        for (int m = 0; m < 4; ++m) af[m] = *(const short8*)&As[cur][wr * 64 + m * 16 + lr][lg * 8];
#pragma unroll
        for (int n = 0; n < 4; ++n) bfr[n] = *(const short8*)&Bs[cur][wc * 64 + n * 16 + lr][lg * 8];
#pragma unroll
        for (int m = 0; m < 4; ++m)
#pragma unroll
            for (int n = 0; n < 4; ++n)
                acc[m][n] = __builtin_amdgcn_mfma_f32_16x16x32_bf16(af[m], bfr[n], acc[m][n], 0, 0, 0);
        __syncthreads();
        cur ^= 1;
    }

#pragma unroll
    for (int n = 0; n < 4; ++n) {
        int hc = n0 + wc * 64 + n * 16 + lr;
        float db = dwb[e * HDIM + hc];
#pragma unroll
        for (int m = 0; m < 4; ++m) {
#pragma unroll
            for (int r = 0; r < 4; ++r) {
                int row = wr * 64 + m * 16 + lg * 4 + r;
                int tk = rtok[row];
                if (tk >= 0)
                    atomicAdd(out + (size_t)tk * HDIM + hc,
                              rwgt[row] * (acc[m][n][r] + db));
            }
        }
    }
}

// ================= fallback path kernels (round-1 style, small ws) =================
__global__ __launch_bounds__(256) void router_kernel(
    const float* __restrict__ x, const float* __restrict__ rw,
    int* __restrict__ counts, int* __restrict__ toks, float* __restrict__ wgts)
{
    int gwave = (int)((blockIdx.x * 256 + threadIdx.x) >> 6);
    int lane = threadIdx.x & 63;
    if (gwave >= TOK) return;
    const float* xr = x + (size_t)gwave * HDIM;
    double acc[NE];
#pragma unroll
    for (int e = 0; e < NE; ++e) acc[e] = 0.0;
    for (int i = 0; i < HDIM / 64; ++i) {
        int h = i * 64 + lane;
        double xv = (double)xr[h];
        const float* r = rw + (size_t)h * NE;
#pragma unroll
        for (int e = 0; e < NE; ++e) acc[e] += xv * (double)r[e];
    }
#pragma unroll
    for (int e = 0; e < NE; ++e) {
        double v = acc[e];
#pragma unroll
        for (int off = 32; off > 0; off >>= 1) v += __shfl_xor(v, off);
        acc[e] = v;
    }
    if (lane == 0) {
        int i0 = 0; double v0 = acc[0];
#pragma unroll
        for (int e = 1; e < NE; ++e) if (acc[e] > v0) { v0 = acc[e]; i0 = e; }
        int i1 = -1; double v1 = -1e300;
#pragma unroll
        for (int e = 0; e < NE; ++e) if (e != i0 && acc[e] > v1) { v1 = acc[e]; i1 = e; }
        double e1 = exp(v1 - v0);
        float w0 = (float)(1.0 / (1.0 + e1));
        float w1 = (float)(e1 / (1.0 + e1));
        int p0 = atomicAdd(&counts[i0], 1);
        toks[i0 * CAP + p0] = gwave; wgts[i0 * CAP + p0] = w0;
        int p1 = atomicAdd(&counts[i1], 1);
        toks[i1 * CAP + p1] = gwave; wgts[i1 * CAP + p1] = w1;
    }
}

__global__ __launch_bounds__(256) void moe_kernel(
    const float* __restrict__ x,
    const float* __restrict__ gup, const float* __restrict__ gub,
    const float* __restrict__ dwn, const float* __restrict__ dwb,
    const int* __restrict__ counts, const int* __restrict__ toks,
    const float* __restrict__ wgts, float* __restrict__ out)
{
    int e = blockIdx.y;
    int cnt = counts[e];
    int row0 = blockIdx.x * 64;
    if (row0 >= cnt) return;

    __shared__ __align__(16) unsigned short sA[64][40];
    __shared__ __align__(16) unsigned short sB[64][40];
    __shared__ __align__(16) unsigned short sAct[64][520];
    __shared__ int   rtok[64];
    __shared__ float rwgt[64];

    int tid = threadIdx.x;
    if (tid < 64) {
        int idx = row0 + tid;
        bool v = idx < cnt;
        rtok[tid] = v ? toks[e * CAP + idx] : -1;
        rwgt[tid] = v ? wgts[e * CAP + idx] : 0.0f;
    }
    __syncthreads();

    int lane = tid & 63;
    int w = tid >> 6;
    int wr = w >> 1, wc = w & 1;
    int lr = lane & 15, lg = lane >> 4;
    int ar = tid >> 2, ac0 = (tid & 3) * 8;
    int bk = tid >> 3, bf0 = (tid & 7) * 8;
    const float* gupE = gup + (size_t)e * HDIM * F2;

    for (int nb = 0; nb < F2 / 64; ++nb) {
        f32x4 acc[2][2];
#pragma unroll
        for (int mi = 0; mi < 2; ++mi)
#pragma unroll
            for (int ni = 0; ni < 2; ++ni) acc[mi][ni] = (f32x4){0.f, 0.f, 0.f, 0.f};
        for (int kb = 0; kb < HDIM / 32; ++kb) {
            __syncthreads();
            {
                int tk = rtok[ar];
                short8 vv = {0,0,0,0,0,0,0,0};
                if (tk >= 0) {
                    const float* p = x + (size_t)tk * HDIM + kb * 32 + ac0;
                    float4 u0 = *(const float4*)(p); float4 u1 = *(const float4*)(p + 4);
                    vv[0]=(short)f2bf(u0.x); vv[1]=(short)f2bf(u0.y); vv[2]=(short)f2bf(u0.z); vv[3]=(short)f2bf(u0.w);
                    vv[4]=(short)f2bf(u1.x); vv[5]=(short)f2bf(u1.y); vv[6]=(short)f2bf(u1.z); vv[7]=(short)f2bf(u1.w);
                }
                *(short8*)&sA[ar][ac0] = vv;
            }
            {
                const float* p = gupE + (size_t)(kb * 32 + bk) * F2 + nb * 64 + bf0;
                float4 u0 = *(const float4*)(p); float4 u1 = *(const float4*)(p + 4);
                sB[bf0+0][bk]=f2bf(u0.x); sB[bf0+1][bk]=f2bf(u0.y); sB[bf0+2][bk]=f2bf(u0.z); sB[bf0+3][bk]=f2bf(u0.w);
                sB[bf0+4][bk]=f2bf(u1.x); sB[bf0+5][bk]=f2bf(u1.y); sB[bf0+6][bk]=f2bf(u1.z); sB[bf0+7][bk]=f2bf(u1.w);
            }
            __syncthreads();
            short8 a0 = *(const short8*)&sA[wr*32+lr][lg*8];
            short8 a1 = *(const short8*)&sA[wr*32+16+lr][lg*8];
            short8 b0 = *(const short8*)&sB[wc*32+lr][lg*8];
            short8 b1 = *(const short8*)&sB[wc*32+16+lr][lg*8];
            acc[0][0] = __builtin_amdgcn_mfma_f32_16x16x32_bf16(a0,b0,acc[0][0],0,0,0);
            acc[0][1] = __builtin_amdgcn_mfma_f32_16x16x32_bf16(a0,b1,acc[0][1],0,0,0);
            acc[1][0] = __builtin_amdgcn_mfma_f32_16x16x32_bf16(a1,b0,acc[1][0],0,0,0);
            acc[1][1] = __builtin_amdgcn_mfma_f32_16x16x32_bf16(a1,b1,acc[1][1],0,0,0);
        }
#pragma unroll
        for (int ni = 0; ni < 2; ++ni) {
            int fc = nb * 64 + wc * 32 + ni * 16 + lr;
            float bias = gub[e * F2 + fc];
#pragma unroll
            for (int mi = 0; mi < 2; ++mi)
#pragma unroll
                for (int r = 0; r < 4; ++r) {
                    float gu = acc[mi][ni][r] + bias;
                    float other = __shfl_xor(gu, 1);
                    float gate = (lr & 1) ? other : gu;
                    float up   = (lr & 1) ? gu : other;
                    gate = fminf(gate, LIMIT);
                    up = fminf(fmaxf(up, -LIMIT), LIMIT);
                    float glu = gate / (1.0f + __expf(-ALPHA * gate));
                    float av = (up + 1.0f) * glu;
                    if (!(lr & 1)) sAct[wr*32+mi*16+lg*4+r][fc >> 1] = f2bf(av);
                }
        }
    }
    __syncthreads();

    const float* dwnE = dwn + (size_t)e * NI * HDIM;
    int tks[2][4]; float wvs[2][4];
#pragma unroll
    for (int mi = 0; mi < 2; ++mi)
#pragma unroll
        for (int r = 0; r < 4; ++r) {
            int row = wr*32 + mi*16 + lg*4 + r;
            tks[mi][r] = rtok[row]; wvs[mi][r] = rwgt[row];
        }
    for (int nb = 0; nb < HDIM / 64; ++nb) {
        f32x4 acc[2][2];
#pragma unroll
        for (int mi = 0; mi < 2; ++mi)
#pragma unroll
            for (int ni = 0; ni < 2; ++ni) acc[mi][ni] = (f32x4){0.f,0.f,0.f,0.f};
        for (int kb = 0; kb < NI / 32; ++kb) {
            __syncthreads();
            {
                const float* p = dwnE + (size_t)(kb*32 + bk) * HDIM + nb*64 + bf0;
                float4 u0 = *(const float4*)(p); float4 u1 = *(const float4*)(p + 4);
                sB[bf0+0][bk]=f2bf(u0.x); sB[bf0+1][bk]=f2bf(u0.y); sB[bf0+2][bk]=f2bf(u0.z); sB[bf0+3][bk]=f2bf(u0.w);
                sB[bf0+4][bk]=f2bf(u1.x); sB[bf0+5][bk]=f2bf(u1.y); sB[bf0+6][bk]=f2bf(u1.z); sB[bf0+7][bk]=f2bf(u1.w);
            }
            __syncthreads();
            short8 a0 = *(const short8*)&sAct[wr*32+lr][kb*32+lg*8];
            short8 a1 = *(const short8*)&sAct[wr*32+16+lr][kb*32+lg*8];
            short8 b0 = *(const short8*)&sB[wc*32+lr][lg*8];
            short8 b1 = *(const short8*)&sB[wc*32+16+lr][lg*8];
            acc[0][0] = __builtin_amdgcn_mfma_f32_16x16x32_bf16(a0,b0,acc[0][0],0,0,0);
            acc[0][1] = __builtin_amdgcn_mfma_f32_16x16x32_bf16(a0,b1,acc[0][1],0,0,0);
            acc[1][0] = __builtin_amdgcn_mfma_f32_16x16x32_bf16(a1,b0,acc[1][0],0,0,0);
            acc[1][1] = __builtin_amdgcn_mfma_f32_16x16x32_bf16(a1,b1,acc[1][1],0,0,0);
        }
#pragma unroll
        for (int ni = 0; ni < 2; ++ni) {
            int hc = nb*64 + wc*32 + ni*16 + lr;
            float db = dwb[e * HDIM + hc];
#pragma unroll
            for (int mi = 0; mi < 2; ++mi)
#pragma unroll
                for (int r = 0; r < 4; ++r) {
                    int tk = tks[mi][r];
                    if (tk >= 0)
                        atomicAdd(out + (size_t)tk * HDIM + hc, wvs[mi][r] * (acc[mi][ni][r] + db));
                }
        }
    }
}

extern "C" void kernel_launch(void* const* d_in, const int* in_sizes, int n_in,
                              void* d_out, int out_size, void* d_ws, size_t ws_size,
                              hipStream_t stream) {
    const float* x   = (const float*)d_in[0];
    const float* rw  = (const float*)d_in[1];
    const float* gup = (const float*)d_in[2];
    const float* gub = (const float*)d_in[3];
    const float* dwn = (const float*)d_in[4];
    const float* dwb = (const float*)d_in[5];
    float* out = (float*)d_out;

    // ---- ws layout ----
    const size_t OFF_COUNTS = 0;                 // 256 B
    const size_t OFF_ZP     = 256;               // 4 KB zero page
    const size_t OFF_TOKS   = 4352;
    const size_t OFF_WGTS   = OFF_TOKS + (size_t)NE * CAP * 4;
    const size_t OFF_XBF    = OFF_WGTS + (size_t)NE * CAP * 4;
    const size_t OFF_GUPT   = OFF_XBF  + (size_t)TOK * HDIM * 2;
    const size_t OFF_DWNT   = OFF_GUPT + (size_t)NE * HDIM * F2 * 2;
    const size_t OFF_ACT    = OFF_DWNT + (size_t)NE * NI * HDIM * 2;
    const size_t REQ        = OFF_ACT  + (size_t)NE * CAP2 * NI * 2;
    // router partials (4 MB) reuse the act region (act written only after combine)

    if (ws_size >= REQ) {
        int*            counts = (int*)((char*)d_ws + OFF_COUNTS);
        unsigned short* zp     = (unsigned short*)((char*)d_ws + OFF_ZP);
        int*            toks   = (int*)((char*)d_ws + OFF_TOKS);
        float*          wgts   = (float*)((char*)d_ws + OFF_WGTS);
        unsigned short* xbf    = (unsigned short*)((char*)d_ws + OFF_XBF);
        unsigned short* gupT   = (unsigned short*)((char*)d_ws + OFF_GUPT);
        unsigned short* dwnT   = (unsigned short*)((char*)d_ws + OFF_DWNT);
        unsigned short* act    = (unsigned short*)((char*)d_ws + OFF_ACT);
        double*         part   = (double*)((char*)d_ws + OFF_ACT);

        hipMemsetAsync(d_ws, 0, 4352, stream);                       // counts + zero page
        hipMemsetAsync(d_out, 0, (size_t)out_size * sizeof(float), stream);

        dim3 tg1(F2 / 64, HDIM / 64, NE);
        transpose_kernel<<<tg1, 256, 0, stream>>>(gup, gupT, HDIM, F2);
        dim3 tg2(HDIM / 64, NI / 64, NE);
        transpose_kernel<<<tg2, 256, 0, stream>>>(dwn, dwnT, NI, HDIM);

        router_partial_kernel<<<(TOK / 16) * 4, 64, 0, stream>>>(x, rw, part, xbf);
        router_combine_kernel<<<TOK / 256, 256, 0, stream>>>(part, counts, toks, wgts);

        int g1 = (CAP2 / 128) * (F2 / 128) * NE;     // 2048
        gemm1_kernel<<<g1, 256, 0, stream>>>(xbf, gupT, gub, counts, toks, act, zp);
        int g2 = (CAP2 / 128) * (HDIM / 128) * NE;   // 2048
        gemm2_kernel<<<g2, 256, 0, stream>>>(act, dwnT, dwb, counts, toks, wgts, out);
    } else {
        // fallback: round-1 path (~1.1 MB of ws)
        int*   counts = (int*)d_ws;
        int*   toks   = (int*)((char*)d_ws + 64);
        float* wgts   = (float*)((char*)d_ws + 64 + (size_t)NE * CAP * sizeof(int));
        hipMemsetAsync(d_ws, 0, 64, stream);
        hipMemsetAsync(d_out, 0, (size_t)out_size * sizeof(float), stream);
        router_kernel<<<TOK / 4, 256, 0, stream>>>(x, rw, counts, toks, wgts);
        dim3 gm(TOK / 64, NE);
        moe_kernel<<<gm, 256, 0, stream>>>(x, gup, gub, dwn, dwb, counts, toks, wgts, out);
    }
}

// Round 5
// 194.716 us; speedup vs baseline: 6.0823x; 1.1839x over previous
//
#include <hip/hip_runtime.h>
#include <hip/hip_bf16.h>
#include <math.h>

#define TOK   8192
#define HDIM  1024
#define NE    16
#define NI    512
#define F2    1024
#define CAP   8192
#define CAP2  2048
#define ALPHA 1.702f
#define LIMIT 7.0f

typedef __attribute__((ext_vector_type(8))) short short8;
typedef __attribute__((ext_vector_type(4))) short short4v;
typedef __attribute__((ext_vector_type(4))) float f32x4;

static __device__ __forceinline__ unsigned short f2bf(float f) {
    unsigned int u = __float_as_uint(f);
    u += 0x7FFFu + ((u >> 16) & 1u);
    return (unsigned short)(u >> 16);
}

#define GLD_LDS16(g, l) __builtin_amdgcn_global_load_lds(                     \
    (const __attribute__((address_space(1))) void*)(g),                       \
    (__attribute__((address_space(3))) void*)(l), 16, 0, 0)

// ================= router phase A: fp64 partial logits, fused x->bf16 =================
__global__ __launch_bounds__(64) void router_partial_kernel(
    const float* __restrict__ x, const float* __restrict__ rw,
    double* __restrict__ part, unsigned short* __restrict__ xbf)
{
    int bx = blockIdx.x;
    int tile = bx >> 2, ksl = bx & 3;
    int t0 = tile * 16;
    int hbase = ksl * 256;

    __shared__ __align__(16) float sx[16][68];
    __shared__ __align__(16) float srw[64][16];

    int lane = threadIdx.x;
    int tt = lane & 15, eg = lane >> 4;

    double acc[4] = {0.0, 0.0, 0.0, 0.0};

    for (int hc = 0; hc < 4; ++hc) {
        int h0 = hbase + hc * 64;
        __syncthreads();
#pragma unroll
        for (int j = 0; j < 4; ++j) {
            int fidx = j * 64 + lane;
            int t = fidx >> 4, c4 = (fidx & 15) * 4;
            float4 v = *(const float4*)(x + (size_t)(t0 + t) * HDIM + h0 + c4);
            *(float4*)&sx[t][c4] = v;
            short4v s;
            s[0] = (short)f2bf(v.x); s[1] = (short)f2bf(v.y);
            s[2] = (short)f2bf(v.z); s[3] = (short)f2bf(v.w);
            *(short4v*)(xbf + (size_t)(t0 + t) * HDIM + h0 + c4) = s;
        }
#pragma unroll
        for (int j = 0; j < 4; ++j) {
            int ridx = j * 64 + lane;
            int h = ridx >> 2, e4 = (ridx & 3) * 4;
            float4 v = *(const float4*)(rw + (size_t)(h0 + h) * NE + e4);
            *(float4*)&srw[h][e4] = v;
        }
        __syncthreads();
#pragma unroll 8
        for (int j = 0; j < 64; ++j) {
            float xv = sx[tt][j];
            float4 wv = *(const float4*)&srw[j][eg * 4];
            double xd = (double)xv;
            acc[0] += xd * (double)wv.x;
            acc[1] += xd * (double)wv.y;
            acc[2] += xd * (double)wv.z;
            acc[3] += xd * (double)wv.w;
        }
    }
#pragma unroll
    for (int q = 0; q < 4; ++q)
        part[(size_t)(ksl * NE + eg * 4 + q) * TOK + t0 + tt] = acc[q];
}

// ===== router phase B: combine, top-2, softmax, aggregated scatter + inverse map =====
__global__ __launch_bounds__(256) void router_combine_kernel(
    const double* __restrict__ part,
    int* __restrict__ counts, int* __restrict__ toks, float* __restrict__ wgts,
    unsigned short* __restrict__ inv)
{
    __shared__ int lhist[NE];
    __shared__ int lbase[NE];
    int tid = threadIdx.x;
    int t = blockIdx.x * 256 + tid;
    if (tid < NE) lhist[tid] = 0;
    __syncthreads();

    double acc[NE];
#pragma unroll
    for (int e = 0; e < NE; ++e)
        acc[e] = part[(size_t)(0 * NE + e) * TOK + t]
               + part[(size_t)(1 * NE + e) * TOK + t]
               + part[(size_t)(2 * NE + e) * TOK + t]
               + part[(size_t)(3 * NE + e) * TOK + t];

    int i0 = 0; double v0 = acc[0];
#pragma unroll
    for (int e = 1; e < NE; ++e) if (acc[e] > v0) { v0 = acc[e]; i0 = e; }
    int i1 = -1; double v1 = -1e300;
#pragma unroll
    for (int e = 0; e < NE; ++e) if (e != i0 && acc[e] > v1) { v1 = acc[e]; i1 = e; }
    double e1 = exp(v1 - v0);
    float w0 = (float)(1.0 / (1.0 + e1));
    float w1 = (float)(e1 / (1.0 + e1));

    int r0 = atomicAdd(&lhist[i0], 1);
    int r1 = atomicAdd(&lhist[i1], 1);
    __syncthreads();
    if (tid < NE) lbase[tid] = atomicAdd(&counts[tid], lhist[tid]);
    __syncthreads();
    int p0 = lbase[i0] + r0; if (p0 > 2047) p0 = 2047;
    int p1 = lbase[i1] + r1; if (p1 > 2047) p1 = 2047;
    toks[i0 * CAP + p0] = t; wgts[i0 * CAP + p0] = w0;
    toks[i1 * CAP + p1] = t; wgts[i1 * CAP + p1] = w1;
    inv[2 * t]     = (unsigned short)((i0 << 11) | p0);
    inv[2 * t + 1] = (unsigned short)((i1 << 11) | p1);
}

// ------------- transpose + convert: in [E][R][C] fp32 -> out [E][C][R] bf16 -------------
__global__ __launch_bounds__(256) void transpose_kernel(
    const float* __restrict__ in, unsigned short* __restrict__ out, int R, int C)
{
    int e = blockIdx.z;
    const float* pin = in + (size_t)e * R * C;
    unsigned short* pout = out + (size_t)e * R * C;
    __shared__ float t2[64][65];
    int c0 = blockIdx.x * 64, r0 = blockIdx.y * 64;
    int tid = threadIdx.x;
#pragma unroll
    for (int j = 0; j < 4; ++j) {
        int idx4 = j * 256 + tid;
        int r = idx4 >> 4, c4 = (idx4 & 15) * 4;
        float4 v = *(const float4*)(pin + (size_t)(r0 + r) * C + c0 + c4);
        t2[c4 + 0][r] = v.x;
        t2[c4 + 1][r] = v.y;
        t2[c4 + 2][r] = v.z;
        t2[c4 + 3][r] = v.w;
    }
    __syncthreads();
#pragma unroll
    for (int j = 0; j < 2; ++j) {
        int idx = j * 256 + tid;
        int n = idx >> 3, k0 = (idx & 7) * 8;
        short8 v;
#pragma unroll
        for (int q = 0; q < 8; ++q) v[q] = (short)f2bf(t2[n][k0 + q]);
        *(short8*)(pout + (size_t)(c0 + n) * R + r0 + k0) = v;
    }
}

// ---------------- GEMM1: x_bf (gathered) @ gupT^T + bias -> act (bf16); 2-phase dbuf ----------------
__global__ __launch_bounds__(256) void gemm1_kernel(
    const unsigned short* __restrict__ xb, const unsigned short* __restrict__ gupT,
    const float* __restrict__ gub,
    const int* __restrict__ counts, const int* __restrict__ toks,
    unsigned short* __restrict__ act, const unsigned short* __restrict__ zp)
{
    int b = blockIdx.x;
    int e = b & 15;
    int j = b >> 4;
    int nt = j & 7;
    int mt = j >> 3;
    int cnt = counts[e];
    int row0 = mt * 128;
    if (row0 >= cnt) return;
    int n0 = nt * 128;

    __shared__ __align__(16) unsigned short As[2][128][32];
    __shared__ __align__(16) unsigned short Bs[2][128][32];
    __shared__ int rtok[128];

    int tid = threadIdx.x;
    int lane = tid & 63;
    int w = tid >> 6;
    int wr = w >> 1, wc = w & 1;
    int lr = lane & 15, lg = lane >> 4;

    if (tid < 128) {
        int p = row0 + tid;
        rtok[tid] = (p < cnt) ? toks[e * CAP + p] : -1;
    }
    __syncthreads();

    int srow = lane >> 2;
    int scol = (lane & 3) * 8;
    const unsigned short* gaA[2];
    const unsigned short* gaB[2];
    const unsigned short* gupE = gupT + (size_t)e * HDIM * F2;
#pragma unroll
    for (int i = 0; i < 2; ++i) {
        int arow = w * 32 + i * 16 + srow;
        int tk = rtok[arow];
        gaA[i] = (tk >= 0) ? (xb + (size_t)tk * HDIM + scol) : (zp + scol);
        int brow = n0 + w * 32 + i * 16 + srow;
        gaB[i] = gupE + (size_t)brow * HDIM + scol;
    }

    f32x4 acc[4][4];
#pragma unroll
    for (int m = 0; m < 4; ++m)
#pragma unroll
        for (int n = 0; n < 4; ++n) acc[m][n] = (f32x4){0.f, 0.f, 0.f, 0.f};

    const int NT = HDIM / 32;
#pragma unroll
    for (int i = 0; i < 2; ++i) {
        GLD_LDS16(gaA[i], &As[0][w * 32 + i * 16][0]);
        GLD_LDS16(gaB[i], &Bs[0][w * 32 + i * 16][0]);
    }
    __syncthreads();

    int cur = 0;
    for (int kb = 0; kb < NT; ++kb) {
        if (kb + 1 < NT) {
#pragma unroll
            for (int i = 0; i < 2; ++i) {
                GLD_LDS16(gaA[i] + (kb + 1) * 32, &As[cur ^ 1][w * 32 + i * 16][0]);
                GLD_LDS16(gaB[i] + (kb + 1) * 32, &Bs[cur ^ 1][w * 32 + i * 16][0]);
            }
        }
        short8 af[4], bfr[4];
#pragma unroll
        for (int m = 0; m < 4; ++m) af[m] = *(const short8*)&As[cur][wr * 64 + m * 16 + lr][lg * 8];
#pragma unroll
        for (int n = 0; n < 4; ++n) bfr[n] = *(const short8*)&Bs[cur][wc * 64 + n * 16 + lr][lg * 8];
#pragma unroll
        for (int m = 0; m < 4; ++m)
#pragma unroll
            for (int n = 0; n < 4; ++n)
                acc[m][n] = __builtin_amdgcn_mfma_f32_16x16x32_bf16(af[m], bfr[n], acc[m][n], 0, 0, 0);
        __syncthreads();
        cur ^= 1;
    }

    unsigned short* actE = act + (size_t)e * CAP2 * NI;
#pragma unroll
    for (int n = 0; n < 4; ++n) {
        int fc = n0 + wc * 64 + n * 16 + lr;
        float bias = gub[e * F2 + fc];
#pragma unroll
        for (int m = 0; m < 4; ++m) {
#pragma unroll
            for (int r = 0; r < 4; ++r) {
                float gu = acc[m][n][r] + bias;
                float other = __shfl_xor(gu, 1);
                float gate = (lr & 1) ? other : gu;
                float up   = (lr & 1) ? gu    : other;
                gate = fminf(gate, LIMIT);
                up   = fminf(fmaxf(up, -LIMIT), LIMIT);
                float glu = gate / (1.0f + __expf(-ALPHA * gate));
                float av  = (up + 1.0f) * glu;
                if (!(lr & 1)) {
                    int row = row0 + wr * 64 + m * 16 + lg * 4 + r;
                    actE[(size_t)row * NI + (fc >> 1)] = f2bf(av);
                }
            }
        }
    }
}

// ------- GEMM2 (tier A): act @ dwnT^T, *score, +bias -> compact y[base[e]+p][HDIM] -------
__global__ __launch_bounds__(256) void gemm2_y_kernel(
    const unsigned short* __restrict__ act, const unsigned short* __restrict__ dwnT,
    const float* __restrict__ dwb,
    const int* __restrict__ counts, const float* __restrict__ wgts,
    float* __restrict__ y)
{
    int b = blockIdx.x;
    int e = b & 15;
    int j = b >> 4;
    int nt = j & 7;
    int mt = j >> 3;
    int cnt = counts[e];
    int row0 = mt * 128;
    if (row0 >= cnt) return;
    int n0 = nt * 128;

    int base_e = 0;
#pragma unroll
    for (int q = 0; q < NE; ++q) base_e += (q < e) ? counts[q] : 0;

    __shared__ __align__(16) unsigned short As[2][128][32];
    __shared__ __align__(16) unsigned short Bs[2][128][32];
    __shared__ float rwgt[128];

    int tid = threadIdx.x;
    int lane = tid & 63;
    int w = tid >> 6;
    int wr = w >> 1, wc = w & 1;
    int lr = lane & 15, lg = lane >> 4;

    if (tid < 128) {
        int p = row0 + tid;
        rwgt[tid] = (p < cnt) ? wgts[e * CAP + p] : 0.0f;
    }
    __syncthreads();

    int srow = lane >> 2;
    int scol = (lane & 3) * 8;
    const unsigned short* gaA[2];
    const unsigned short* gaB[2];
    const unsigned short* actE = act + (size_t)e * CAP2 * NI;
    const unsigned short* dwnE = dwnT + (size_t)e * HDIM * NI;
#pragma unroll
    for (int i = 0; i < 2; ++i) {
        int arow = row0 + w * 32 + i * 16 + srow;
        gaA[i] = actE + (size_t)arow * NI + scol;
        int brow = n0 + w * 32 + i * 16 + srow;
        gaB[i] = dwnE + (size_t)brow * NI + scol;
    }

    f32x4 acc[4][4];
#pragma unroll
    for (int m = 0; m < 4; ++m)
#pragma unroll
        for (int n = 0; n < 4; ++n) acc[m][n] = (f32x4){0.f, 0.f, 0.f, 0.f};

    const int NT = NI / 32;
#pragma unroll
    for (int i = 0; i < 2; ++i) {
        GLD_LDS16(gaA[i], &As[0][w * 32 + i * 16][0]);
        GLD_LDS16(gaB[i], &Bs[0][w * 32 + i * 16][0]);
    }
    __syncthreads();

    int cur = 0;
    for (int kb = 0; kb < NT; ++kb) {
        if (kb + 1 < NT) {
#pragma unroll
            for (int i = 0; i < 2; ++i) {
                GLD_LDS16(gaA[i] + (kb + 1) * 32, &As[cur ^ 1][w * 32 + i * 16][0]);
                GLD_LDS16(gaB[i] + (kb + 1) * 32, &Bs[cur ^ 1][w * 32 + i * 16][0]);
            }
        }
        short8 af[4], bfr[4];
#pragma unroll
        for (int m = 0; m < 4; ++m) af[m] = *(const short8*)&As[cur][wr * 64 + m * 16 + lr][lg * 8];
#pragma unroll
        for (int n = 0; n < 4; ++n) bfr[n] = *(const short8*)&Bs[cur][wc * 64 + n * 16 + lr][lg * 8];
#pragma unroll
        for (int m = 0; m < 4; ++m)
#pragma unroll
            for (int n = 0; n < 4; ++n)
                acc[m][n] = __builtin_amdgcn_mfma_f32_16x16x32_bf16(af[m], bfr[n], acc[m][n], 0, 0, 0);
        __syncthreads();
        cur ^= 1;
    }

    float* yB = y + (size_t)(base_e + row0) * HDIM;
#pragma unroll
    for (int n = 0; n < 4; ++n) {
        int hc = n0 + wc * 64 + n * 16 + lr;
        float db = dwb[e * HDIM + hc];
#pragma unroll
        for (int m = 0; m < 4; ++m) {
#pragma unroll
            for (int r = 0; r < 4; ++r) {
                int rl = wr * 64 + m * 16 + lg * 4 + r;
                if (row0 + rl < cnt)
                    yB[(size_t)rl * HDIM + hc] = rwgt[rl] * (acc[m][n][r] + db);
            }
        }
    }
}

// ------- out combine: out[t] = y[slot0] + y[slot1]; fully coalesced, no atomics -------
__global__ __launch_bounds__(256) void out_combine_kernel(
    const float* __restrict__ y, const unsigned short* __restrict__ inv,
    const int* __restrict__ counts, float* __restrict__ out)
{
    __shared__ int sbase[NE];
    int tid = threadIdx.x;
    int t = blockIdx.x;
    if (tid == 0) {
        int s = 0;
#pragma unroll
        for (int e = 0; e < NE; ++e) { sbase[e] = s; s += counts[e]; }
    }
    __syncthreads();
    unsigned short v0 = inv[2 * t], v1 = inv[2 * t + 1];
    int s0 = sbase[v0 >> 11] + (v0 & 2047);
    int s1 = sbase[v1 >> 11] + (v1 & 2047);
    float4 a = *(const float4*)(y + (size_t)s0 * HDIM + tid * 4);
    float4 c = *(const float4*)(y + (size_t)s1 * HDIM + tid * 4);
    float4 o; o.x = a.x + c.x; o.y = a.y + c.y; o.z = a.z + c.z; o.w = a.w + c.w;
    *(float4*)(out + (size_t)t * HDIM + tid * 4) = o;
}

// ------- GEMM2 (tier B fallback): atomic scatter-add version -------
__global__ __launch_bounds__(256) void gemm2_kernel(
    const unsigned short* __restrict__ act, const unsigned short* __restrict__ dwnT,
    const float* __restrict__ dwb,
    const int* __restrict__ counts, const int* __restrict__ toks,
    const float* __restrict__ wgts, float* __restrict__ out)
{
    int b = blockIdx.x;
    int e = b & 15;
    int j = b >> 4;
    int nt = j & 7;
    int mt = j >> 3;
    int cnt = counts[e];
    int row0 = mt * 128;
    if (row0 >= cnt) return;
    int n0 = nt * 128;

    __shared__ __align__(16) unsigned short As[2][128][32];
    __shared__ __align__(16) unsigned short Bs[2][128][32];
    __shared__ int   rtok[128];
    __shared__ float rwgt[128];

    int tid = threadIdx.x;
    int lane = tid & 63;
    int w = tid >> 6;
    int wr = w >> 1, wc = w & 1;
    int lr = lane & 15, lg = lane >> 4;

    if (tid < 128) {
        int p = row0 + tid;
        bool v = p < cnt;
        rtok[tid] = v ? toks[e * CAP + p] : -1;
        rwgt[tid] = v ? wgts[e * CAP + p] : 0.0f;
    }
    __syncthreads();

    int srow = lane >> 2;
    int scol = (lane & 3) * 8;
    const unsigned short* gaA[2];
    const unsigned short* gaB[2];
    const unsigned short* actE = act + (size_t)e * CAP2 * NI;
    const unsigned short* dwnE = dwnT + (size_t)e * HDIM * NI;
#pragma unroll
    for (int i = 0; i < 2; ++i) {
        int arow = row0 + w * 32 + i * 16 + srow;
        gaA[i] = actE + (size_t)arow * NI + scol;
        int brow = n0 + w * 32 + i * 16 + srow;
        gaB[i] = dwnE + (size_t)brow * NI + scol;
    }

    f32x4 acc[4][4];
#pragma unroll
    for (int m = 0; m < 4; ++m)
#pragma unroll
        for (int n = 0; n < 4; ++n) acc[m][n] = (f32x4){0.f, 0.f, 0.f, 0.f};

    const int NT = NI / 32;
#pragma unroll
    for (int i = 0; i < 2; ++i) {
        GLD_LDS16(gaA[i], &As[0][w * 32 + i * 16][0]);
        GLD_LDS16(gaB[i], &Bs[0][w * 32 + i * 16][0]);
    }
    __syncthreads();

    int cur = 0;
    for (int kb = 0; kb < NT; ++kb) {
        if (kb + 1 < NT) {
#pragma unroll
            for (int i = 0; i < 2; ++i) {
                GLD_LDS16(gaA[i] + (kb + 1) * 32, &As[cur ^ 1][w * 32 + i * 16][0]);
                GLD_LDS16(gaB[i] + (kb + 1) * 32, &Bs[cur ^ 1][w * 32 + i * 16][0]);
            }
        }
        short8 af[4], bfr[4];
#pragma unroll
        for (int m = 0; m < 4; ++m) af[m] = *(const short8*)&As[cur][wr * 64 + m * 16 + lr][lg * 8];
#pragma unroll
        for (int n = 0; n < 4; ++n) bfr[n] = *(const short8*)&Bs[cur][wc * 64 + n * 16 + lr][lg * 8];
#pragma unroll
        for (int m = 0; m < 4; ++m)
#pragma unroll
            for (int n = 0; n < 4; ++n)
                acc[m][n] = __builtin_amdgcn_mfma_f32_16x16x32_bf16(af[m], bfr[n], acc[m][n], 0, 0, 0);
        __syncthreads();
        cur ^= 1;
    }

#pragma unroll
    for (int n = 0; n < 4; ++n) {
        int hc = n0 + wc * 64 + n * 16 + lr;
        float db = dwb[e * HDIM + hc];
#pragma unroll
        for (int m = 0; m < 4; ++m) {
#pragma unroll
            for (int r = 0; r < 4; ++r) {
                int row = wr * 64 + m * 16 + lg * 4 + r;
                int tk = rtok[row];
                if (tk >= 0)
                    atomicAdd(out + (size_t)tk * HDIM + hc,
                              rwgt[row] * (acc[m][n][r] + db));
            }
        }
    }
}

// ================= fallback path kernels (round-1 style, small ws) =================
__global__ __launch_bounds__(256) void router_kernel(
    const float* __restrict__ x, const float* __restrict__ rw,
    int* __restrict__ counts, int* __restrict__ toks, float* __restrict__ wgts)
{
    int gwave = (int)((blockIdx.x * 256 + threadIdx.x) >> 6);
    int lane = threadIdx.x & 63;
    if (gwave >= TOK) return;
    const float* xr = x + (size_t)gwave * HDIM;
    double acc[NE];
#pragma unroll
    for (int e = 0; e < NE; ++e) acc[e] = 0.0;
    for (int i = 0; i < HDIM / 64; ++i) {
        int h = i * 64 + lane;
        double xv = (double)xr[h];
        const float* r = rw + (size_t)h * NE;
#pragma unroll
        for (int e = 0; e < NE; ++e) acc[e] += xv * (double)r[e];
    }
#pragma unroll
    for (int e = 0; e < NE; ++e) {
        double v = acc[e];
#pragma unroll
        for (int off = 32; off > 0; off >>= 1) v += __shfl_xor(v, off);
        acc[e] = v;
    }
    if (lane == 0) {
        int i0 = 0; double v0 = acc[0];
#pragma unroll
        for (int e = 1; e < NE; ++e) if (acc[e] > v0) { v0 = acc[e]; i0 = e; }
        int i1 = -1; double v1 = -1e300;
#pragma unroll
        for (int e = 0; e < NE; ++e) if (e != i0 && acc[e] > v1) { v1 = acc[e]; i1 = e; }
        double e1 = exp(v1 - v0);
        float w0 = (float)(1.0 / (1.0 + e1));
        float w1 = (float)(e1 / (1.0 + e1));
        int p0 = atomicAdd(&counts[i0], 1);
        toks[i0 * CAP + p0] = gwave; wgts[i0 * CAP + p0] = w0;
        int p1 = atomicAdd(&counts[i1], 1);
        toks[i1 * CAP + p1] = gwave; wgts[i1 * CAP + p1] = w1;
    }
}

__global__ __launch_bounds__(256) void moe_kernel(
    const float* __restrict__ x,
    const float* __restrict__ gup, const float* __restrict__ gub,
    const float* __restrict__ dwn, const float* __restrict__ dwb,
    const int* __restrict__ counts, const int* __restrict__ toks,
    const float* __restrict__ wgts, float* __restrict__ out)
{
    int e = blockIdx.y;
    int cnt = counts[e];
    int row0 = blockIdx.x * 64;
    if (row0 >= cnt) return;

    __shared__ __align__(16) unsigned short sA[64][40];
    __shared__ __align__(16) unsigned short sB[64][40];
    __shared__ __align__(16) unsigned short sAct[64][520];
    __shared__ int   rtok[64];
    __shared__ float rwgt[64];

    int tid = threadIdx.x;
    if (tid < 64) {
        int idx = row0 + tid;
        bool v = idx < cnt;
        rtok[tid] = v ? toks[e * CAP + idx] : -1;
        rwgt[tid] = v ? wgts[e * CAP + idx] : 0.0f;
    }
    __syncthreads();

    int lane = tid & 63;
    int w = tid >> 6;
    int wr = w >> 1, wc = w & 1;
    int lr = lane & 15, lg = lane >> 4;
    int ar = tid >> 2, ac0 = (tid & 3) * 8;
    int bk = tid >> 3, bf0 = (tid & 7) * 8;
    const float* gupE = gup + (size_t)e * HDIM * F2;

    for (int nb = 0; nb < F2 / 64; ++nb) {
        f32x4 acc[2][2];
#pragma unroll
        for (int mi = 0; mi < 2; ++mi)
#pragma unroll
            for (int ni = 0; ni < 2; ++ni) acc[mi][ni] = (f32x4){0.f, 0.f, 0.f, 0.f};
        for (int kb = 0; kb < HDIM / 32; ++kb) {
            __syncthreads();
            {
                int tk = rtok[ar];
                short8 vv = {0,0,0,0,0,0,0,0};
                if (tk >= 0) {
                    const float* p = x + (size_t)tk * HDIM + kb * 32 + ac0;
                    float4 u0 = *(const float4*)(p); float4 u1 = *(const float4*)(p + 4);
                    vv[0]=(short)f2bf(u0.x); vv[1]=(short)f2bf(u0.y); vv[2]=(short)f2bf(u0.z); vv[3]=(short)f2bf(u0.w);
                    vv[4]=(short)f2bf(u1.x); vv[5]=(short)f2bf(u1.y); vv[6]=(short)f2bf(u1.z); vv[7]=(short)f2bf(u1.w);
                }
                *(short8*)&sA[ar][ac0] = vv;
            }
            {
                const float* p = gupE + (size_t)(kb * 32 + bk) * F2 + nb * 64 + bf0;
                float4 u0 = *(const float4*)(p); float4 u1 = *(const float4*)(p + 4);
                sB[bf0+0][bk]=f2bf(u0.x); sB[bf0+1][bk]=f2bf(u0.y); sB[bf0+2][bk]=f2bf(u0.z); sB[bf0+3][bk]=f2bf(u0.w);
                sB[bf0+4][bk]=f2bf(u1.x); sB[bf0+5][bk]=f2bf(u1.y); sB[bf0+6][bk]=f2bf(u1.z); sB[bf0+7][bk]=f2bf(u1.w);
            }
            __syncthreads();
            short8 a0 = *(const short8*)&sA[wr*32+lr][lg*8];
            short8 a1 = *(const short8*)&sA[wr*32+16+lr][lg*8];
            short8 b0 = *(const short8*)&sB[wc*32+lr][lg*8];
            short8 b1 = *(const short8*)&sB[wc*32+16+lr][lg*8];
            acc[0][0] = __builtin_amdgcn_mfma_f32_16x16x32_bf16(a0,b0,acc[0][0],0,0,0);
            acc[0][1] = __builtin_amdgcn_mfma_f32_16x16x32_bf16(a0,b1,acc[0][1],0,0,0);
            acc[1][0] = __builtin_amdgcn_mfma_f32_16x16x32_bf16(a1,b0,acc[1][0],0,0,0);
            acc[1][1] = __builtin_amdgcn_mfma_f32_16x16x32_bf16(a1,b1,acc[1][1],0,0,0);
        }
#pragma unroll
        for (int ni = 0; ni < 2; ++ni) {
            int fc = nb * 64 + wc * 32 + ni * 16 + lr;
            float bias = gub[e * F2 + fc];
#pragma unroll
            for (int mi = 0; mi < 2; ++mi)
#pragma unroll
                for (int r = 0; r < 4; ++r) {
                    float gu = acc[mi][ni][r] + bias;
                    float other = __shfl_xor(gu, 1);
                    float gate = (lr & 1) ? other : gu;
                    float up   = (lr & 1) ? gu : other;
                    gate = fminf(gate, LIMIT);
                    up = fminf(fmaxf(up, -LIMIT), LIMIT);
                    float glu = gate / (1.0f + __expf(-ALPHA * gate));
                    float av = (up + 1.0f) * glu;
                    if (!(lr & 1)) sAct[wr*32+mi*16+lg*4+r][fc >> 1] = f2bf(av);
                }
        }
    }
    __syncthreads();

    const float* dwnE = dwn + (size_t)e * NI * HDIM;
    int tks[2][4]; float wvs[2][4];
#pragma unroll
    for (int mi = 0; mi < 2; ++mi)
#pragma unroll
        for (int r = 0; r < 4; ++r) {
            int row = wr*32 + mi*16 + lg*4 + r;
            tks[mi][r] = rtok[row]; wvs[mi][r] = rwgt[row];
        }
    for (int nb = 0; nb < HDIM / 64; ++nb) {
        f32x4 acc[2][2];
#pragma unroll
        for (int mi = 0; mi < 2; ++mi)
#pragma unroll
            for (int ni = 0; ni < 2; ++ni) acc[mi][ni] = (f32x4){0.f,0.f,0.f,0.f};
        for (int kb = 0; kb < NI / 32; ++kb) {
            __syncthreads();
            {
                const float* p = dwnE + (size_t)(kb*32 + bk) * HDIM + nb*64 + bf0;
                float4 u0 = *(const float4*)(p); float4 u1 = *(const float4*)(p + 4);
                sB[bf0+0][bk]=f2bf(u0.x); sB[bf0+1][bk]=f2bf(u0.y); sB[bf0+2][bk]=f2bf(u0.z); sB[bf0+3][bk]=f2bf(u0.w);
                sB[bf0+4][bk]=f2bf(u1.x); sB[bf0+5][bk]=f2bf(u1.y); sB[bf0+6][bk]=f2bf(u1.z); sB[bf0+7][bk]=f2bf(u1.w);
            }
            __syncthreads();
            short8 a0 = *(const short8*)&sAct[wr*32+lr][kb*32+lg*8];
            short8 a1 = *(const short8*)&sAct[wr*32+16+lr][kb*32+lg*8];
            short8 b0 = *(const short8*)&sB[wc*32+lr][lg*8];
            short8 b1 = *(const short8*)&sB[wc*32+16+lr][lg*8];
            acc[0][0] = __builtin_amdgcn_mfma_f32_16x16x32_bf16(a0,b0,acc[0][0],0,0,0);
            acc[0][1] = __builtin_amdgcn_mfma_f32_16x16x32_bf16(a0,b1,acc[0][1],0,0,0);
            acc[1][0] = __builtin_amdgcn_mfma_f32_16x16x32_bf16(a1,b0,acc[1][0],0,0,0);
            acc[1][1] = __builtin_amdgcn_mfma_f32_16x16x32_bf16(a1,b1,acc[1][1],0,0,0);
        }
#pragma unroll
        for (int ni = 0; ni < 2; ++ni) {
            int hc = nb*64 + wc*32 + ni*16 + lr;
            float db = dwb[e * HDIM + hc];
#pragma unroll
            for (int mi = 0; mi < 2; ++mi)
#pragma unroll
                for (int r = 0; r < 4; ++r) {
                    int tk = tks[mi][r];
                    if (tk >= 0)
                        atomicAdd(out + (size_t)tk * HDIM + hc, wvs[mi][r] * (acc[mi][ni][r] + db));
                }
        }
    }
}

extern "C" void kernel_launch(void* const* d_in, const int* in_sizes, int n_in,
                              void* d_out, int out_size, void* d_ws, size_t ws_size,
                              hipStream_t stream) {
    const float* x   = (const float*)d_in[0];
    const float* rw  = (const float*)d_in[1];
    const float* gup = (const float*)d_in[2];
    const float* gub = (const float*)d_in[3];
    const float* dwn = (const float*)d_in[4];
    const float* dwb = (const float*)d_in[5];
    float* out = (float*)d_out;

    // ---- ws layout (tier A / tier B shared) ----
    const size_t OFF_COUNTS = 0;                                   // 256 B
    const size_t OFF_ZP     = 256;                                 // 4 KB zero page
    const size_t OFF_INV    = 4352;                                // 32 KB
    const size_t OFF_TOKS   = OFF_INV  + (size_t)TOK * 2 * 2;
    const size_t OFF_WGTS   = OFF_TOKS + (size_t)NE * CAP * 4;
    const size_t OFF_DWNT   = OFF_WGTS + (size_t)NE * CAP * 4;
    const size_t OFF_ACT    = OFF_DWNT + (size_t)NE * NI * HDIM * 2;   // part (4MB) aliases here
    const size_t OFF_XBF    = OFF_ACT  + (size_t)NE * CAP2 * NI * 2;
    const size_t OFF_GUPT   = OFF_XBF  + (size_t)TOK * HDIM * 2;
    const size_t REQ_B      = OFF_GUPT + (size_t)NE * HDIM * F2 * 2;
    const size_t OFF_Y      = OFF_XBF;                             // aliases xbf+gupT (dead after gemm1)
    const size_t REQ_A      = OFF_Y + (size_t)2 * TOK * HDIM * 4;  // 64 MB compact fp32 y

    if (ws_size >= REQ_B) {
        int*            counts = (int*)((char*)d_ws + OFF_COUNTS);
        unsigned short* zp     = (unsigned short*)((char*)d_ws + OFF_ZP);
        unsigned short* inv    = (unsigned short*)((char*)d_ws + OFF_INV);
        int*            toks   = (int*)((char*)d_ws + OFF_TOKS);
        float*          wgts   = (float*)((char*)d_ws + OFF_WGTS);
        unsigned short* dwnT   = (unsigned short*)((char*)d_ws + OFF_DWNT);
        unsigned short* act    = (unsigned short*)((char*)d_ws + OFF_ACT);
        double*         part   = (double*)((char*)d_ws + OFF_ACT);
        unsigned short* xbf    = (unsigned short*)((char*)d_ws + OFF_XBF);
        unsigned short* gupT   = (unsigned short*)((char*)d_ws + OFF_GUPT);
        float*          y      = (float*)((char*)d_ws + OFF_Y);

        hipMemsetAsync(d_ws, 0, 4352, stream);   // counts + zero page

        dim3 tg1(F2 / 64, HDIM / 64, NE);
        transpose_kernel<<<tg1, 256, 0, stream>>>(gup, gupT, HDIM, F2);
        dim3 tg2(HDIM / 64, NI / 64, NE);
        transpose_kernel<<<tg2, 256, 0, stream>>>(dwn, dwnT, NI, HDIM);

        router_partial_kernel<<<(TOK / 16) * 4, 64, 0, stream>>>(x, rw, part, xbf);
        router_combine_kernel<<<TOK / 256, 256, 0, stream>>>(part, counts, toks, wgts, inv);

        int g1 = (CAP2 / 128) * (F2 / 128) * NE;     // 2048
        gemm1_kernel<<<g1, 256, 0, stream>>>(xbf, gupT, gub, counts, toks, act, zp);
        int g2 = (CAP2 / 128) * (HDIM / 128) * NE;   // 2048

        if (ws_size >= REQ_A) {
            gemm2_y_kernel<<<g2, 256, 0, stream>>>(act, dwnT, dwb, counts, wgts, y);
            out_combine_kernel<<<TOK, 256, 0, stream>>>(y, inv, counts, out);
        } else {
            hipMemsetAsync(d_out, 0, (size_t)out_size * sizeof(float), stream);
            gemm2_kernel<<<g2, 256, 0, stream>>>(act, dwnT, dwb, counts, toks, wgts, out);
        }
    } else {
        // fallback: round-1 path (~1.1 MB of ws)
        int*   counts = (int*)d_ws;
        int*   toks   = (int*)((char*)d_ws + 64);
        float* wgts   = (float*)((char*)d_ws + 64 + (size_t)NE * CAP * sizeof(int));
        hipMemsetAsync(d_ws, 0, 64, stream);
        hipMemsetAsync(d_out, 0, (size_t)out_size * sizeof(float), stream);
        router_kernel<<<TOK / 4, 256, 0, stream>>>(x, rw, counts, toks, wgts);
        dim3 gm(TOK / 64, NE);
        moe_kernel<<<gm, 256, 0, stream>>>(x, gup, gub, dwn, dwb, counts, toks, wgts, out);
    }
}

// Round 6
// 182.240 us; speedup vs baseline: 6.4987x; 1.0685x over previous
//
#include <hip/hip_runtime.h>
#include <hip/hip_bf16.h>
#include <math.h>

#define TOK   8192
#define HDIM  1024
#define NE    16
#define NI    512
#define F2    1024
#define CAP   8192
#define CAP2  2048
#define ALPHA 1.702f
#define LIMIT 7.0f

typedef __attribute__((ext_vector_type(8))) short short8;
typedef __attribute__((ext_vector_type(4))) short short4v;
typedef __attribute__((ext_vector_type(4))) float f32x4;

static __device__ __forceinline__ unsigned short f2bf(float f) {
    unsigned int u = __float_as_uint(f);
    u += 0x7FFFu + ((u >> 16) & 1u);
    return (unsigned short)(u >> 16);
}
static __device__ __forceinline__ float bf2f(unsigned short u) {
    return __uint_as_float((unsigned int)u << 16);
}

#define GLD_LDS16(g, l) __builtin_amdgcn_global_load_lds(                     \
    (const __attribute__((address_space(1))) void*)(g),                       \
    (__attribute__((address_space(3))) void*)(l), 16, 0, 0)

// ================= router phase A: fp64 partial logits, fused x->bf16 =================
__global__ __launch_bounds__(64) void router_partial_kernel(
    const float* __restrict__ x, const float* __restrict__ rw,
    double* __restrict__ part, unsigned short* __restrict__ xbf)
{
    int bx = blockIdx.x;
    int tile = bx >> 2, ksl = bx & 3;
    int t0 = tile * 16;
    int hbase = ksl * 256;

    __shared__ __align__(16) float sx[16][68];
    __shared__ __align__(16) float srw[64][16];

    int lane = threadIdx.x;
    int tt = lane & 15, eg = lane >> 4;

    double acc[4] = {0.0, 0.0, 0.0, 0.0};

    for (int hc = 0; hc < 4; ++hc) {
        int h0 = hbase + hc * 64;
        __syncthreads();
#pragma unroll
        for (int j = 0; j < 4; ++j) {
            int fidx = j * 64 + lane;
            int t = fidx >> 4, c4 = (fidx & 15) * 4;
            float4 v = *(const float4*)(x + (size_t)(t0 + t) * HDIM + h0 + c4);
            *(float4*)&sx[t][c4] = v;
            short4v s;
            s[0] = (short)f2bf(v.x); s[1] = (short)f2bf(v.y);
            s[2] = (short)f2bf(v.z); s[3] = (short)f2bf(v.w);
            *(short4v*)(xbf + (size_t)(t0 + t) * HDIM + h0 + c4) = s;
        }
#pragma unroll
        for (int j = 0; j < 4; ++j) {
            int ridx = j * 64 + lane;
            int h = ridx >> 2, e4 = (ridx & 3) * 4;
            float4 v = *(const float4*)(rw + (size_t)(h0 + h) * NE + e4);
            *(float4*)&srw[h][e4] = v;
        }
        __syncthreads();
#pragma unroll 8
        for (int j = 0; j < 64; ++j) {
            float xv = sx[tt][j];
            float4 wv = *(const float4*)&srw[j][eg * 4];
            double xd = (double)xv;
            acc[0] += xd * (double)wv.x;
            acc[1] += xd * (double)wv.y;
            acc[2] += xd * (double)wv.z;
            acc[3] += xd * (double)wv.w;
        }
    }
#pragma unroll
    for (int q = 0; q < 4; ++q)
        part[(size_t)(ksl * NE + eg * 4 + q) * TOK + t0 + tt] = acc[q];
}

// ===== router phase B: combine, top-2, softmax, aggregated scatter + inverse map =====
__global__ __launch_bounds__(256) void router_combine_kernel(
    const double* __restrict__ part,
    int* __restrict__ counts, int* __restrict__ toks, float* __restrict__ wgts,
    unsigned short* __restrict__ inv)
{
    __shared__ int lhist[NE];
    __shared__ int lbase[NE];
    int tid = threadIdx.x;
    int t = blockIdx.x * 256 + tid;
    if (tid < NE) lhist[tid] = 0;
    __syncthreads();

    double acc[NE];
#pragma unroll
    for (int e = 0; e < NE; ++e)
        acc[e] = part[(size_t)(0 * NE + e) * TOK + t]
               + part[(size_t)(1 * NE + e) * TOK + t]
               + part[(size_t)(2 * NE + e) * TOK + t]
               + part[(size_t)(3 * NE + e) * TOK + t];

    int i0 = 0; double v0 = acc[0];
#pragma unroll
    for (int e = 1; e < NE; ++e) if (acc[e] > v0) { v0 = acc[e]; i0 = e; }
    int i1 = -1; double v1 = -1e300;
#pragma unroll
    for (int e = 0; e < NE; ++e) if (e != i0 && acc[e] > v1) { v1 = acc[e]; i1 = e; }
    double e1 = exp(v1 - v0);
    float w0 = (float)(1.0 / (1.0 + e1));
    float w1 = (float)(e1 / (1.0 + e1));

    int r0 = atomicAdd(&lhist[i0], 1);
    int r1 = atomicAdd(&lhist[i1], 1);
    __syncthreads();
    if (tid < NE) lbase[tid] = atomicAdd(&counts[tid], lhist[tid]);
    __syncthreads();
    int p0 = lbase[i0] + r0; if (p0 > 2047) p0 = 2047;
    int p1 = lbase[i1] + r1; if (p1 > 2047) p1 = 2047;
    toks[i0 * CAP + p0] = t; wgts[i0 * CAP + p0] = w0;
    toks[i1 * CAP + p1] = t; wgts[i1 * CAP + p1] = w1;
    inv[2 * t]     = (unsigned short)((i0 << 11) | p0);
    inv[2 * t + 1] = (unsigned short)((i1 << 11) | p1);
}

// ------------- transpose + convert: in [E][R][C] fp32 -> out [E][C][R] bf16 -------------
// perm=1 (gate/up interleave-split for gup): output row for source col c:
//   tile=c>>7, ct=c&127, fl=ct>>1, h=ct&1 -> R = tile*128 + (fl>>4)*32 + h*16 + (fl&15)
__global__ __launch_bounds__(256) void transpose_kernel(
    const float* __restrict__ in, unsigned short* __restrict__ out, int R, int C, int perm)
{
    int e = blockIdx.z;
    const float* pin = in + (size_t)e * R * C;
    unsigned short* pout = out + (size_t)e * R * C;
    __shared__ float t2[64][65];
    int c0 = blockIdx.x * 64, r0 = blockIdx.y * 64;
    int tid = threadIdx.x;
#pragma unroll
    for (int j = 0; j < 4; ++j) {
        int idx4 = j * 256 + tid;
        int r = idx4 >> 4, c4 = (idx4 & 15) * 4;
        float4 v = *(const float4*)(pin + (size_t)(r0 + r) * C + c0 + c4);
        t2[c4 + 0][r] = v.x;
        t2[c4 + 1][r] = v.y;
        t2[c4 + 2][r] = v.z;
        t2[c4 + 3][r] = v.w;
    }
    __syncthreads();
#pragma unroll
    for (int j = 0; j < 2; ++j) {
        int idx = j * 256 + tid;
        int n = idx >> 3, k0 = (idx & 7) * 8;
        short8 v;
#pragma unroll
        for (int q = 0; q < 8; ++q) v[q] = (short)f2bf(t2[n][k0 + q]);
        int c = c0 + n;
        int orow;
        if (perm) {
            int tile = c >> 7, ct = c & 127;
            int fl = ct >> 1, h = ct & 1;
            orow = (tile << 7) | ((fl >> 4) << 5) | (h << 4) | (fl & 15);
        } else {
            orow = c;
        }
        *(short8*)(pout + (size_t)orow * R + r0 + k0) = v;
    }
}

// ---------------- GEMM1: x_bf (gathered) @ gupT^T + bias -> act (bf16) ----------------
// 2-phase dbuf; XOR bank-swizzle (source-side + read-side); gate/up permuted B rows.
__global__ __launch_bounds__(256) void gemm1_kernel(
    const unsigned short* __restrict__ xb, const unsigned short* __restrict__ gupT,
    const float* __restrict__ gub,
    const int* __restrict__ counts, const int* __restrict__ toks,
    unsigned short* __restrict__ act, const unsigned short* __restrict__ zp)
{
    int b = blockIdx.x;
    int e = b & 15;
    int j = b >> 4;
    int nt = j & 7;
    int mt = j >> 3;
    int cnt = counts[e];
    int row0 = mt * 128;
    if (row0 >= cnt) return;
    int n0 = nt * 128;

    __shared__ __align__(16) unsigned short As[2][128][32];
    __shared__ __align__(16) unsigned short Bs[2][128][32];
    __shared__ int rtok[128];

    int tid = threadIdx.x;
    int lane = tid & 63;
    int w = tid >> 6;
    int wr = w >> 1, wc = w & 1;
    int lr = lane & 15, lg = lane >> 4;

    if (tid < 128) {
        int p = row0 + tid;
        rtok[tid] = (p < cnt) ? toks[e * CAP + p] : -1;
    }
    __syncthreads();

    int srow = lane >> 2;
    // source-side XOR swizzle: LDS slot (lane&3) <- global chunk (lane&3)^((lane>>3)&3)
    int scol = (((lane & 3) ^ ((lane >> 3) & 3)) * 8);
    // read-side: k-chunk lg lives at LDS slot lg^((lr>>1)&3)
    int slt = (lg ^ ((lr >> 1) & 3)) * 8;

    const unsigned short* gaA[2];
    const unsigned short* gaB[2];
    const unsigned short* gupE = gupT + (size_t)e * HDIM * F2;
#pragma unroll
    for (int i = 0; i < 2; ++i) {
        int arow = w * 32 + i * 16 + srow;
        int tk = rtok[arow];
        gaA[i] = (tk >= 0) ? (xb + (size_t)tk * HDIM + scol) : (zp + scol);
        int brow = n0 + w * 32 + i * 16 + srow;
        gaB[i] = gupE + (size_t)brow * HDIM + scol;
    }

    f32x4 acc[4][4];
#pragma unroll
    for (int m = 0; m < 4; ++m)
#pragma unroll
        for (int n = 0; n < 4; ++n) acc[m][n] = (f32x4){0.f, 0.f, 0.f, 0.f};

    const int NT = HDIM / 32;
#pragma unroll
    for (int i = 0; i < 2; ++i) {
        GLD_LDS16(gaA[i], &As[0][w * 32 + i * 16][0]);
        GLD_LDS16(gaB[i], &Bs[0][w * 32 + i * 16][0]);
    }
    __syncthreads();

    int cur = 0;
    for (int kb = 0; kb < NT; ++kb) {
        if (kb + 1 < NT) {
#pragma unroll
            for (int i = 0; i < 2; ++i) {
                GLD_LDS16(gaA[i] + (kb + 1) * 32, &As[cur ^ 1][w * 32 + i * 16][0]);
                GLD_LDS16(gaB[i] + (kb + 1) * 32, &Bs[cur ^ 1][w * 32 + i * 16][0]);
            }
        }
        short8 af[4], bfr[4];
#pragma unroll
        for (int m = 0; m < 4; ++m) af[m] = *(const short8*)&As[cur][wr * 64 + m * 16 + lr][slt];
#pragma unroll
        for (int n = 0; n < 4; ++n) bfr[n] = *(const short8*)&Bs[cur][wc * 64 + n * 16 + lr][slt];
#pragma unroll
        for (int m = 0; m < 4; ++m)
#pragma unroll
            for (int n = 0; n < 4; ++n)
                acc[m][n] = __builtin_amdgcn_mfma_f32_16x16x32_bf16(af[m], bfr[n], acc[m][n], 0, 0, 0);
        __syncthreads();
        cur ^= 1;
    }

    // epilogue: permuted B rows => acc[m][2q]=gate, acc[m][2q+1]=up of SAME feature, same lane
    unsigned short* actE = act + (size_t)e * CAP2 * NI;
    int fbase = nt * 64 + wc * 32;
#pragma unroll
    for (int q = 0; q < 2; ++q) {
        int f = fbase + q * 16 + lr;                  // act feature index (0..511)
        float bg = gub[e * F2 + 2 * f];
        float bu = gub[e * F2 + 2 * f + 1];
#pragma unroll
        for (int m = 0; m < 4; ++m) {
#pragma unroll
            for (int r = 0; r < 4; ++r) {
                float gate = acc[m][2 * q][r] + bg;
                float up   = acc[m][2 * q + 1][r] + bu;
                gate = fminf(gate, LIMIT);
                up   = fminf(fmaxf(up, -LIMIT), LIMIT);
                float glu = gate / (1.0f + __expf(-ALPHA * gate));
                float av  = (up + 1.0f) * glu;
                int row = row0 + wr * 64 + m * 16 + lg * 4 + r;
                actE[(size_t)row * NI + f] = f2bf(av);
            }
        }
    }
}

// ------- GEMM2 (tier A): act @ dwnT^T, *score, +bias -> compact bf16 y[base[e]+p][HDIM] -------
__global__ __launch_bounds__(256) void gemm2_y_kernel(
    const unsigned short* __restrict__ act, const unsigned short* __restrict__ dwnT,
    const float* __restrict__ dwb,
    const int* __restrict__ counts, const float* __restrict__ wgts,
    unsigned short* __restrict__ y)
{
    int b = blockIdx.x;
    int e = b & 15;
    int j = b >> 4;
    int nt = j & 7;
    int mt = j >> 3;
    int cnt = counts[e];
    int row0 = mt * 128;
    if (row0 >= cnt) return;
    int n0 = nt * 128;

    int base_e = 0;
#pragma unroll
    for (int q = 0; q < NE; ++q) base_e += (q < e) ? counts[q] : 0;

    __shared__ __align__(16) unsigned short As[2][128][32];
    __shared__ __align__(16) unsigned short Bs[2][128][32];
    __shared__ float rwgt[128];

    int tid = threadIdx.x;
    int lane = tid & 63;
    int w = tid >> 6;
    int wr = w >> 1, wc = w & 1;
    int lr = lane & 15, lg = lane >> 4;

    if (tid < 128) {
        int p = row0 + tid;
        rwgt[tid] = (p < cnt) ? wgts[e * CAP + p] : 0.0f;
    }
    __syncthreads();

    int srow = lane >> 2;
    int scol = (((lane & 3) ^ ((lane >> 3) & 3)) * 8);
    int slt = (lg ^ ((lr >> 1) & 3)) * 8;

    const unsigned short* gaA[2];
    const unsigned short* gaB[2];
    const unsigned short* actE = act + (size_t)e * CAP2 * NI;
    const unsigned short* dwnE = dwnT + (size_t)e * HDIM * NI;
#pragma unroll
    for (int i = 0; i < 2; ++i) {
        int arow = row0 + w * 32 + i * 16 + srow;
        gaA[i] = actE + (size_t)arow * NI + scol;
        int brow = n0 + w * 32 + i * 16 + srow;
        gaB[i] = dwnE + (size_t)brow * NI + scol;
    }

    f32x4 acc[4][4];
#pragma unroll
    for (int m = 0; m < 4; ++m)
#pragma unroll
        for (int n = 0; n < 4; ++n) acc[m][n] = (f32x4){0.f, 0.f, 0.f, 0.f};

    const int NT = NI / 32;
#pragma unroll
    for (int i = 0; i < 2; ++i) {
        GLD_LDS16(gaA[i], &As[0][w * 32 + i * 16][0]);
        GLD_LDS16(gaB[i], &Bs[0][w * 32 + i * 16][0]);
    }
    __syncthreads();

    int cur = 0;
    for (int kb = 0; kb < NT; ++kb) {
        if (kb + 1 < NT) {
#pragma unroll
            for (int i = 0; i < 2; ++i) {
                GLD_LDS16(gaA[i] + (kb + 1) * 32, &As[cur ^ 1][w * 32 + i * 16][0]);
                GLD_LDS16(gaB[i] + (kb + 1) * 32, &Bs[cur ^ 1][w * 32 + i * 16][0]);
            }
        }
        short8 af[4], bfr[4];
#pragma unroll
        for (int m = 0; m < 4; ++m) af[m] = *(const short8*)&As[cur][wr * 64 + m * 16 + lr][slt];
#pragma unroll
        for (int n = 0; n < 4; ++n) bfr[n] = *(const short8*)&Bs[cur][wc * 64 + n * 16 + lr][slt];
#pragma unroll
        for (int m = 0; m < 4; ++m)
#pragma unroll
            for (int n = 0; n < 4; ++n)
                acc[m][n] = __builtin_amdgcn_mfma_f32_16x16x32_bf16(af[m], bfr[n], acc[m][n], 0, 0, 0);
        __syncthreads();
        cur ^= 1;
    }

    unsigned short* yB = y + (size_t)(base_e + row0) * HDIM;
#pragma unroll
    for (int n = 0; n < 4; ++n) {
        int hc = n0 + wc * 64 + n * 16 + lr;
        float db = dwb[e * HDIM + hc];
#pragma unroll
        for (int m = 0; m < 4; ++m) {
#pragma unroll
            for (int r = 0; r < 4; ++r) {
                int rl = wr * 64 + m * 16 + lg * 4 + r;
                if (row0 + rl < cnt)
                    yB[(size_t)rl * HDIM + hc] = f2bf(rwgt[rl] * (acc[m][n][r] + db));
            }
        }
    }
}

// ------- out combine: out[t] = y[slot0] + y[slot1]; bf16 reads, coalesced, no atomics -------
__global__ __launch_bounds__(256) void out_combine_kernel(
    const unsigned short* __restrict__ y, const unsigned short* __restrict__ inv,
    const int* __restrict__ counts, float* __restrict__ out)
{
    __shared__ int sbase[NE];
    int tid = threadIdx.x;
    int t = blockIdx.x;
    if (tid == 0) {
        int s = 0;
#pragma unroll
        for (int e = 0; e < NE; ++e) { sbase[e] = s; s += counts[e]; }
    }
    __syncthreads();
    unsigned short v0 = inv[2 * t], v1 = inv[2 * t + 1];
    int s0 = sbase[v0 >> 11] + (v0 & 2047);
    int s1 = sbase[v1 >> 11] + (v1 & 2047);
    short4v a = *(const short4v*)(y + (size_t)s0 * HDIM + tid * 4);
    short4v c = *(const short4v*)(y + (size_t)s1 * HDIM + tid * 4);
    float4 o;
    o.x = bf2f((unsigned short)a[0]) + bf2f((unsigned short)c[0]);
    o.y = bf2f((unsigned short)a[1]) + bf2f((unsigned short)c[1]);
    o.z = bf2f((unsigned short)a[2]) + bf2f((unsigned short)c[2]);
    o.w = bf2f((unsigned short)a[3]) + bf2f((unsigned short)c[3]);
    *(float4*)(out + (size_t)t * HDIM + tid * 4) = o;
}

// ================= fallback path kernels (round-1 style, small ws) =================
__global__ __launch_bounds__(256) void router_kernel(
    const float* __restrict__ x, const float* __restrict__ rw,
    int* __restrict__ counts, int* __restrict__ toks, float* __restrict__ wgts)
{
    int gwave = (int)((blockIdx.x * 256 + threadIdx.x) >> 6);
    int lane = threadIdx.x & 63;
    if (gwave >= TOK) return;
    const float* xr = x + (size_t)gwave * HDIM;
    double acc[NE];
#pragma unroll
    for (int e = 0; e < NE; ++e) acc[e] = 0.0;
    for (int i = 0; i < HDIM / 64; ++i) {
        int h = i * 64 + lane;
        double xv = (double)xr[h];
        const float* r = rw + (size_t)h * NE;
#pragma unroll
        for (int e = 0; e < NE; ++e) acc[e] += xv * (double)r[e];
    }
#pragma unroll
    for (int e = 0; e < NE; ++e) {
        double v = acc[e];
#pragma unroll
        for (int off = 32; off > 0; off >>= 1) v += __shfl_xor(v, off);
        acc[e] = v;
    }
    if (lane == 0) {
        int i0 = 0; double v0 = acc[0];
#pragma unroll
        for (int e = 1; e < NE; ++e) if (acc[e] > v0) { v0 = acc[e]; i0 = e; }
        int i1 = -1; double v1 = -1e300;
#pragma unroll
        for (int e = 0; e < NE; ++e) if (e != i0 && acc[e] > v1) { v1 = acc[e]; i1 = e; }
        double e1 = exp(v1 - v0);
        float w0 = (float)(1.0 / (1.0 + e1));
        float w1 = (float)(e1 / (1.0 + e1));
        int p0 = atomicAdd(&counts[i0], 1);
        toks[i0 * CAP + p0] = gwave; wgts[i0 * CAP + p0] = w0;
        int p1 = atomicAdd(&counts[i1], 1);
        toks[i1 * CAP + p1] = gwave; wgts[i1 * CAP + p1] = w1;
    }
}

__global__ __launch_bounds__(256) void moe_kernel(
    const float* __restrict__ x,
    const float* __restrict__ gup, const float* __restrict__ gub,
    const float* __restrict__ dwn, const float* __restrict__ dwb,
    const int* __restrict__ counts, const int* __restrict__ toks,
    const float* __restrict__ wgts, float* __restrict__ out)
{
    int e = blockIdx.y;
    int cnt = counts[e];
    int row0 = blockIdx.x * 64;
    if (row0 >= cnt) return;

    __shared__ __align__(16) unsigned short sA[64][40];
    __shared__ __align__(16) unsigned short sB[64][40];
    __shared__ __align__(16) unsigned short sAct[64][520];
    __shared__ int   rtok[64];
    __shared__ float rwgt[64];

    int tid = threadIdx.x;
    if (tid < 64) {
        int idx = row0 + tid;
        bool v = idx < cnt;
        rtok[tid] = v ? toks[e * CAP + idx] : -1;
        rwgt[tid] = v ? wgts[e * CAP + idx] : 0.0f;
    }
    __syncthreads();

    int lane = tid & 63;
    int w = tid >> 6;
    int wr = w >> 1, wc = w & 1;
    int lr = lane & 15, lg = lane >> 4;
    int ar = tid >> 2, ac0 = (tid & 3) * 8;
    int bk = tid >> 3, bf0 = (tid & 7) * 8;
    const float* gupE = gup + (size_t)e * HDIM * F2;

    for (int nb = 0; nb < F2 / 64; ++nb) {
        f32x4 acc[2][2];
#pragma unroll
        for (int mi = 0; mi < 2; ++mi)
#pragma unroll
            for (int ni = 0; ni < 2; ++ni) acc[mi][ni] = (f32x4){0.f, 0.f, 0.f, 0.f};
        for (int kb = 0; kb < HDIM / 32; ++kb) {
            __syncthreads();
            {
                int tk = rtok[ar];
                short8 vv = {0,0,0,0,0,0,0,0};
                if (tk >= 0) {
                    const float* p = x + (size_t)tk * HDIM + kb * 32 + ac0;
                    float4 u0 = *(const float4*)(p); float4 u1 = *(const float4*)(p + 4);
                    vv[0]=(short)f2bf(u0.x); vv[1]=(short)f2bf(u0.y); vv[2]=(short)f2bf(u0.z); vv[3]=(short)f2bf(u0.w);
                    vv[4]=(short)f2bf(u1.x); vv[5]=(short)f2bf(u1.y); vv[6]=(short)f2bf(u1.z); vv[7]=(short)f2bf(u1.w);
                }
                *(short8*)&sA[ar][ac0] = vv;
            }
            {
                const float* p = gupE + (size_t)(kb * 32 + bk) * F2 + nb * 64 + bf0;
                float4 u0 = *(const float4*)(p); float4 u1 = *(const float4*)(p + 4);
                sB[bf0+0][bk]=f2bf(u0.x); sB[bf0+1][bk]=f2bf(u0.y); sB[bf0+2][bk]=f2bf(u0.z); sB[bf0+3][bk]=f2bf(u0.w);
                sB[bf0+4][bk]=f2bf(u1.x); sB[bf0+5][bk]=f2bf(u1.y); sB[bf0+6][bk]=f2bf(u1.z); sB[bf0+7][bk]=f2bf(u1.w);
            }
            __syncthreads();
            short8 a0 = *(const short8*)&sA[wr*32+lr][lg*8];
            short8 a1 = *(const short8*)&sA[wr*32+16+lr][lg*8];
            short8 b0 = *(const short8*)&sB[wc*32+lr][lg*8];
            short8 b1 = *(const short8*)&sB[wc*32+16+lr][lg*8];
            acc[0][0] = __builtin_amdgcn_mfma_f32_16x16x32_bf16(a0,b0,acc[0][0],0,0,0);
            acc[0][1] = __builtin_amdgcn_mfma_f32_16x16x32_bf16(a0,b1,acc[0][1],0,0,0);
            acc[1][0] = __builtin_amdgcn_mfma_f32_16x16x32_bf16(a1,b0,acc[1][0],0,0,0);
            acc[1][1] = __builtin_amdgcn_mfma_f32_16x16x32_bf16(a1,b1,acc[1][1],0,0,0);
        }
#pragma unroll
        for (int ni = 0; ni < 2; ++ni) {
            int fc = nb * 64 + wc * 32 + ni * 16 + lr;
            float bias = gub[e * F2 + fc];
#pragma unroll
            for (int mi = 0; mi < 2; ++mi)
#pragma unroll
                for (int r = 0; r < 4; ++r) {
                    float gu = acc[mi][ni][r] + bias;
                    float other = __shfl_xor(gu, 1);
                    float gate = (lr & 1) ? other : gu;
                    float up   = (lr & 1) ? gu : other;
                    gate = fminf(gate, LIMIT);
                    up = fminf(fmaxf(up, -LIMIT), LIMIT);
                    float glu = gate / (1.0f + __expf(-ALPHA * gate));
                    float av = (up + 1.0f) * glu;
                    if (!(lr & 1)) sAct[wr*32+mi*16+lg*4+r][fc >> 1] = f2bf(av);
                }
        }
    }
    __syncthreads();

    const float* dwnE = dwn + (size_t)e * NI * HDIM;
    int tks[2][4]; float wvs[2][4];
#pragma unroll
    for (int mi = 0; mi < 2; ++mi)
#pragma unroll
        for (int r = 0; r < 4; ++r) {
            int row = wr*32 + mi*16 + lg*4 + r;
            tks[mi][r] = rtok[row]; wvs[mi][r] = rwgt[row];
        }
    for (int nb = 0; nb < HDIM / 64; ++nb) {
        f32x4 acc[2][2];
#pragma unroll
        for (int mi = 0; mi < 2; ++mi)
#pragma unroll
            for (int ni = 0; ni < 2; ++ni) acc[mi][ni] = (f32x4){0.f,0.f,0.f,0.f};
        for (int kb = 0; kb < NI / 32; ++kb) {
            __syncthreads();
            {
                const float* p = dwnE + (size_t)(kb*32 + bk) * HDIM + nb*64 + bf0;
                float4 u0 = *(const float4*)(p); float4 u1 = *(const float4*)(p + 4);
                sB[bf0+0][bk]=f2bf(u0.x); sB[bf0+1][bk]=f2bf(u0.y); sB[bf0+2][bk]=f2bf(u0.z); sB[bf0+3][bk]=f2bf(u0.w);
                sB[bf0+4][bk]=f2bf(u1.x); sB[bf0+5][bk]=f2bf(u1.y); sB[bf0+6][bk]=f2bf(u1.z); sB[bf0+7][bk]=f2bf(u1.w);
            }
            __syncthreads();
            short8 a0 = *(const short8*)&sAct[wr*32+lr][kb*32+lg*8];
            short8 a1 = *(const short8*)&sAct[wr*32+16+lr][kb*32+lg*8];
            short8 b0 = *(const short8*)&sB[wc*32+lr][lg*8];
            short8 b1 = *(const short8*)&sB[wc*32+16+lr][lg*8];
            acc[0][0] = __builtin_amdgcn_mfma_f32_16x16x32_bf16(a0,b0,acc[0][0],0,0,0);
            acc[0][1] = __builtin_amdgcn_mfma_f32_16x16x32_bf16(a0,b1,acc[0][1],0,0,0);
            acc[1][0] = __builtin_amdgcn_mfma_f32_16x16x32_bf16(a1,b0,acc[1][0],0,0,0);
            acc[1][1] = __builtin_amdgcn_mfma_f32_16x16x32_bf16(a1,b1,acc[1][1],0,0,0);
        }
#pragma unroll
        for (int ni = 0; ni < 2; ++ni) {
            int hc = nb*64 + wc*32 + ni*16 + lr;
            float db = dwb[e * HDIM + hc];
#pragma unroll
            for (int mi = 0; mi < 2; ++mi)
#pragma unroll
                for (int r = 0; r < 4; ++r) {
                    int tk = tks[mi][r];
                    if (tk >= 0)
                        atomicAdd(out + (size_t)tk * HDIM + hc, wvs[mi][r] * (acc[mi][ni][r] + db));
                }
        }
    }
}

extern "C" void kernel_launch(void* const* d_in, const int* in_sizes, int n_in,
                              void* d_out, int out_size, void* d_ws, size_t ws_size,
                              hipStream_t stream) {
    const float* x   = (const float*)d_in[0];
    const float* rw  = (const float*)d_in[1];
    const float* gup = (const float*)d_in[2];
    const float* gub = (const float*)d_in[3];
    const float* dwn = (const float*)d_in[4];
    const float* dwb = (const float*)d_in[5];
    float* out = (float*)d_out;

    // ---- ws layout ----
    const size_t OFF_COUNTS = 0;                                   // 256 B
    const size_t OFF_ZP     = 256;                                 // 4 KB zero page
    const size_t OFF_INV    = 4352;                                // 32 KB
    const size_t OFF_TOKS   = OFF_INV  + (size_t)TOK * 2 * 2;
    const size_t OFF_WGTS   = OFF_TOKS + (size_t)NE * CAP * 4;
    const size_t OFF_DWNT   = OFF_WGTS + (size_t)NE * CAP * 4;
    const size_t OFF_ACT    = OFF_DWNT + (size_t)NE * NI * HDIM * 2;   // part (4MB) aliases here
    const size_t OFF_XBF    = OFF_ACT  + (size_t)NE * CAP2 * NI * 2;
    const size_t OFF_GUPT   = OFF_XBF  + (size_t)TOK * HDIM * 2;
    const size_t REQ_B      = OFF_GUPT + (size_t)NE * HDIM * F2 * 2;
    const size_t OFF_Y      = OFF_XBF;                             // aliases xbf+gupT (dead after gemm1)
    const size_t REQ_A      = OFF_Y + (size_t)2 * TOK * HDIM * 2;  // 32 MB compact bf16 y

    if (ws_size >= REQ_B) {
        int*            counts = (int*)((char*)d_ws + OFF_COUNTS);
        unsigned short* zp     = (unsigned short*)((char*)d_ws + OFF_ZP);
        unsigned short* inv    = (unsigned short*)((char*)d_ws + OFF_INV);
        int*            toks   = (int*)((char*)d_ws + OFF_TOKS);
        float*          wgts   = (float*)((char*)d_ws + OFF_WGTS);
        unsigned short* dwnT   = (unsigned short*)((char*)d_ws + OFF_DWNT);
        unsigned short* act    = (unsigned short*)((char*)d_ws + OFF_ACT);
        double*         part   = (double*)((char*)d_ws + OFF_ACT);
        unsigned short* xbf    = (unsigned short*)((char*)d_ws + OFF_XBF);
        unsigned short* gupT   = (unsigned short*)((char*)d_ws + OFF_GUPT);
        unsigned short* y      = (unsigned short*)((char*)d_ws + OFF_Y);

        hipMemsetAsync(d_ws, 0, 4352, stream);   // counts + zero page

        dim3 tg1(F2 / 64, HDIM / 64, NE);
        transpose_kernel<<<tg1, 256, 0, stream>>>(gup, gupT, HDIM, F2, 1);   // gate/up permuted
        dim3 tg2(HDIM / 64, NI / 64, NE);
        transpose_kernel<<<tg2, 256, 0, stream>>>(dwn, dwnT, NI, HDIM, 0);

        router_partial_kernel<<<(TOK / 16) * 4, 64, 0, stream>>>(x, rw, part, xbf);
        router_combine_kernel<<<TOK / 256, 256, 0, stream>>>(part, counts, toks, wgts, inv);

        int g1 = (CAP2 / 128) * (F2 / 128) * NE;     // 2048
        gemm1_kernel<<<g1, 256, 0, stream>>>(xbf, gupT, gub, counts, toks, act, zp);
        int g2 = (CAP2 / 128) * (HDIM / 128) * NE;   // 2048

        if (ws_size >= REQ_A) {
            gemm2_y_kernel<<<g2, 256, 0, stream>>>(act, dwnT, dwb, counts, wgts, y);
            out_combine_kernel<<<TOK, 256, 0, stream>>>(y, inv, counts, out);
        } else {
            hipMemsetAsync(d_out, 0, (size_t)out_size * sizeof(float), stream);
            // (unreachable in practice: REQ_A < REQ_B)
            out_combine_kernel<<<TOK, 256, 0, stream>>>(y, inv, counts, out);
        }
    } else {
        // fallback: round-1 path (~1.1 MB of ws)
        int*   counts = (int*)d_ws;
        int*   toks   = (int*)((char*)d_ws + 64);
        float* wgts   = (float*)((char*)d_ws + 64 + (size_t)NE * CAP * sizeof(int));
        hipMemsetAsync(d_ws, 0, 64, stream);
        hipMemsetAsync(d_out, 0, (size_t)out_size * sizeof(float), stream);
        router_kernel<<<TOK / 4, 256, 0, stream>>>(x, rw, counts, toks, wgts);
        dim3 gm(TOK / 64, NE);
        moe_kernel<<<gm, 256, 0, stream>>>(x, gup, gub, dwn, dwb, counts, toks, wgts, out);
    }
}

// Round 7
// 173.564 us; speedup vs baseline: 6.8236x; 1.0500x over previous
//
#include <hip/hip_runtime.h>
#include <hip/hip_bf16.h>
#include <math.h>

#define TOK   8192
#define HDIM  1024
#define NE    16
#define NI    512
#define F2    1024
#define CAP   8192
#define CAP2  2048
#define ALPHA 1.702f
#define LIMIT 7.0f

typedef __attribute__((ext_vector_type(8))) short short8;
typedef __attribute__((ext_vector_type(4))) short short4v;
typedef __attribute__((ext_vector_type(4))) float f32x4;

static __device__ __forceinline__ unsigned short f2bf(float f) {
    unsigned int u = __float_as_uint(f);
    u += 0x7FFFu + ((u >> 16) & 1u);
    return (unsigned short)(u >> 16);
}
static __device__ __forceinline__ float bf2f(unsigned short u) {
    return __uint_as_float((unsigned int)u << 16);
}

#define GLD_LDS16(g, l) __builtin_amdgcn_global_load_lds(                     \
    (const __attribute__((address_space(1))) void*)(g),                       \
    (__attribute__((address_space(3))) void*)(l), 16, 0, 0)

// ================= router phase A: fp64 partial logits, fused x->bf16 =================
__global__ __launch_bounds__(64) void router_partial_kernel(
    const float* __restrict__ x, const float* __restrict__ rw,
    double* __restrict__ part, unsigned short* __restrict__ xbf)
{
    int bx = blockIdx.x;
    int tile = bx >> 2, ksl = bx & 3;
    int t0 = tile * 16;
    int hbase = ksl * 256;

    __shared__ __align__(16) float sx[16][68];
    __shared__ __align__(16) float srw[64][16];

    int lane = threadIdx.x;
    int tt = lane & 15, eg = lane >> 4;

    double acc[4] = {0.0, 0.0, 0.0, 0.0};

    for (int hc = 0; hc < 4; ++hc) {
        int h0 = hbase + hc * 64;
        __syncthreads();
#pragma unroll
        for (int j = 0; j < 4; ++j) {
            int fidx = j * 64 + lane;
            int t = fidx >> 4, c4 = (fidx & 15) * 4;
            float4 v = *(const float4*)(x + (size_t)(t0 + t) * HDIM + h0 + c4);
            *(float4*)&sx[t][c4] = v;
            short4v s;
            s[0] = (short)f2bf(v.x); s[1] = (short)f2bf(v.y);
            s[2] = (short)f2bf(v.z); s[3] = (short)f2bf(v.w);
            *(short4v*)(xbf + (size_t)(t0 + t) * HDIM + h0 + c4) = s;
        }
#pragma unroll
        for (int j = 0; j < 4; ++j) {
            int ridx = j * 64 + lane;
            int h = ridx >> 2, e4 = (ridx & 3) * 4;
            float4 v = *(const float4*)(rw + (size_t)(h0 + h) * NE + e4);
            *(float4*)&srw[h][e4] = v;
        }
        __syncthreads();
#pragma unroll 8
        for (int j = 0; j < 64; ++j) {
            float xv = sx[tt][j];
            float4 wv = *(const float4*)&srw[j][eg * 4];
            double xd = (double)xv;
            acc[0] += xd * (double)wv.x;
            acc[1] += xd * (double)wv.y;
            acc[2] += xd * (double)wv.z;
            acc[3] += xd * (double)wv.w;
        }
    }
#pragma unroll
    for (int q = 0; q < 4; ++q)
        part[(size_t)(ksl * NE + eg * 4 + q) * TOK + t0 + tt] = acc[q];
}

// ===== router phase B: combine, top-2, softmax, aggregated scatter + inverse map =====
__global__ __launch_bounds__(256) void router_combine_kernel(
    const double* __restrict__ part,
    int* __restrict__ counts, int* __restrict__ toks, float* __restrict__ wgts,
    unsigned short* __restrict__ inv)
{
    __shared__ int lhist[NE];
    __shared__ int lbase[NE];
    int tid = threadIdx.x;
    int t = blockIdx.x * 256 + tid;
    if (tid < NE) lhist[tid] = 0;
    __syncthreads();

    double acc[NE];
#pragma unroll
    for (int e = 0; e < NE; ++e)
        acc[e] = part[(size_t)(0 * NE + e) * TOK + t]
               + part[(size_t)(1 * NE + e) * TOK + t]
               + part[(size_t)(2 * NE + e) * TOK + t]
               + part[(size_t)(3 * NE + e) * TOK + t];

    int i0 = 0; double v0 = acc[0];
#pragma unroll
    for (int e = 1; e < NE; ++e) if (acc[e] > v0) { v0 = acc[e]; i0 = e; }
    int i1 = -1; double v1 = -1e300;
#pragma unroll
    for (int e = 0; e < NE; ++e) if (e != i0 && acc[e] > v1) { v1 = acc[e]; i1 = e; }
    double e1 = exp(v1 - v0);
    float w0 = (float)(1.0 / (1.0 + e1));
    float w1 = (float)(e1 / (1.0 + e1));

    int r0 = atomicAdd(&lhist[i0], 1);
    int r1 = atomicAdd(&lhist[i1], 1);
    __syncthreads();
    if (tid < NE) lbase[tid] = atomicAdd(&counts[tid], lhist[tid]);
    __syncthreads();
    int p0 = lbase[i0] + r0; if (p0 > 2047) p0 = 2047;
    int p1 = lbase[i1] + r1; if (p1 > 2047) p1 = 2047;
    toks[i0 * CAP + p0] = t; wgts[i0 * CAP + p0] = w0;
    toks[i1 * CAP + p1] = t; wgts[i1 * CAP + p1] = w1;
    inv[2 * t]     = (unsigned short)((i0 << 11) | p0);
    inv[2 * t + 1] = (unsigned short)((i1 << 11) | p1);
}

// ------------- transpose + convert: in [E][R][C] fp32 -> out [E][C][R] bf16 -------------
__global__ __launch_bounds__(256) void transpose_kernel(
    const float* __restrict__ in, unsigned short* __restrict__ out, int R, int C, int perm)
{
    int e = blockIdx.z;
    const float* pin = in + (size_t)e * R * C;
    unsigned short* pout = out + (size_t)e * R * C;
    __shared__ float t2[64][65];
    int c0 = blockIdx.x * 64, r0 = blockIdx.y * 64;
    int tid = threadIdx.x;
#pragma unroll
    for (int j = 0; j < 4; ++j) {
        int idx4 = j * 256 + tid;
        int r = idx4 >> 4, c4 = (idx4 & 15) * 4;
        float4 v = *(const float4*)(pin + (size_t)(r0 + r) * C + c0 + c4);
        t2[c4 + 0][r] = v.x;
        t2[c4 + 1][r] = v.y;
        t2[c4 + 2][r] = v.z;
        t2[c4 + 3][r] = v.w;
    }
    __syncthreads();
#pragma unroll
    for (int j = 0; j < 2; ++j) {
        int idx = j * 256 + tid;
        int n = idx >> 3, k0 = (idx & 7) * 8;
        short8 v;
#pragma unroll
        for (int q = 0; q < 8; ++q) v[q] = (short)f2bf(t2[n][k0 + q]);
        int c = c0 + n;
        int orow;
        if (perm) {
            int tile = c >> 7, ct = c & 127;
            int fl = ct >> 1, h = ct & 1;
            orow = (tile << 7) | ((fl >> 4) << 5) | (h << 4) | (fl & 15);
        } else {
            orow = c;
        }
        *(short8*)(pout + (size_t)orow * R + r0 + k0) = v;
    }
}

// ===== counted-vmcnt 2-phase K-loop (T4): 4 gld_lds/tile/thread, vmcnt(4) before barrier =====
#define KLOOP_BODY(NT, KOFF)                                                          \
    int cur = 0;                                                                      \
    for (int kb = 0; kb < (NT); ++kb) {                                               \
        if (kb + 1 < (NT)) {                                                          \
            _Pragma("unroll")                                                         \
            for (int i = 0; i < 2; ++i) {                                             \
                GLD_LDS16(gaA[i] + (kb + 1) * (KOFF), &As[cur ^ 1][w * 32 + i * 16][0]); \
                GLD_LDS16(gaB[i] + (kb + 1) * (KOFF), &Bs[cur ^ 1][w * 32 + i * 16][0]); \
            }                                                                         \
            asm volatile("s_waitcnt vmcnt(4)" ::: "memory");                          \
        } else {                                                                      \
            asm volatile("s_waitcnt vmcnt(0)" ::: "memory");                          \
        }                                                                             \
        __builtin_amdgcn_sched_barrier(0);                                            \
        __builtin_amdgcn_s_barrier();                                                 \
        __builtin_amdgcn_sched_barrier(0);                                            \
        short8 af[4], bfr[4];                                                         \
        _Pragma("unroll")                                                             \
        for (int m = 0; m < 4; ++m) af[m] = *(const short8*)&As[cur][wr * 64 + m * 16 + lr][slt]; \
        _Pragma("unroll")                                                             \
        for (int n = 0; n < 4; ++n) bfr[n] = *(const short8*)&Bs[cur][wc * 64 + n * 16 + lr][slt]; \
        _Pragma("unroll")                                                             \
        for (int m = 0; m < 4; ++m)                                                   \
            _Pragma("unroll")                                                         \
            for (int n = 0; n < 4; ++n)                                               \
                acc[m][n] = __builtin_amdgcn_mfma_f32_16x16x32_bf16(af[m], bfr[n], acc[m][n], 0, 0, 0); \
        asm volatile("s_waitcnt lgkmcnt(0)" ::: "memory");                            \
        __builtin_amdgcn_sched_barrier(0);                                            \
        __builtin_amdgcn_s_barrier();                                                 \
        __builtin_amdgcn_sched_barrier(0);                                            \
        cur ^= 1;                                                                     \
    }

// ---------------- GEMM1: x_bf (gathered) @ gupT^T + bias -> act (bf16) ----------------
__global__ __launch_bounds__(256) void gemm1_kernel(
    const unsigned short* __restrict__ xb, const unsigned short* __restrict__ gupT,
    const float* __restrict__ gub,
    const int* __restrict__ counts, const int* __restrict__ toks,
    unsigned short* __restrict__ act, const unsigned short* __restrict__ zp)
{
    int b = blockIdx.x;
    int e = b & 15;
    int j = b >> 4;
    int nt = j & 7;
    int mt = j >> 3;
    int cnt = counts[e];
    int row0 = mt * 128;
    if (row0 >= cnt) return;
    int n0 = nt * 128;

    __shared__ __align__(16) unsigned short As[2][128][32];
    __shared__ __align__(16) unsigned short Bs[2][128][32];
    __shared__ int rtok[128];

    int tid = threadIdx.x;
    int lane = tid & 63;
    int w = tid >> 6;
    int wr = w >> 1, wc = w & 1;
    int lr = lane & 15, lg = lane >> 4;

    if (tid < 128) {
        int p = row0 + tid;
        rtok[tid] = (p < cnt) ? toks[e * CAP + p] : -1;
    }
    __syncthreads();

    int srow = lane >> 2;
    int scol = (((lane & 3) ^ ((lane >> 3) & 3)) * 8);
    int slt = (lg ^ ((lr >> 1) & 3)) * 8;

    const unsigned short* gaA[2];
    const unsigned short* gaB[2];
    const unsigned short* gupE = gupT + (size_t)e * HDIM * F2;
#pragma unroll
    for (int i = 0; i < 2; ++i) {
        int arow = w * 32 + i * 16 + srow;
        int tk = rtok[arow];
        gaA[i] = (tk >= 0) ? (xb + (size_t)tk * HDIM + scol) : (zp + scol);
        int brow = n0 + w * 32 + i * 16 + srow;
        gaB[i] = gupE + (size_t)brow * HDIM + scol;
    }

    f32x4 acc[4][4];
#pragma unroll
    for (int m = 0; m < 4; ++m)
#pragma unroll
        for (int n = 0; n < 4; ++n) acc[m][n] = (f32x4){0.f, 0.f, 0.f, 0.f};

#pragma unroll
    for (int i = 0; i < 2; ++i) {
        GLD_LDS16(gaA[i], &As[0][w * 32 + i * 16][0]);
        GLD_LDS16(gaB[i], &Bs[0][w * 32 + i * 16][0]);
    }

    KLOOP_BODY(HDIM / 32, 32)

    // epilogue: permuted B rows => acc[m][2q]=gate, acc[m][2q+1]=up of SAME feature, same lane
    unsigned short* actE = act + (size_t)e * CAP2 * NI;
    int fbase = nt * 64 + wc * 32;
#pragma unroll
    for (int q = 0; q < 2; ++q) {
        int f = fbase + q * 16 + lr;
        float bg = gub[e * F2 + 2 * f];
        float bu = gub[e * F2 + 2 * f + 1];
#pragma unroll
        for (int m = 0; m < 4; ++m) {
#pragma unroll
            for (int r = 0; r < 4; ++r) {
                float gate = acc[m][2 * q][r] + bg;
                float up   = acc[m][2 * q + 1][r] + bu;
                gate = fminf(gate, LIMIT);
                up   = fminf(fmaxf(up, -LIMIT), LIMIT);
                float glu = gate / (1.0f + __expf(-ALPHA * gate));
                float av  = (up + 1.0f) * glu;
                int row = row0 + wr * 64 + m * 16 + lg * 4 + r;
                actE[(size_t)row * NI + f] = f2bf(av);
            }
        }
    }
}

// ------- GEMM2 (tier A): act @ dwnT^T, *score, +bias -> compact bf16 y[base[e]+p][HDIM] -------
__global__ __launch_bounds__(256) void gemm2_y_kernel(
    const unsigned short* __restrict__ act, const unsigned short* __restrict__ dwnT,
    const float* __restrict__ dwb,
    const int* __restrict__ counts, const float* __restrict__ wgts,
    unsigned short* __restrict__ y)
{
    int b = blockIdx.x;
    int e = b & 15;
    int j = b >> 4;
    int nt = j & 7;
    int mt = j >> 3;
    int cnt = counts[e];
    int row0 = mt * 128;
    if (row0 >= cnt) return;
    int n0 = nt * 128;

    int base_e = 0;
#pragma unroll
    for (int q = 0; q < NE; ++q) base_e += (q < e) ? counts[q] : 0;

    __shared__ __align__(16) unsigned short As[2][128][32];
    __shared__ __align__(16) unsigned short Bs[2][128][32];
    __shared__ float rwgt[128];

    int tid = threadIdx.x;
    int lane = tid & 63;
    int w = tid >> 6;
    int wr = w >> 1, wc = w & 1;
    int lr = lane & 15, lg = lane >> 4;

    if (tid < 128) {
        int p = row0 + tid;
        rwgt[tid] = (p < cnt) ? wgts[e * CAP + p] : 0.0f;
    }
    __syncthreads();

    int srow = lane >> 2;
    int scol = (((lane & 3) ^ ((lane >> 3) & 3)) * 8);
    int slt = (lg ^ ((lr >> 1) & 3)) * 8;

    const unsigned short* gaA[2];
    const unsigned short* gaB[2];
    const unsigned short* actE = act + (size_t)e * CAP2 * NI;
    const unsigned short* dwnE = dwnT + (size_t)e * HDIM * NI;
#pragma unroll
    for (int i = 0; i < 2; ++i) {
        int arow = row0 + w * 32 + i * 16 + srow;
        gaA[i] = actE + (size_t)arow * NI + scol;
        int brow = n0 + w * 32 + i * 16 + srow;
        gaB[i] = dwnE + (size_t)brow * NI + scol;
    }

    f32x4 acc[4][4];
#pragma unroll
    for (int m = 0; m < 4; ++m)
#pragma unroll
        for (int n = 0; n < 4; ++n) acc[m][n] = (f32x4){0.f, 0.f, 0.f, 0.f};

#pragma unroll
    for (int i = 0; i < 2; ++i) {
        GLD_LDS16(gaA[i], &As[0][w * 32 + i * 16][0]);
        GLD_LDS16(gaB[i], &Bs[0][w * 32 + i * 16][0]);
    }

    KLOOP_BODY(NI / 32, 32)

    unsigned short* yB = y + (size_t)(base_e + row0) * HDIM;
#pragma unroll
    for (int n = 0; n < 4; ++n) {
        int hc = n0 + wc * 64 + n * 16 + lr;
        float db = dwb[e * HDIM + hc];
#pragma unroll
        for (int m = 0; m < 4; ++m) {
#pragma unroll
            for (int r = 0; r < 4; ++r) {
                int rl = wr * 64 + m * 16 + lg * 4 + r;
                if (row0 + rl < cnt)
                    yB[(size_t)rl * HDIM + hc] = f2bf(rwgt[rl] * (acc[m][n][r] + db));
            }
        }
    }
}

// ------- out combine: out[t] = y[slot0] + y[slot1]; bf16 reads, coalesced, no atomics -------
__global__ __launch_bounds__(256) void out_combine_kernel(
    const unsigned short* __restrict__ y, const unsigned short* __restrict__ inv,
    const int* __restrict__ counts, float* __restrict__ out)
{
    __shared__ int sbase[NE];
    int tid = threadIdx.x;
    int t = blockIdx.x;
    if (tid == 0) {
        int s = 0;
#pragma unroll
        for (int e = 0; e < NE; ++e) { sbase[e] = s; s += counts[e]; }
    }
    __syncthreads();
    unsigned short v0 = inv[2 * t], v1 = inv[2 * t + 1];
    int s0 = sbase[v0 >> 11] + (v0 & 2047);
    int s1 = sbase[v1 >> 11] + (v1 & 2047);
    short4v a = *(const short4v*)(y + (size_t)s0 * HDIM + tid * 4);
    short4v c = *(const short4v*)(y + (size_t)s1 * HDIM + tid * 4);
    float4 o;
    o.x = bf2f((unsigned short)a[0]) + bf2f((unsigned short)c[0]);
    o.y = bf2f((unsigned short)a[1]) + bf2f((unsigned short)c[1]);
    o.z = bf2f((unsigned short)a[2]) + bf2f((unsigned short)c[2]);
    o.w = bf2f((unsigned short)a[3]) + bf2f((unsigned short)c[3]);
    *(float4*)(out + (size_t)t * HDIM + tid * 4) = o;
}

// ================= fallback path kernels (round-1 style, small ws) =================
__global__ __launch_bounds__(256) void router_kernel(
    const float* __restrict__ x, const float* __restrict__ rw,
    int* __restrict__ counts, int* __restrict__ toks, float* __restrict__ wgts)
{
    int gwave = (int)((blockIdx.x * 256 + threadIdx.x) >> 6);
    int lane = threadIdx.x & 63;
    if (gwave >= TOK) return;
    const float* xr = x + (size_t)gwave * HDIM;
    double acc[NE];
#pragma unroll
    for (int e = 0; e < NE; ++e) acc[e] = 0.0;
    for (int i = 0; i < HDIM / 64; ++i) {
        int h = i * 64 + lane;
        double xv = (double)xr[h];
        const float* r = rw + (size_t)h * NE;
#pragma unroll
        for (int e = 0; e < NE; ++e) acc[e] += xv * (double)r[e];
    }
#pragma unroll
    for (int e = 0; e < NE; ++e) {
        double v = acc[e];
#pragma unroll
        for (int off = 32; off > 0; off >>= 1) v += __shfl_xor(v, off);
        acc[e] = v;
    }
    if (lane == 0) {
        int i0 = 0; double v0 = acc[0];
#pragma unroll
        for (int e = 1; e < NE; ++e) if (acc[e] > v0) { v0 = acc[e]; i0 = e; }
        int i1 = -1; double v1 = -1e300;
#pragma unroll
        for (int e = 0; e < NE; ++e) if (e != i0 && acc[e] > v1) { v1 = acc[e]; i1 = e; }
        double e1 = exp(v1 - v0);
        float w0 = (float)(1.0 / (1.0 + e1));
        float w1 = (float)(e1 / (1.0 + e1));
        int p0 = atomicAdd(&counts[i0], 1);
        toks[i0 * CAP + p0] = gwave; wgts[i0 * CAP + p0] = w0;
        int p1 = atomicAdd(&counts[i1], 1);
        toks[i1 * CAP + p1] = gwave; wgts[i1 * CAP + p1] = w1;
    }
}

__global__ __launch_bounds__(256) void moe_kernel(
    const float* __restrict__ x,
    const float* __restrict__ gup, const float* __restrict__ gub,
    const float* __restrict__ dwn, const float* __restrict__ dwb,
    const int* __restrict__ counts, const int* __restrict__ toks,
    const float* __restrict__ wgts, float* __restrict__ out)
{
    int e = blockIdx.y;
    int cnt = counts[e];
    int row0 = blockIdx.x * 64;
    if (row0 >= cnt) return;

    __shared__ __align__(16) unsigned short sA[64][40];
    __shared__ __align__(16) unsigned short sB[64][40];
    __shared__ __align__(16) unsigned short sAct[64][520];
    __shared__ int   rtok[64];
    __shared__ float rwgt[64];

    int tid = threadIdx.x;
    if (tid < 64) {
        int idx = row0 + tid;
        bool v = idx < cnt;
        rtok[tid] = v ? toks[e * CAP + idx] : -1;
        rwgt[tid] = v ? wgts[e * CAP + idx] : 0.0f;
    }
    __syncthreads();

    int lane = tid & 63;
    int w = tid >> 6;
    int wr = w >> 1, wc = w & 1;
    int lr = lane & 15, lg = lane >> 4;
    int ar = tid >> 2, ac0 = (tid & 3) * 8;
    int bk = tid >> 3, bf0 = (tid & 7) * 8;
    const float* gupE = gup + (size_t)e * HDIM * F2;

    for (int nb = 0; nb < F2 / 64; ++nb) {
        f32x4 acc[2][2];
#pragma unroll
        for (int mi = 0; mi < 2; ++mi)
#pragma unroll
            for (int ni = 0; ni < 2; ++ni) acc[mi][ni] = (f32x4){0.f, 0.f, 0.f, 0.f};
        for (int kb = 0; kb < HDIM / 32; ++kb) {
            __syncthreads();
            {
                int tk = rtok[ar];
                short8 vv = {0,0,0,0,0,0,0,0};
                if (tk >= 0) {
                    const float* p = x + (size_t)tk * HDIM + kb * 32 + ac0;
                    float4 u0 = *(const float4*)(p); float4 u1 = *(const float4*)(p + 4);
                    vv[0]=(short)f2bf(u0.x); vv[1]=(short)f2bf(u0.y); vv[2]=(short)f2bf(u0.z); vv[3]=(short)f2bf(u0.w);
                    vv[4]=(short)f2bf(u1.x); vv[5]=(short)f2bf(u1.y); vv[6]=(short)f2bf(u1.z); vv[7]=(short)f2bf(u1.w);
                }
                *(short8*)&sA[ar][ac0] = vv;
            }
            {
                const float* p = gupE + (size_t)(kb * 32 + bk) * F2 + nb * 64 + bf0;
                float4 u0 = *(const float4*)(p); float4 u1 = *(const float4*)(p + 4);
                sB[bf0+0][bk]=f2bf(u0.x); sB[bf0+1][bk]=f2bf(u0.y); sB[bf0+2][bk]=f2bf(u0.z); sB[bf0+3][bk]=f2bf(u0.w);
                sB[bf0+4][bk]=f2bf(u1.x); sB[bf0+5][bk]=f2bf(u1.y); sB[bf0+6][bk]=f2bf(u1.z); sB[bf0+7][bk]=f2bf(u1.w);
            }
            __syncthreads();
            short8 a0 = *(const short8*)&sA[wr*32+lr][lg*8];
            short8 a1 = *(const short8*)&sA[wr*32+16+lr][lg*8];
            short8 b0 = *(const short8*)&sB[wc*32+lr][lg*8];
            short8 b1 = *(const short8*)&sB[wc*32+16+lr][lg*8];
            acc[0][0] = __builtin_amdgcn_mfma_f32_16x16x32_bf16(a0,b0,acc[0][0],0,0,0);
            acc[0][1] = __builtin_amdgcn_mfma_f32_16x16x32_bf16(a0,b1,acc[0][1],0,0,0);
            acc[1][0] = __builtin_amdgcn_mfma_f32_16x16x32_bf16(a1,b0,acc[1][0],0,0,0);
            acc[1][1] = __builtin_amdgcn_mfma_f32_16x16x32_bf16(a1,b1,acc[1][1],0,0,0);
        }
#pragma unroll
        for (int ni = 0; ni < 2; ++ni) {
            int fc = nb * 64 + wc * 32 + ni * 16 + lr;
            float bias = gub[e * F2 + fc];
#pragma unroll
            for (int mi = 0; mi < 2; ++mi)
#pragma unroll
                for (int r = 0; r < 4; ++r) {
                    float gu = acc[mi][ni][r] + bias;
                    float other = __shfl_xor(gu, 1);
                    float gate = (lr & 1) ? other : gu;
                    float up   = (lr & 1) ? gu : other;
                    gate = fminf(gate, LIMIT);
                    up = fminf(fmaxf(up, -LIMIT), LIMIT);
                    float glu = gate / (1.0f + __expf(-ALPHA * gate));
                    float av = (up + 1.0f) * glu;
                    if (!(lr & 1)) sAct[wr*32+mi*16+lg*4+r][fc >> 1] = f2bf(av);
                }
        }
    }
    __syncthreads();

    const float* dwnE = dwn + (size_t)e * NI * HDIM;
    int tks[2][4]; float wvs[2][4];
#pragma unroll
    for (int mi = 0; mi < 2; ++mi)
#pragma unroll
        for (int r = 0; r < 4; ++r) {
            int row = wr*32 + mi*16 + lg*4 + r;
            tks[mi][r] = rtok[row]; wvs[mi][r] = rwgt[row];
        }
    for (int nb = 0; nb < HDIM / 64; ++nb) {
        f32x4 acc[2][2];
#pragma unroll
        for (int mi = 0; mi < 2; ++mi)
#pragma unroll
            for (int ni = 0; ni < 2; ++ni) acc[mi][ni] = (f32x4){0.f,0.f,0.f,0.f};
        for (int kb = 0; kb < NI / 32; ++kb) {
            __syncthreads();
            {
                const float* p = dwnE + (size_t)(kb*32 + bk) * HDIM + nb*64 + bf0;
                float4 u0 = *(const float4*)(p); float4 u1 = *(const float4*)(p + 4);
                sB[bf0+0][bk]=f2bf(u0.x); sB[bf0+1][bk]=f2bf(u0.y); sB[bf0+2][bk]=f2bf(u0.z); sB[bf0+3][bk]=f2bf(u0.w);
                sB[bf0+4][bk]=f2bf(u1.x); sB[bf0+5][bk]=f2bf(u1.y); sB[bf0+6][bk]=f2bf(u1.z); sB[bf0+7][bk]=f2bf(u1.w);
            }
            __syncthreads();
            short8 a0 = *(const short8*)&sAct[wr*32+lr][kb*32+lg*8];
            short8 a1 = *(const short8*)&sAct[wr*32+16+lr][kb*32+lg*8];
            short8 b0 = *(const short8*)&sB[wc*32+lr][lg*8];
            short8 b1 = *(const short8*)&sB[wc*32+16+lr][lg*8];
            acc[0][0] = __builtin_amdgcn_mfma_f32_16x16x32_bf16(a0,b0,acc[0][0],0,0,0);
            acc[0][1] = __builtin_amdgcn_mfma_f32_16x16x32_bf16(a0,b1,acc[0][1],0,0,0);
            acc[1][0] = __builtin_amdgcn_mfma_f32_16x16x32_bf16(a1,b0,acc[1][0],0,0,0);
            acc[1][1] = __builtin_amdgcn_mfma_f32_16x16x32_bf16(a1,b1,acc[1][1],0,0,0);
        }
#pragma unroll
        for (int ni = 0; ni < 2; ++ni) {
            int hc = nb*64 + wc*32 + ni*16 + lr;
            float db = dwb[e * HDIM + hc];
#pragma unroll
            for (int mi = 0; mi < 2; ++mi)
#pragma unroll
                for (int r = 0; r < 4; ++r) {
                    int tk = tks[mi][r];
                    if (tk >= 0)
                        atomicAdd(out + (size_t)tk * HDIM + hc, wvs[mi][r] * (acc[mi][ni][r] + db));
                }
        }
    }
}

extern "C" void kernel_launch(void* const* d_in, const int* in_sizes, int n_in,
                              void* d_out, int out_size, void* d_ws, size_t ws_size,
                              hipStream_t stream) {
    const float* x   = (const float*)d_in[0];
    const float* rw  = (const float*)d_in[1];
    const float* gup = (const float*)d_in[2];
    const float* gub = (const float*)d_in[3];
    const float* dwn = (const float*)d_in[4];
    const float* dwb = (const float*)d_in[5];
    float* out = (float*)d_out;

    // ---- ws layout ----
    const size_t OFF_COUNTS = 0;                                   // 256 B
    const size_t OFF_ZP     = 256;                                 // 4 KB zero page
    const size_t OFF_INV    = 4352;                                // 32 KB
    const size_t OFF_TOKS   = OFF_INV  + (size_t)TOK * 2 * 2;
    const size_t OFF_WGTS   = OFF_TOKS + (size_t)NE * CAP * 4;
    const size_t OFF_DWNT   = OFF_WGTS + (size_t)NE * CAP * 4;
    const size_t OFF_ACT    = OFF_DWNT + (size_t)NE * NI * HDIM * 2;   // part (4MB) aliases here
    const size_t OFF_XBF    = OFF_ACT  + (size_t)NE * CAP2 * NI * 2;
    const size_t OFF_GUPT   = OFF_XBF  + (size_t)TOK * HDIM * 2;
    const size_t REQ_B      = OFF_GUPT + (size_t)NE * HDIM * F2 * 2;
    const size_t OFF_Y      = OFF_XBF;                             // aliases xbf+gupT (dead after gemm1)
    const size_t REQ_A      = OFF_Y + (size_t)2 * TOK * HDIM * 2;  // 32 MB compact bf16 y

    if (ws_size >= REQ_B) {
        int*            counts = (int*)((char*)d_ws + OFF_COUNTS);
        unsigned short* zp     = (unsigned short*)((char*)d_ws + OFF_ZP);
        unsigned short* inv    = (unsigned short*)((char*)d_ws + OFF_INV);
        int*            toks   = (int*)((char*)d_ws + OFF_TOKS);
        float*          wgts   = (float*)((char*)d_ws + OFF_WGTS);
        unsigned short* dwnT   = (unsigned short*)((char*)d_ws + OFF_DWNT);
        unsigned short* act    = (unsigned short*)((char*)d_ws + OFF_ACT);
        double*         part   = (double*)((char*)d_ws + OFF_ACT);
        unsigned short* xbf    = (unsigned short*)((char*)d_ws + OFF_XBF);
        unsigned short* gupT   = (unsigned short*)((char*)d_ws + OFF_GUPT);
        unsigned short* y      = (unsigned short*)((char*)d_ws + OFF_Y);

        hipMemsetAsync(d_ws, 0, 4352, stream);   // counts + zero page

        dim3 tg1(F2 / 64, HDIM / 64, NE);
        transpose_kernel<<<tg1, 256, 0, stream>>>(gup, gupT, HDIM, F2, 1);   // gate/up permuted
        dim3 tg2(HDIM / 64, NI / 64, NE);
        transpose_kernel<<<tg2, 256, 0, stream>>>(dwn, dwnT, NI, HDIM, 0);

        router_partial_kernel<<<(TOK / 16) * 4, 64, 0, stream>>>(x, rw, part, xbf);
        router_combine_kernel<<<TOK / 256, 256, 0, stream>>>(part, counts, toks, wgts, inv);

        int g1 = (CAP2 / 128) * (F2 / 128) * NE;     // 2048
        gemm1_kernel<<<g1, 256, 0, stream>>>(xbf, gupT, gub, counts, toks, act, zp);
        int g2 = (CAP2 / 128) * (HDIM / 128) * NE;   // 2048

        if (ws_size >= REQ_A) {
            gemm2_y_kernel<<<g2, 256, 0, stream>>>(act, dwnT, dwb, counts, wgts, y);
            out_combine_kernel<<<TOK, 256, 0, stream>>>(y, inv, counts, out);
        } else {
            hipMemsetAsync(d_out, 0, (size_t)out_size * sizeof(float), stream);
            out_combine_kernel<<<TOK, 256, 0, stream>>>(y, inv, counts, out);
        }
    } else {
        // fallback: round-1 path (~1.1 MB of ws)
        int*   counts = (int*)d_ws;
        int*   toks   = (int*)((char*)d_ws + 64);
        float* wgts   = (float*)((char*)d_ws + 64 + (size_t)NE * CAP * sizeof(int));
        hipMemsetAsync(d_ws, 0, 64, stream);
        hipMemsetAsync(d_out, 0, (size_t)out_size * sizeof(float), stream);
        router_kernel<<<TOK / 4, 256, 0, stream>>>(x, rw, counts, toks, wgts);
        dim3 gm(TOK / 64, NE);
        moe_kernel<<<gm, 256, 0, stream>>>(x, gup, gub, dwn, dwb, counts, toks, wgts, out);
    }
}

// Round 8
// 168.346 us; speedup vs baseline: 7.0350x; 1.0310x over previous
//
#include <hip/hip_runtime.h>
#include <hip/hip_bf16.h>
#include <math.h>

#define TOK   8192
#define HDIM  1024
#define NE    16
#define NI    512
#define F2    1024
#define CAP   8192
#define CAP2  2048
#define ALPHA 1.702f
#define LIMIT 7.0f

typedef __attribute__((ext_vector_type(8))) short short8;
typedef __attribute__((ext_vector_type(4))) short short4v;
typedef __attribute__((ext_vector_type(4))) float f32x4;

static __device__ __forceinline__ unsigned short f2bf(float f) {
    unsigned int u = __float_as_uint(f);
    u += 0x7FFFu + ((u >> 16) & 1u);
    return (unsigned short)(u >> 16);
}
static __device__ __forceinline__ float bf2f(unsigned short u) {
    return __uint_as_float((unsigned int)u << 16);
}

#define GLD_LDS16(g, l) __builtin_amdgcn_global_load_lds(                     \
    (const __attribute__((address_space(1))) void*)(g),                       \
    (__attribute__((address_space(3))) void*)(l), 16, 0, 0)

// ================= router phase A: fp64 partial logits, fused x->bf16 =================
__global__ __launch_bounds__(64) void router_partial_kernel(
    const float* __restrict__ x, const float* __restrict__ rw,
    double* __restrict__ part, unsigned short* __restrict__ xbf)
{
    int bx = blockIdx.x;
    int tile = bx >> 2, ksl = bx & 3;
    int t0 = tile * 16;
    int hbase = ksl * 256;

    __shared__ __align__(16) float sx[16][68];
    __shared__ __align__(16) float srw[64][16];

    int lane = threadIdx.x;
    int tt = lane & 15, eg = lane >> 4;

    double acc[4] = {0.0, 0.0, 0.0, 0.0};

    for (int hc = 0; hc < 4; ++hc) {
        int h0 = hbase + hc * 64;
        __syncthreads();
#pragma unroll
        for (int j = 0; j < 4; ++j) {
            int fidx = j * 64 + lane;
            int t = fidx >> 4, c4 = (fidx & 15) * 4;
            float4 v = *(const float4*)(x + (size_t)(t0 + t) * HDIM + h0 + c4);
            *(float4*)&sx[t][c4] = v;
            short4v s;
            s[0] = (short)f2bf(v.x); s[1] = (short)f2bf(v.y);
            s[2] = (short)f2bf(v.z); s[3] = (short)f2bf(v.w);
            *(short4v*)(xbf + (size_t)(t0 + t) * HDIM + h0 + c4) = s;
        }
#pragma unroll
        for (int j = 0; j < 4; ++j) {
            int ridx = j * 64 + lane;
            int h = ridx >> 2, e4 = (ridx & 3) * 4;
            float4 v = *(const float4*)(rw + (size_t)(h0 + h) * NE + e4);
            *(float4*)&srw[h][e4] = v;
        }
        __syncthreads();
#pragma unroll 8
        for (int j = 0; j < 64; ++j) {
            float xv = sx[tt][j];
            float4 wv = *(const float4*)&srw[j][eg * 4];
            double xd = (double)xv;
            acc[0] += xd * (double)wv.x;
            acc[1] += xd * (double)wv.y;
            acc[2] += xd * (double)wv.z;
            acc[3] += xd * (double)wv.w;
        }
    }
#pragma unroll
    for (int q = 0; q < 4; ++q)
        part[(size_t)(ksl * NE + eg * 4 + q) * TOK + t0 + tt] = acc[q];
}

// ===== router phase B: combine, top-2, softmax, aggregated scatter + inverse map =====
__global__ __launch_bounds__(256) void router_combine_kernel(
    const double* __restrict__ part,
    int* __restrict__ counts, int* __restrict__ toks, float* __restrict__ wgts,
    unsigned short* __restrict__ inv)
{
    __shared__ int lhist[NE];
    __shared__ int lbase[NE];
    int tid = threadIdx.x;
    int t = blockIdx.x * 256 + tid;
    if (tid < NE) lhist[tid] = 0;
    __syncthreads();

    double acc[NE];
#pragma unroll
    for (int e = 0; e < NE; ++e)
        acc[e] = part[(size_t)(0 * NE + e) * TOK + t]
               + part[(size_t)(1 * NE + e) * TOK + t]
               + part[(size_t)(2 * NE + e) * TOK + t]
               + part[(size_t)(3 * NE + e) * TOK + t];

    int i0 = 0; double v0 = acc[0];
#pragma unroll
    for (int e = 1; e < NE; ++e) if (acc[e] > v0) { v0 = acc[e]; i0 = e; }
    int i1 = -1; double v1 = -1e300;
#pragma unroll
    for (int e = 0; e < NE; ++e) if (e != i0 && acc[e] > v1) { v1 = acc[e]; i1 = e; }
    double e1 = exp(v1 - v0);
    float w0 = (float)(1.0 / (1.0 + e1));
    float w1 = (float)(e1 / (1.0 + e1));

    int r0 = atomicAdd(&lhist[i0], 1);
    int r1 = atomicAdd(&lhist[i1], 1);
    __syncthreads();
    if (tid < NE) lbase[tid] = atomicAdd(&counts[tid], lhist[tid]);
    __syncthreads();
    int p0 = lbase[i0] + r0; if (p0 > 2047) p0 = 2047;
    int p1 = lbase[i1] + r1; if (p1 > 2047) p1 = 2047;
    toks[i0 * CAP + p0] = t; wgts[i0 * CAP + p0] = w0;
    toks[i1 * CAP + p1] = t; wgts[i1 * CAP + p1] = w1;
    inv[2 * t]     = (unsigned short)((i0 << 11) | p0);
    inv[2 * t + 1] = (unsigned short)((i1 << 11) | p1);
}

// ------------- transpose + convert: in [E][R][C] fp32 -> out [E][C][R] bf16 -------------
__global__ __launch_bounds__(256) void transpose_kernel(
    const float* __restrict__ in, unsigned short* __restrict__ out, int R, int C, int perm)
{
    int e = blockIdx.z;
    const float* pin = in + (size_t)e * R * C;
    unsigned short* pout = out + (size_t)e * R * C;
    __shared__ float t2[64][65];
    int c0 = blockIdx.x * 64, r0 = blockIdx.y * 64;
    int tid = threadIdx.x;
#pragma unroll
    for (int j = 0; j < 4; ++j) {
        int idx4 = j * 256 + tid;
        int r = idx4 >> 4, c4 = (idx4 & 15) * 4;
        float4 v = *(const float4*)(pin + (size_t)(r0 + r) * C + c0 + c4);
        t2[c4 + 0][r] = v.x;
        t2[c4 + 1][r] = v.y;
        t2[c4 + 2][r] = v.z;
        t2[c4 + 3][r] = v.w;
    }
    __syncthreads();
#pragma unroll
    for (int j = 0; j < 2; ++j) {
        int idx = j * 256 + tid;
        int n = idx >> 3, k0 = (idx & 7) * 8;
        short8 v;
#pragma unroll
        for (int q = 0; q < 8; ++q) v[q] = (short)f2bf(t2[n][k0 + q]);
        int c = c0 + n;
        int orow;
        if (perm) {
            int tile = c >> 7, ct = c & 127;
            int fl = ct >> 1, h = ct & 1;
            orow = (tile << 7) | ((fl >> 4) << 5) | (h << 4) | (fl & 15);
        } else {
            orow = c;
        }
        *(short8*)(pout + (size_t)orow * R + r0 + k0) = v;
    }
}

// ===== 3-buffer counted-vmcnt K-loop (T3/T4, prefetch depth 2): =====
// prologue stages tiles 0,1; iter kb issues tile kb+2, waits vmcnt(8) (tiles kb+1,kb+2
// stay in flight -> ~2 iterations (>=800cyc) to cover HBM latency), computes buf[kb%3].
#define KLOOP_BODY(NT, KOFF)                                                          \
    int c0 = 0;                                                                       \
    for (int kb = 0; kb < (NT); ++kb) {                                               \
        if (kb + 2 < (NT)) {                                                          \
            int cpre = c0 + 2; if (cpre >= 3) cpre -= 3;                              \
            _Pragma("unroll")                                                         \
            for (int i = 0; i < 2; ++i) {                                             \
                GLD_LDS16(gaA[i] + (kb + 2) * (KOFF), &As[cpre][w * 32 + i * 16][0]); \
                GLD_LDS16(gaB[i] + (kb + 2) * (KOFF), &Bs[cpre][w * 32 + i * 16][0]); \
            }                                                                         \
            asm volatile("s_waitcnt vmcnt(8)" ::: "memory");                          \
        } else if (kb + 1 < (NT)) {                                                   \
            asm volatile("s_waitcnt vmcnt(4)" ::: "memory");                          \
        } else {                                                                      \
            asm volatile("s_waitcnt vmcnt(0)" ::: "memory");                          \
        }                                                                             \
        __builtin_amdgcn_sched_barrier(0);                                            \
        __builtin_amdgcn_s_barrier();                                                 \
        __builtin_amdgcn_sched_barrier(0);                                            \
        short8 af[4], bfr[4];                                                         \
        _Pragma("unroll")                                                             \
        for (int m = 0; m < 4; ++m) af[m] = *(const short8*)&As[c0][wr * 64 + m * 16 + lr][slt]; \
        _Pragma("unroll")                                                             \
        for (int n = 0; n < 4; ++n) bfr[n] = *(const short8*)&Bs[c0][wc * 64 + n * 16 + lr][slt]; \
        _Pragma("unroll")                                                             \
        for (int m = 0; m < 4; ++m)                                                   \
            _Pragma("unroll")                                                         \
            for (int n = 0; n < 4; ++n)                                               \
                acc[m][n] = __builtin_amdgcn_mfma_f32_16x16x32_bf16(af[m], bfr[n], acc[m][n], 0, 0, 0); \
        asm volatile("s_waitcnt lgkmcnt(0)" ::: "memory");                            \
        __builtin_amdgcn_sched_barrier(0);                                            \
        __builtin_amdgcn_s_barrier();                                                 \
        __builtin_amdgcn_sched_barrier(0);                                            \
        c0 = (c0 + 1 == 3) ? 0 : c0 + 1;                                              \
    }

#define KLOOP_PROLOGUE(KOFF)                                                          \
    _Pragma("unroll")                                                                 \
    for (int i = 0; i < 2; ++i) {                                                     \
        GLD_LDS16(gaA[i], &As[0][w * 32 + i * 16][0]);                                \
        GLD_LDS16(gaB[i], &Bs[0][w * 32 + i * 16][0]);                                \
    }                                                                                 \
    _Pragma("unroll")                                                                 \
    for (int i = 0; i < 2; ++i) {                                                     \
        GLD_LDS16(gaA[i] + (KOFF), &As[1][w * 32 + i * 16][0]);                       \
        GLD_LDS16(gaB[i] + (KOFF), &Bs[1][w * 32 + i * 16][0]);                       \
    }

// ---------------- GEMM1: x_bf (gathered) @ gupT^T + bias -> act (bf16) ----------------
__global__ __launch_bounds__(256) void gemm1_kernel(
    const unsigned short* __restrict__ xb, const unsigned short* __restrict__ gupT,
    const float* __restrict__ gub,
    const int* __restrict__ counts, const int* __restrict__ toks,
    unsigned short* __restrict__ act, const unsigned short* __restrict__ zp)
{
    int b = blockIdx.x;
    int e = b & 15;
    int j = b >> 4;
    int nt = j & 7;
    int mt = j >> 3;
    int cnt = counts[e];
    int row0 = mt * 128;
    if (row0 >= cnt) return;
    int n0 = nt * 128;

    __shared__ __align__(16) unsigned short As[3][128][32];
    __shared__ __align__(16) unsigned short Bs[3][128][32];
    __shared__ int rtok[128];

    int tid = threadIdx.x;
    int lane = tid & 63;
    int w = tid >> 6;
    int wr = w >> 1, wc = w & 1;
    int lr = lane & 15, lg = lane >> 4;

    if (tid < 128) {
        int p = row0 + tid;
        rtok[tid] = (p < cnt) ? toks[e * CAP + p] : -1;
    }
    __syncthreads();

    int srow = lane >> 2;
    int scol = (((lane & 3) ^ ((lane >> 3) & 3)) * 8);
    int slt = (lg ^ ((lr >> 1) & 3)) * 8;

    const unsigned short* gaA[2];
    const unsigned short* gaB[2];
    const unsigned short* gupE = gupT + (size_t)e * HDIM * F2;
#pragma unroll
    for (int i = 0; i < 2; ++i) {
        int arow = w * 32 + i * 16 + srow;
        int tk = rtok[arow];
        gaA[i] = (tk >= 0) ? (xb + (size_t)tk * HDIM + scol) : (zp + scol);
        int brow = n0 + w * 32 + i * 16 + srow;
        gaB[i] = gupE + (size_t)brow * HDIM + scol;
    }

    f32x4 acc[4][4];
#pragma unroll
    for (int m = 0; m < 4; ++m)
#pragma unroll
        for (int n = 0; n < 4; ++n) acc[m][n] = (f32x4){0.f, 0.f, 0.f, 0.f};

    KLOOP_PROLOGUE(32)
    KLOOP_BODY(HDIM / 32, 32)

    // epilogue: permuted B rows => acc[m][2q]=gate, acc[m][2q+1]=up of SAME feature, same lane
    unsigned short* actE = act + (size_t)e * CAP2 * NI;
    int fbase = nt * 64 + wc * 32;
#pragma unroll
    for (int q = 0; q < 2; ++q) {
        int f = fbase + q * 16 + lr;
        float bg = gub[e * F2 + 2 * f];
        float bu = gub[e * F2 + 2 * f + 1];
#pragma unroll
        for (int m = 0; m < 4; ++m) {
#pragma unroll
            for (int r = 0; r < 4; ++r) {
                float gate = acc[m][2 * q][r] + bg;
                float up   = acc[m][2 * q + 1][r] + bu;
                gate = fminf(gate, LIMIT);
                up   = fminf(fmaxf(up, -LIMIT), LIMIT);
                float glu = gate / (1.0f + __expf(-ALPHA * gate));
                float av  = (up + 1.0f) * glu;
                int row = row0 + wr * 64 + m * 16 + lg * 4 + r;
                actE[(size_t)row * NI + f] = f2bf(av);
            }
        }
    }
}

// ------- GEMM2 (tier A): act @ dwnT^T, *score, +bias -> compact bf16 y[base[e]+p][HDIM] -------
__global__ __launch_bounds__(256) void gemm2_y_kernel(
    const unsigned short* __restrict__ act, const unsigned short* __restrict__ dwnT,
    const float* __restrict__ dwb,
    const int* __restrict__ counts, const float* __restrict__ wgts,
    unsigned short* __restrict__ y)
{
    int b = blockIdx.x;
    int e = b & 15;
    int j = b >> 4;
    int nt = j & 7;
    int mt = j >> 3;
    int cnt = counts[e];
    int row0 = mt * 128;
    if (row0 >= cnt) return;
    int n0 = nt * 128;

    int base_e = 0;
#pragma unroll
    for (int q = 0; q < NE; ++q) base_e += (q < e) ? counts[q] : 0;

    __shared__ __align__(16) unsigned short As[3][128][32];
    __shared__ __align__(16) unsigned short Bs[3][128][32];
    __shared__ float rwgt[128];

    int tid = threadIdx.x;
    int lane = tid & 63;
    int w = tid >> 6;
    int wr = w >> 1, wc = w & 1;
    int lr = lane & 15, lg = lane >> 4;

    if (tid < 128) {
        int p = row0 + tid;
        rwgt[tid] = (p < cnt) ? wgts[e * CAP + p] : 0.0f;
    }
    __syncthreads();

    int srow = lane >> 2;
    int scol = (((lane & 3) ^ ((lane >> 3) & 3)) * 8);
    int slt = (lg ^ ((lr >> 1) & 3)) * 8;

    const unsigned short* gaA[2];
    const unsigned short* gaB[2];
    const unsigned short* actE = act + (size_t)e * CAP2 * NI;
    const unsigned short* dwnE = dwnT + (size_t)e * HDIM * NI;
#pragma unroll
    for (int i = 0; i < 2; ++i) {
        int arow = row0 + w * 32 + i * 16 + srow;
        gaA[i] = actE + (size_t)arow * NI + scol;
        int brow = n0 + w * 32 + i * 16 + srow;
        gaB[i] = dwnE + (size_t)brow * NI + scol;
    }

    f32x4 acc[4][4];
#pragma unroll
    for (int m = 0; m < 4; ++m)
#pragma unroll
        for (int n = 0; n < 4; ++n) acc[m][n] = (f32x4){0.f, 0.f, 0.f, 0.f};

    KLOOP_PROLOGUE(32)
    KLOOP_BODY(NI / 32, 32)

    unsigned short* yB = y + (size_t)(base_e + row0) * HDIM;
#pragma unroll
    for (int n = 0; n < 4; ++n) {
        int hc = n0 + wc * 64 + n * 16 + lr;
        float db = dwb[e * HDIM + hc];
#pragma unroll
        for (int m = 0; m < 4; ++m) {
#pragma unroll
            for (int r = 0; r < 4; ++r) {
                int rl = wr * 64 + m * 16 + lg * 4 + r;
                if (row0 + rl < cnt)
                    yB[(size_t)rl * HDIM + hc] = f2bf(rwgt[rl] * (acc[m][n][r] + db));
            }
        }
    }
}

// ------- out combine: out[t] = y[slot0] + y[slot1]; bf16 reads, coalesced, no atomics -------
__global__ __launch_bounds__(256) void out_combine_kernel(
    const unsigned short* __restrict__ y, const unsigned short* __restrict__ inv,
    const int* __restrict__ counts, float* __restrict__ out)
{
    __shared__ int sbase[NE];
    int tid = threadIdx.x;
    int t = blockIdx.x;
    if (tid == 0) {
        int s = 0;
#pragma unroll
        for (int e = 0; e < NE; ++e) { sbase[e] = s; s += counts[e]; }
    }
    __syncthreads();
    unsigned short v0 = inv[2 * t], v1 = inv[2 * t + 1];
    int s0 = sbase[v0 >> 11] + (v0 & 2047);
    int s1 = sbase[v1 >> 11] + (v1 & 2047);
    short4v a = *(const short4v*)(y + (size_t)s0 * HDIM + tid * 4);
    short4v c = *(const short4v*)(y + (size_t)s1 * HDIM + tid * 4);
    float4 o;
    o.x = bf2f((unsigned short)a[0]) + bf2f((unsigned short)c[0]);
    o.y = bf2f((unsigned short)a[1]) + bf2f((unsigned short)c[1]);
    o.z = bf2f((unsigned short)a[2]) + bf2f((unsigned short)c[2]);
    o.w = bf2f((unsigned short)a[3]) + bf2f((unsigned short)c[3]);
    *(float4*)(out + (size_t)t * HDIM + tid * 4) = o;
}

// ================= fallback path kernels (round-1 style, small ws) =================
__global__ __launch_bounds__(256) void router_kernel(
    const float* __restrict__ x, const float* __restrict__ rw,
    int* __restrict__ counts, int* __restrict__ toks, float* __restrict__ wgts)
{
    int gwave = (int)((blockIdx.x * 256 + threadIdx.x) >> 6);
    int lane = threadIdx.x & 63;
    if (gwave >= TOK) return;
    const float* xr = x + (size_t)gwave * HDIM;
    double acc[NE];
#pragma unroll
    for (int e = 0; e < NE; ++e) acc[e] = 0.0;
    for (int i = 0; i < HDIM / 64; ++i) {
        int h = i * 64 + lane;
        double xv = (double)xr[h];
        const float* r = rw + (size_t)h * NE;
#pragma unroll
        for (int e = 0; e < NE; ++e) acc[e] += xv * (double)r[e];
    }
#pragma unroll
    for (int e = 0; e < NE; ++e) {
        double v = acc[e];
#pragma unroll
        for (int off = 32; off > 0; off >>= 1) v += __shfl_xor(v, off);
        acc[e] = v;
    }
    if (lane == 0) {
        int i0 = 0; double v0 = acc[0];
#pragma unroll
        for (int e = 1; e < NE; ++e) if (acc[e] > v0) { v0 = acc[e]; i0 = e; }
        int i1 = -1; double v1 = -1e300;
#pragma unroll
        for (int e = 0; e < NE; ++e) if (e != i0 && acc[e] > v1) { v1 = acc[e]; i1 = e; }
        double e1 = exp(v1 - v0);
        float w0 = (float)(1.0 / (1.0 + e1));
        float w1 = (float)(e1 / (1.0 + e1));
        int p0 = atomicAdd(&counts[i0], 1);
        toks[i0 * CAP + p0] = gwave; wgts[i0 * CAP + p0] = w0;
        int p1 = atomicAdd(&counts[i1], 1);
        toks[i1 * CAP + p1] = gwave; wgts[i1 * CAP + p1] = w1;
    }
}

__global__ __launch_bounds__(256) void moe_kernel(
    const float* __restrict__ x,
    const float* __restrict__ gup, const float* __restrict__ gub,
    const float* __restrict__ dwn, const float* __restrict__ dwb,
    const int* __restrict__ counts, const int* __restrict__ toks,
    const float* __restrict__ wgts, float* __restrict__ out)
{
    int e = blockIdx.y;
    int cnt = counts[e];
    int row0 = blockIdx.x * 64;
    if (row0 >= cnt) return;

    __shared__ __align__(16) unsigned short sA[64][40];
    __shared__ __align__(16) unsigned short sB[64][40];
    __shared__ __align__(16) unsigned short sAct[64][520];
    __shared__ int   rtok[64];
    __shared__ float rwgt[64];

    int tid = threadIdx.x;
    if (tid < 64) {
        int idx = row0 + tid;
        bool v = idx < cnt;
        rtok[tid] = v ? toks[e * CAP + idx] : -1;
        rwgt[tid] = v ? wgts[e * CAP + idx] : 0.0f;
    }
    __syncthreads();

    int lane = tid & 63;
    int w = tid >> 6;
    int wr = w >> 1, wc = w & 1;
    int lr = lane & 15, lg = lane >> 4;
    int ar = tid >> 2, ac0 = (tid & 3) * 8;
    int bk = tid >> 3, bf0 = (tid & 7) * 8;
    const float* gupE = gup + (size_t)e * HDIM * F2;

    for (int nb = 0; nb < F2 / 64; ++nb) {
        f32x4 acc[2][2];
#pragma unroll
        for (int mi = 0; mi < 2; ++mi)
#pragma unroll
            for (int ni = 0; ni < 2; ++ni) acc[mi][ni] = (f32x4){0.f, 0.f, 0.f, 0.f};
        for (int kb = 0; kb < HDIM / 32; ++kb) {
            __syncthreads();
            {
                int tk = rtok[ar];
                short8 vv = {0,0,0,0,0,0,0,0};
                if (tk >= 0) {
                    const float* p = x + (size_t)tk * HDIM + kb * 32 + ac0;
                    float4 u0 = *(const float4*)(p); float4 u1 = *(const float4*)(p + 4);
                    vv[0]=(short)f2bf(u0.x); vv[1]=(short)f2bf(u0.y); vv[2]=(short)f2bf(u0.z); vv[3]=(short)f2bf(u0.w);
                    vv[4]=(short)f2bf(u1.x); vv[5]=(short)f2bf(u1.y); vv[6]=(short)f2bf(u1.z); vv[7]=(short)f2bf(u1.w);
                }
                *(short8*)&sA[ar][ac0] = vv;
            }
            {
                const float* p = gupE + (size_t)(kb * 32 + bk) * F2 + nb * 64 + bf0;
                float4 u0 = *(const float4*)(p); float4 u1 = *(const float4*)(p + 4);
                sB[bf0+0][bk]=f2bf(u0.x); sB[bf0+1][bk]=f2bf(u0.y); sB[bf0+2][bk]=f2bf(u0.z); sB[bf0+3][bk]=f2bf(u0.w);
                sB[bf0+4][bk]=f2bf(u1.x); sB[bf0+5][bk]=f2bf(u1.y); sB[bf0+6][bk]=f2bf(u1.z); sB[bf0+7][bk]=f2bf(u1.w);
            }
            __syncthreads();
            short8 a0 = *(const short8*)&sA[wr*32+lr][lg*8];
            short8 a1 = *(const short8*)&sA[wr*32+16+lr][lg*8];
            short8 b0 = *(const short8*)&sB[wc*32+lr][lg*8];
            short8 b1 = *(const short8*)&sB[wc*32+16+lr][lg*8];
            acc[0][0] = __builtin_amdgcn_mfma_f32_16x16x32_bf16(a0,b0,acc[0][0],0,0,0);
            acc[0][1] = __builtin_amdgcn_mfma_f32_16x16x32_bf16(a0,b1,acc[0][1],0,0,0);
            acc[1][0] = __builtin_amdgcn_mfma_f32_16x16x32_bf16(a1,b0,acc[1][0],0,0,0);
            acc[1][1] = __builtin_amdgcn_mfma_f32_16x16x32_bf16(a1,b1,acc[1][1],0,0,0);
        }
#pragma unroll
        for (int ni = 0; ni < 2; ++ni) {
            int fc = nb * 64 + wc * 32 + ni * 16 + lr;
            float bias = gub[e * F2 + fc];
#pragma unroll
            for (int mi = 0; mi < 2; ++mi)
#pragma unroll
                for (int r = 0; r < 4; ++r) {
                    float gu = acc[mi][ni][r] + bias;
                    float other = __shfl_xor(gu, 1);
                    float gate = (lr & 1) ? other : gu;
                    float up   = (lr & 1) ? gu : other;
                    gate = fminf(gate, LIMIT);
                    up = fminf(fmaxf(up, -LIMIT), LIMIT);
                    float glu = gate / (1.0f + __expf(-ALPHA * gate));
                    float av = (up + 1.0f) * glu;
                    if (!(lr & 1)) sAct[wr*32+mi*16+lg*4+r][fc >> 1] = f2bf(av);
                }
        }
    }
    __syncthreads();

    const float* dwnE = dwn + (size_t)e * NI * HDIM;
    int tks[2][4]; float wvs[2][4];
#pragma unroll
    for (int mi = 0; mi < 2; ++mi)
#pragma unroll
        for (int r = 0; r < 4; ++r) {
            int row = wr*32 + mi*16 + lg*4 + r;
            tks[mi][r] = rtok[row]; wvs[mi][r] = rwgt[row];
        }
    for (int nb = 0; nb < HDIM / 64; ++nb) {
        f32x4 acc[2][2];
#pragma unroll
        for (int mi = 0; mi < 2; ++mi)
#pragma unroll
            for (int ni = 0; ni < 2; ++ni) acc[mi][ni] = (f32x4){0.f,0.f,0.f,0.f};
        for (int kb = 0; kb < NI / 32; ++kb) {
            __syncthreads();
            {
                const float* p = dwnE + (size_t)(kb*32 + bk) * HDIM + nb*64 + bf0;
                float4 u0 = *(const float4*)(p); float4 u1 = *(const float4*)(p + 4);
                sB[bf0+0][bk]=f2bf(u0.x); sB[bf0+1][bk]=f2bf(u0.y); sB[bf0+2][bk]=f2bf(u0.z); sB[bf0+3][bk]=f2bf(u0.w);
                sB[bf0+4][bk]=f2bf(u1.x); sB[bf0+5][bk]=f2bf(u1.y); sB[bf0+6][bk]=f2bf(u1.z); sB[bf0+7][bk]=f2bf(u1.w);
            }
            __syncthreads();
            short8 a0 = *(const short8*)&sAct[wr*32+lr][kb*32+lg*8];
            short8 a1 = *(const short8*)&sAct[wr*32+16+lr][kb*32+lg*8];
            short8 b0 = *(const short8*)&sB[wc*32+lr][lg*8];
            short8 b1 = *(const short8*)&sB[wc*32+16+lr][lg*8];
            acc[0][0] = __builtin_amdgcn_mfma_f32_16x16x32_bf16(a0,b0,acc[0][0],0,0,0);
            acc[0][1] = __builtin_amdgcn_mfma_f32_16x16x32_bf16(a0,b1,acc[0][1],0,0,0);
            acc[1][0] = __builtin_amdgcn_mfma_f32_16x16x32_bf16(a1,b0,acc[1][0],0,0,0);
            acc[1][1] = __builtin_amdgcn_mfma_f32_16x16x32_bf16(a1,b1,acc[1][1],0,0,0);
        }
#pragma unroll
        for (int ni = 0; ni < 2; ++ni) {
            int hc = nb*64 + wc*32 + ni*16 + lr;
            float db = dwb[e * HDIM + hc];
#pragma unroll
            for (int mi = 0; mi < 2; ++mi)
#pragma unroll
                for (int r = 0; r < 4; ++r) {
                    int tk = tks[mi][r];
                    if (tk >= 0)
                        atomicAdd(out + (size_t)tk * HDIM + hc, wvs[mi][r] * (acc[mi][ni][r] + db));
                }
        }
    }
}

extern "C" void kernel_launch(void* const* d_in, const int* in_sizes, int n_in,
                              void* d_out, int out_size, void* d_ws, size_t ws_size,
                              hipStream_t stream) {
    const float* x   = (const float*)d_in[0];
    const float* rw  = (const float*)d_in[1];
    const float* gup = (const float*)d_in[2];
    const float* gub = (const float*)d_in[3];
    const float* dwn = (const float*)d_in[4];
    const float* dwb = (const float*)d_in[5];
    float* out = (float*)d_out;

    // ---- ws layout ----
    const size_t OFF_COUNTS = 0;                                   // 256 B
    const size_t OFF_ZP     = 256;                                 // 4 KB zero page
    const size_t OFF_INV    = 4352;                                // 32 KB
    const size_t OFF_TOKS   = OFF_INV  + (size_t)TOK * 2 * 2;
    const size_t OFF_WGTS   = OFF_TOKS + (size_t)NE * CAP * 4;
    const size_t OFF_DWNT   = OFF_WGTS + (size_t)NE * CAP * 4;
    const size_t OFF_ACT    = OFF_DWNT + (size_t)NE * NI * HDIM * 2;   // part (4MB) aliases here
    const size_t OFF_XBF    = OFF_ACT  + (size_t)NE * CAP2 * NI * 2;
    const size_t OFF_GUPT   = OFF_XBF  + (size_t)TOK * HDIM * 2;
    const size_t REQ_B      = OFF_GUPT + (size_t)NE * HDIM * F2 * 2;
    const size_t OFF_Y      = OFF_XBF;                             // aliases xbf+gupT (dead after gemm1)
    const size_t REQ_A      = OFF_Y + (size_t)2 * TOK * HDIM * 2;  // 32 MB compact bf16 y

    if (ws_size >= REQ_B) {
        int*            counts = (int*)((char*)d_ws + OFF_COUNTS);
        unsigned short* zp     = (unsigned short*)((char*)d_ws + OFF_ZP);
        unsigned short* inv    = (unsigned short*)((char*)d_ws + OFF_INV);
        int*            toks   = (int*)((char*)d_ws + OFF_TOKS);
        float*          wgts   = (float*)((char*)d_ws + OFF_WGTS);
        unsigned short* dwnT   = (unsigned short*)((char*)d_ws + OFF_DWNT);
        unsigned short* act    = (unsigned short*)((char*)d_ws + OFF_ACT);
        double*         part   = (double*)((char*)d_ws + OFF_ACT);
        unsigned short* xbf    = (unsigned short*)((char*)d_ws + OFF_XBF);
        unsigned short* gupT   = (unsigned short*)((char*)d_ws + OFF_GUPT);
        unsigned short* y      = (unsigned short*)((char*)d_ws + OFF_Y);

        hipMemsetAsync(d_ws, 0, 4352, stream);   // counts + zero page

        dim3 tg1(F2 / 64, HDIM / 64, NE);
        transpose_kernel<<<tg1, 256, 0, stream>>>(gup, gupT, HDIM, F2, 1);   // gate/up permuted
        dim3 tg2(HDIM / 64, NI / 64, NE);
        transpose_kernel<<<tg2, 256, 0, stream>>>(dwn, dwnT, NI, HDIM, 0);

        router_partial_kernel<<<(TOK / 16) * 4, 64, 0, stream>>>(x, rw, part, xbf);
        router_combine_kernel<<<TOK / 256, 256, 0, stream>>>(part, counts, toks, wgts, inv);

        int g1 = (CAP2 / 128) * (F2 / 128) * NE;     // 2048
        gemm1_kernel<<<g1, 256, 0, stream>>>(xbf, gupT, gub, counts, toks, act, zp);
        int g2 = (CAP2 / 128) * (HDIM / 128) * NE;   // 2048

        if (ws_size >= REQ_A) {
            gemm2_y_kernel<<<g2, 256, 0, stream>>>(act, dwnT, dwb, counts, wgts, y);
            out_combine_kernel<<<TOK, 256, 0, stream>>>(y, inv, counts, out);
        } else {
            hipMemsetAsync(d_out, 0, (size_t)out_size * sizeof(float), stream);
            out_combine_kernel<<<TOK, 256, 0, stream>>>(y, inv, counts, out);
        }
    } else {
        // fallback: round-1 path (~1.1 MB of ws)
        int*   counts = (int*)d_ws;
        int*   toks   = (int*)((char*)d_ws + 64);
        float* wgts   = (float*)((char*)d_ws + 64 + (size_t)NE * CAP * sizeof(int));
        hipMemsetAsync(d_ws, 0, 64, stream);
        hipMemsetAsync(d_out, 0, (size_t)out_size * sizeof(float), stream);
        router_kernel<<<TOK / 4, 256, 0, stream>>>(x, rw, counts, toks, wgts);
        dim3 gm(TOK / 64, NE);
        moe_kernel<<<gm, 256, 0, stream>>>(x, gup, gub, dwn, dwb, counts, toks, wgts, out);
    }
}